// Round 1
// 1578.115 us; speedup vs baseline: 1.1940x; 1.1940x over previous
//
#include <hip/hip_runtime.h>
#include <hip/hip_bf16.h>

constexpr int B_ = 8, N_ = 2048, K_ = 20;
constexpr float EPS_ = 1e-5f;

// ---- weight area offsets (in floats) ----
constexpr int OW1T = 0;                    // W1^T  [512][256]
constexpr int OWST = OW1T + 512 * 256;     // Ws^T  [512][256]
constexpr int OW2T = OWST + 512 * 256;     // W2^T  [256][256]
constexpr int OWQT = OW2T + 256 * 256;     // wq^T  [256][64]
constexpr int OWKT = OWQT + 256 * 64;
constexpr int OWVT = OWKT + 256 * 64;
constexpr int OWUT = OWVT + 256 * 64;
constexpr int OWRT = OWUT + 256 * 64;      // wr^T  [256][128]
constexpr int OWET = OWRT + 256 * 128;     // we^T  [o][co] 64x128
constexpr int OWTC = OWET + 64 * 128;      // wtp: packed-f16 am_wt [c4][or][j] = 64*128*2 uints (reuses 256*128 f32 slot)
constexpr int OAW1 = OWTC + 256 * 128;     // aw1p: packed-f16 am_w1 [o2][c] = 32*256 uints (reuses 64*256 f32 slot)
constexpr int OPW1 = OAW1 + 64 * 256;      // pm_w1 [ph][3]
constexpr int OPW2 = OPW1 + 64 * 3;        // pm_w2 [o][c] 64x64 (native)
constexpr int OB1  = OPW2 + 64 * 64;       // mv_b1 [256]
constexpr int OBS2 = OB1 + 256;            // mv_bs + mv_b2 [256]
constexpr int OBQ  = OBS2 + 256;
constexpr int OBK  = OBQ + 64;
constexpr int OBV  = OBK + 64;
constexpr int OBU  = OBV + 64;
constexpr int OBR  = OBU + 64;             // [128]
constexpr int OBE  = OBR + 128;            // [128]
constexpr int OPB1 = OBE + 128;            // [64]
constexpr int OPSC = OPB1 + 64;
constexpr int OPSH = OPSC + 64;
constexpr int OPB2 = OPSH + 64;
constexpr int OASC = OPB2 + 64;            // [256]
constexpr int OASH = OASC + 256;
constexpr int OAB1 = OASH + 256;
constexpr int OABT = OAB1 + 256;           // [64]

// ---- workspace byte offsets (28 MiB total) ----
constexpr size_t OFFB_WF   = 0;
constexpr size_t OFFB_IDX  = (size_t)2 << 20;
constexpr size_t OFFB_Q    = (size_t)4 << 20;   // [b][n][64]
constexpr size_t OFFB_K    = (size_t)8 << 20;   // [b][n][64]
constexpr size_t OFFB_U    = (size_t)12 << 20;  // [b][n][64]
constexpr size_t OFFB_V    = (size_t)16 << 20;  // [b][n][64]
constexpr size_t OFFB_IDEN = (size_t)20 << 20;  // [b][n][128]

struct InPtrs { const float* p[38]; };

// ---- f16 pair helpers: v_dot2_f32_f16 (full-rate 2xFMA, f32 accumulate) ----
typedef _Float16 half2_t __attribute__((ext_vector_type(2)));

__device__ __forceinline__ float fdot2_(half2_t a, half2_t b, float c) {
  return __builtin_amdgcn_fdot2(a, b, c, false);
}
__device__ __forceinline__ unsigned pkh2(float a, float b) {
  union { unsigned u; half2_t h; } x;
  x.h = half2_t{(_Float16)a, (_Float16)b};
  return x.u;
}
__device__ __forceinline__ half2_t h2u(unsigned u) {
  union { unsigned u; half2_t h; } x;
  x.u = u;
  return x.h;
}

// ------------------------------------------------------------------
// Weight prep: transposes + BN folds (f32) + f16 packs for attn P4/P5
// ------------------------------------------------------------------
__global__ __launch_bounds__(256) void k_prep(InPtrs in, float* __restrict__ wf) {
  const int tid = blockIdx.x * 256 + threadIdx.x;
  const int nth = gridDim.x * 256;
  const float *mv_w1 = in.p[4], *mv_b1 = in.p[5], *mv_w2 = in.p[6], *mv_b2 = in.p[7],
              *mv_ws = in.p[8], *mv_bs = in.p[9], *wk = in.p[10], *bk = in.p[11],
              *wq = in.p[12], *bq = in.p[13], *wv = in.p[14], *bv = in.p[15],
              *wu = in.p[16], *bu = in.p[17], *pm_w1 = in.p[18], *pm_b1 = in.p[19],
              *pm_g = in.p[20], *pm_be = in.p[21], *pm_m = in.p[22], *pm_v = in.p[23],
              *pm_w2 = in.p[24], *pm_b2 = in.p[25], *am_w1 = in.p[26], *am_b1 = in.p[27],
              *am_g = in.p[28], *am_be = in.p[29], *am_m = in.p[30], *am_v = in.p[31],
              *am_wt = in.p[32], *am_bt = in.p[33], *we = in.p[34], *be = in.p[35],
              *wr = in.p[36], *br = in.p[37];

  for (int i = tid; i < 512 * 256; i += nth) { int c = i >> 8, m = i & 255; wf[OW1T + i] = mv_w1[m * 512 + c]; }
  for (int i = tid; i < 512 * 256; i += nth) { int c = i >> 8, m = i & 255; wf[OWST + i] = mv_ws[m * 512 + c]; }
  for (int i = tid; i < 256 * 256; i += nth) { int c = i >> 8, m = i & 255; wf[OW2T + i] = mv_w2[m * 256 + c]; }
  for (int i = tid; i < 256 * 64; i += nth) { int c = i >> 6, m = i & 63; wf[OWQT + i] = wq[m * 256 + c]; }
  for (int i = tid; i < 256 * 64; i += nth) { int c = i >> 6, m = i & 63; wf[OWKT + i] = wk[m * 256 + c]; }
  for (int i = tid; i < 256 * 64; i += nth) { int c = i >> 6, m = i & 63; wf[OWVT + i] = wv[m * 256 + c]; }
  for (int i = tid; i < 256 * 64; i += nth) { int c = i >> 6, m = i & 63; wf[OWUT + i] = wu[m * 256 + c]; }
  for (int i = tid; i < 256 * 128; i += nth) { int c = i >> 7, m = i & 127; wf[OWRT + i] = wr[m * 256 + c]; }
  for (int i = tid; i < 64 * 128; i += nth) { int o = i >> 7, co = i & 127; wf[OWET + i] = we[co * 64 + o]; }
  // wtp[c4][or][j]: half2 over channel pair (c, c+1) with c = 4*c4 + 2*j.
  // Index i = (c4*128 + or)*2 + j so that a uint4 load at ((2cq)*128+or0)*2
  // yields {c2=4cq@or0, c2=4cq+1@or0, c2=4cq@or0+1, c2=4cq+1@or0+1}.
  {
    unsigned* wtp = (unsigned*)(wf + OWTC);
    for (int i = tid; i < 64 * 128 * 2; i += nth) {
      int j = i & 1, orr = (i >> 1) & 127, c4 = i >> 8;
      int c = 4 * c4 + 2 * j;
      wtp[i] = pkh2(am_wt[c * 128 + orr], am_wt[(c + 1) * 128 + orr]);
    }
  }
  // aw1p[o2][c]: half2 over o-pair (2*o2, 2*o2+1) of am_w1^T
  {
    unsigned* aw1p = (unsigned*)(wf + OAW1);
    for (int i = tid; i < 32 * 256; i += nth) {
      int c = i & 255, o2 = i >> 8;
      aw1p[i] = pkh2(am_w1[c * 64 + 2 * o2], am_w1[c * 64 + 2 * o2 + 1]);
    }
  }
  for (int i = tid; i < 192; i += nth) wf[OPW1 + i] = pm_w1[i];
  for (int i = tid; i < 4096; i += nth) wf[OPW2 + i] = pm_w2[i];
  for (int i = tid; i < 256; i += nth) {
    wf[OB1 + i] = mv_b1[i];
    wf[OBS2 + i] = mv_bs[i] + mv_b2[i];
    float sc = am_g[i] / sqrtf(am_v[i] + EPS_);
    wf[OASC + i] = sc;
    wf[OASH + i] = am_be[i] - am_m[i] * sc;
    wf[OAB1 + i] = am_b1[i];
  }
  for (int i = tid; i < 64; i += nth) {
    wf[OBQ + i] = bq[i]; wf[OBK + i] = bk[i];
    wf[OBV + i] = bv[i]; wf[OBU + i] = bu[i];
    wf[OABT + i] = am_bt[i]; wf[OPB1 + i] = pm_b1[i]; wf[OPB2 + i] = pm_b2[i];
    float sc = pm_g[i] / sqrtf(pm_v[i] + EPS_);
    wf[OPSC + i] = sc;
    wf[OPSH + i] = pm_be[i] - pm_m[i] * sc;
  }
  for (int i = tid; i < 128; i += nth) { wf[OBR + i] = br[i]; wf[OBE + i] = be[i]; }
}

// ------------------------------------------------------------------
// Fused mv-MLP + v/iden projections. Outputs transposed: [b][n][ch].
// ------------------------------------------------------------------
__global__ __launch_bounds__(256) void k_mv(const float* __restrict__ wf,
                                            const float* __restrict__ keyf,
                                            const float* __restrict__ qryf,
                                            float* __restrict__ vout,
                                            float* __restrict__ idenout) {
  const int b = blockIdx.y;
  const int n0 = blockIdx.x * 16;
  __shared__ float hidL[256][16];
  __shared__ float valL[256][16];
  __shared__ float wsL[16][64];
  __shared__ float xsL[16][16];
  const int tid = threadIdx.x;
  const int tn = tid & 15, tm = tid >> 4;

  for (int ms = 0; ms < 4; ++ms) {
    float acc[4] = {};
    for (int kt = 0; kt < 512; kt += 16) {
      for (int i = tid; i < 1024; i += 256) {
        int kk = i >> 6, col = i & 63;
        wsL[kk][col] = wf[OW1T + (size_t)(kt + kk) * 256 + ms * 64 + col];
      }
      {
        int kk = tid >> 4, col = tid & 15;
        int c = kt + kk;
        const float* s = (c < 256) ? keyf : qryf;
        xsL[kk][col] = s[((size_t)b * 256 + (c & 255)) * N_ + n0 + col];
      }
      __syncthreads();
#pragma unroll
      for (int kk = 0; kk < 16; ++kk) {
        float x = xsL[kk][tn];
        float4 w4 = *(const float4*)&wsL[kk][tm * 4];
        acc[0] += w4.x * x; acc[1] += w4.y * x; acc[2] += w4.z * x; acc[3] += w4.w * x;
      }
      __syncthreads();
    }
#pragma unroll
    for (int i = 0; i < 4; ++i)
      hidL[ms * 64 + tm * 4 + i][tn] = fmaxf(acc[i] + wf[OB1 + ms * 64 + tm * 4 + i], 0.f);
  }
  __syncthreads();

  for (int ms = 0; ms < 4; ++ms) {
    float acc[4] = {};
    for (int kt = 0; kt < 512; kt += 16) {
      for (int i = tid; i < 1024; i += 256) {
        int kk = i >> 6, col = i & 63;
        wsL[kk][col] = wf[OWST + (size_t)(kt + kk) * 256 + ms * 64 + col];
      }
      {
        int kk = tid >> 4, col = tid & 15;
        int c = kt + kk;
        const float* s = (c < 256) ? keyf : qryf;
        xsL[kk][col] = s[((size_t)b * 256 + (c & 255)) * N_ + n0 + col];
      }
      __syncthreads();
#pragma unroll
      for (int kk = 0; kk < 16; ++kk) {
        float x = xsL[kk][tn];
        float4 w4 = *(const float4*)&wsL[kk][tm * 4];
        acc[0] += w4.x * x; acc[1] += w4.y * x; acc[2] += w4.z * x; acc[3] += w4.w * x;
      }
      __syncthreads();
    }
    for (int kt = 0; kt < 256; kt += 16) {
      for (int i = tid; i < 1024; i += 256) {
        int kk = i >> 6, col = i & 63;
        wsL[kk][col] = wf[OW2T + (size_t)(kt + kk) * 256 + ms * 64 + col];
      }
      __syncthreads();
#pragma unroll
      for (int kk = 0; kk < 16; ++kk) {
        float x = hidL[kt + kk][tn];
        float4 w4 = *(const float4*)&wsL[kk][tm * 4];
        acc[0] += w4.x * x; acc[1] += w4.y * x; acc[2] += w4.z * x; acc[3] += w4.w * x;
      }
      __syncthreads();
    }
#pragma unroll
    for (int i = 0; i < 4; ++i)
      valL[ms * 64 + tm * 4 + i][tn] = acc[i] + wf[OBS2 + ms * 64 + tm * 4 + i];
  }
  __syncthreads();

  {
    float acc[4] = {};
    for (int kt = 0; kt < 256; kt += 16) {
      for (int i = tid; i < 1024; i += 256) {
        int kk = i >> 6, col = i & 63;
        wsL[kk][col] = wf[OWVT + (size_t)(kt + kk) * 64 + col];
      }
      __syncthreads();
#pragma unroll
      for (int kk = 0; kk < 16; ++kk) {
        float x = valL[kt + kk][tn];
        float4 w4 = *(const float4*)&wsL[kk][tm * 4];
        acc[0] += w4.x * x; acc[1] += w4.y * x; acc[2] += w4.z * x; acc[3] += w4.w * x;
      }
      __syncthreads();
    }
    *(float4*)(vout + ((size_t)b * N_ + n0 + tn) * 64 + tm * 4) =
        make_float4(acc[0] + wf[OBV + tm * 4], acc[1] + wf[OBV + tm * 4 + 1],
                    acc[2] + wf[OBV + tm * 4 + 2], acc[3] + wf[OBV + tm * 4 + 3]);
  }
  for (int ms = 0; ms < 2; ++ms) {
    float acc[4] = {};
    for (int kt = 0; kt < 256; kt += 16) {
      for (int i = tid; i < 1024; i += 256) {
        int kk = i >> 6, col = i & 63;
        wsL[kk][col] = wf[OWRT + (size_t)(kt + kk) * 128 + ms * 64 + col];
      }
      __syncthreads();
#pragma unroll
      for (int kk = 0; kk < 16; ++kk) {
        float x = valL[kt + kk][tn];
        float4 w4 = *(const float4*)&wsL[kk][tm * 4];
        acc[0] += w4.x * x; acc[1] += w4.y * x; acc[2] += w4.z * x; acc[3] += w4.w * x;
      }
      __syncthreads();
    }
    int m = ms * 64 + tm * 4;
    *(float4*)(idenout + ((size_t)b * N_ + n0 + tn) * 128 + m) =
        make_float4(acc[0] + wf[OBR + m], acc[1] + wf[OBR + m + 1],
                    acc[2] + wf[OBR + m + 2], acc[3] + wf[OBR + m + 3]);
  }
}

// ------------------------------------------------------------------
// q/k/u projections, one launch; outputs transposed [b][n][64].
// ------------------------------------------------------------------
struct Gx { const float* x0; const float* x1; const float* x2;
            float* o0; float* o1; float* o2; };

__global__ __launch_bounds__(256) void k_gemm64x3(const float* __restrict__ wf, Gx g) {
  const int b = blockIdx.z;
  const int n0 = blockIdx.x * 64;
  const int y = blockIdx.y;
  const int wsel = (y == 2) ? 3 : y;
  const float* Wt = wf + OWQT + wsel * (256 * 64);
  const float* bias = wf + OBQ + wsel * 64;
  const float* x = (y == 0) ? g.x0 : (y == 1) ? g.x1 : g.x2;
  float* out = (y == 0) ? g.o0 : (y == 1) ? g.o1 : g.o2;
  __shared__ float ws_[16][64];
  __shared__ float xs_[16][64];
  const int tid = threadIdx.x, tm = tid & 15, tn = tid >> 4;
  float acc[4][4] = {};
  for (int kt = 0; kt < 256; kt += 16) {
    for (int i = tid; i < 1024; i += 256) {
      int kk = i >> 6, col = i & 63;
      ws_[kk][col] = Wt[(size_t)(kt + kk) * 64 + col];
      xs_[kk][col] = x[((size_t)b * 256 + kt + kk) * N_ + n0 + col];
    }
    __syncthreads();
#pragma unroll
    for (int kk = 0; kk < 16; ++kk) {
      float4 x4 = *(const float4*)&xs_[kk][tn * 4];
      float4 w4 = *(const float4*)&ws_[kk][tm * 4];
      float wv[4] = {w4.x, w4.y, w4.z, w4.w};
      float xv[4] = {x4.x, x4.y, x4.z, x4.w};
#pragma unroll
      for (int i = 0; i < 4; ++i)
#pragma unroll
        for (int j = 0; j < 4; ++j) acc[i][j] += wv[i] * xv[j];
    }
    __syncthreads();
  }
#pragma unroll
  for (int j = 0; j < 4; ++j) {
    *(float4*)(out + ((size_t)b * N_ + n0 + tn * 4 + j) * 64 + tm * 4) =
        make_float4(acc[0][j] + bias[tm * 4], acc[1][j] + bias[tm * 4 + 1],
                    acc[2][j] + bias[tm * 4 + 2], acc[3][j] + bias[tm * 4 + 3]);
  }
}

// ------------------------------------------------------------------
// Self-KNN, register-resident, 1 barrier per round.
// NOTE: the neighbor-kill uses a statically-unrolled index compare —
// a dynamic d2[mi>>8] write forces d2[] into scratch (HBM) and was
// costing ~850 us/launch.
// ------------------------------------------------------------------
__global__ __launch_bounds__(256, 4) void k_knn(const float* __restrict__ pos,
                                                int* __restrict__ idxout) {
  const int b = blockIdx.x >> 11, n = blockIdx.x & 2047;
  __shared__ double redd[2][4];
  __shared__ int redi[2][4];
  const int tid = threadIdx.x;
  const float* pb = pos + (size_t)b * 3 * N_;
  const double xq = pb[n], yq = pb[N_ + n], zq = pb[2 * N_ + n];
  const double sq = xq * xq + yq * yq + zq * zq;
  double d2[8];
#pragma unroll
  for (int s = 0; s < 8; ++s) {
    int i = tid + s * 256;
    double x = pb[i], y = pb[N_ + i], z = pb[2 * N_ + i];
    double psq = x * x + y * y + z * z;
    double dot = xq * x + yq * y + zq * z;
    d2[s] = (sq + psq) - 2.0 * dot;
  }
  const int lane = tid & 63, wv = tid >> 6;
  for (int r = 0; r < K_; ++r) {
    double bd = d2[0];
    int bi = tid;
#pragma unroll
    for (int s = 1; s < 8; ++s)
      if (d2[s] < bd) { bd = d2[s]; bi = tid + s * 256; }
#pragma unroll
    for (int off = 32; off; off >>= 1) {
      double od = __shfl_down(bd, off);
      int oi = __shfl_down(bi, off);
      if (od < bd || (od == bd && oi < bi)) { bd = od; bi = oi; }
    }
    int ph = r & 1;
    if (lane == 0) { redd[ph][wv] = bd; redi[ph][wv] = bi; }
    __syncthreads();
    double md = redd[ph][0];
    int mi = redi[ph][0];
#pragma unroll
    for (int w = 1; w < 4; ++w)
      if (redd[ph][w] < md || (redd[ph][w] == md && redi[ph][w] < mi)) { md = redd[ph][w]; mi = redi[ph][w]; }
    if (tid == 0) idxout[((size_t)b * N_ + n) * K_ + r] = mi;
    // static-index kill: keeps d2[] in VGPRs (no scratch)
#pragma unroll
    for (int s = 0; s < 8; ++s)
      if (mi == tid + s * 256) d2[s] = __builtin_inf();
  }
}

// ------------------------------------------------------------------
// Fused attention tail v4: P4/P5 in packed-f16 v_dot2_f32_f16
// (halves the dominant FMA instruction streams + halves am_w1/wt L2
// traffic), S/V carried in registers P1->P3 (sS f32 buffer deleted),
// lg overlaid on dead t1s+sS_h. 26.9 KB LDS -> 6 blocks/CU.
// ------------------------------------------------------------------
__global__ __launch_bounds__(256, 6) void k_attn(
    const float* __restrict__ wf,
    const float* __restrict__ qb, const float* __restrict__ kb,
    const float* __restrict__ vb, const float* __restrict__ ub,
    const float* __restrict__ idenb, const int* __restrict__ idxb,
    const float* __restrict__ pos, float* __restrict__ out) {
  const int b = blockIdx.x >> 11, n = blockIdx.x & 2047;
  const int tid = threadIdx.x;
  // LDS map (floats). Liveness-based overlays:
  //   [0..1280)    t1s  [20][64]   P2->P3
  //   [1300..1980) sS_h [20][34]u  P3->P4 (packed half2 S, o-pairs)
  //   [0..2580)    lg   [20][129]  P5->P6 (overlays t1s+sS_h, both dead)
  //   [2580..3880) sVal [20][65]   P3->P6
  //   [3880..6520) sHs  [20][132]u P4->P5 (packed half2 h, c-pairs)
  //   [6520..6648) aggs [128]      P6->P7
  //   [6648..6728) idxs[20] + prx/pry/prz[20]
  __shared__ __align__(16) float smem[6728];
  float*    lg   = smem;
  float*    t1s  = smem;
  unsigned* sS_h = (unsigned*)(smem + 1300);
  float*    sVal = smem + 2580;
  unsigned* sHs  = (unsigned*)(smem + 3880);
  float*    aggs = smem + 6520;
  int*      idxs = (int*)(smem + 6648);
  float*    prx  = smem + 6668;
  float*    pry  = smem + 6688;
  float*    prz  = smem + 6708;

  if (tid < 20) idxs[tid] = idxb[((size_t)b * N_ + n) * K_ + tid] & 2047;
  __syncthreads();

  const int o64 = tid & 63, kslot = tid >> 6, kk0 = kslot * 5;

  // P1: coalesced gathers ([b][n][64] layouts); S and V stay in registers
  float sreg[5], vreg[5];
  {
    size_t rowq = ((size_t)b * N_ + n) * 64;
    float qvo = qb[rowq + o64];
    float ufo = ub[rowq + o64];
#pragma unroll
    for (int t = 0; t < 5; ++t) {
      int kk = kk0 + t;
      int j = idxs[kk];
      size_t rowj = ((size_t)b * N_ + j) * 64;
      float kvv = kb[rowj + o64], vvv = vb[rowj + o64], uvv = ub[rowj + o64];
      float ur = ufo - uvv;
      sreg[t] = (qvo - kvv) + ur;
      vreg[t] = vvv + ur;
    }
    if (tid < 20) {
      int j = idxs[tid];
      const float* pp = pos + (size_t)b * 3 * N_;
      prx[tid] = pp[n] - pp[j];
      pry[tid] = pp[N_ + n] - pp[N_ + j];
      prz[tid] = pp[2 * N_ + n] - pp[2 * N_ + j];
    }
  }
  __syncthreads();

  // P2: pos-MLP layer1 + BN + relu -> t1s[kk][ph]
  {
    int ph = o64;
    float w0 = wf[OPW1 + ph * 3], w1 = wf[OPW1 + ph * 3 + 1], w2 = wf[OPW1 + ph * 3 + 2];
    float pb1 = wf[OPB1 + ph], sc = wf[OPSC + ph], sh = wf[OPSH + ph];
#pragma unroll
    for (int t = 0; t < 5; ++t) {
      int kk = kk0 + t;
      float u = pb1 + w0 * prx[kk] + w1 * pry[kk] + w2 * prz[kk];
      t1s[kk * 64 + ph] = fmaxf(u * sc + sh, 0.f);
    }
  }
  __syncthreads();

  // P3: pos-MLP layer2 in registers; write sVal (f32) + sS_h (packed f16,
  // lane pair (o64, o64^1) packed by the even lane via shfl_xor)
  {
    float pes[5];
    float pb2 = wf[OPB2 + o64];
#pragma unroll
    for (int t = 0; t < 5; ++t) pes[t] = pb2;
    const float* w = wf + OPW2 + o64 * 64;
#pragma unroll 4
    for (int c4 = 0; c4 < 16; ++c4) {
      float4 w4 = *(const float4*)(w + c4 * 4);
#pragma unroll
      for (int t = 0; t < 5; ++t) {
        float4 tv = *(const float4*)(t1s + (kk0 + t) * 64 + c4 * 4);
        pes[t] += w4.x * tv.x + w4.y * tv.y + w4.z * tv.z + w4.w * tv.w;
      }
    }
#pragma unroll
    for (int t = 0; t < 5; ++t) {
      float sv = sreg[t] + pes[t];
      float vv = vreg[t] + pes[t];
      sVal[(kk0 + t) * 65 + o64] = vv;
      float so = __shfl_xor(sv, 1);
      if ((o64 & 1) == 0) sS_h[(kk0 + t) * 34 + (o64 >> 1)] = pkh2(sv, so);
    }
  }
  __syncthreads();

  // P4: h = relu(bn(am_w1 @ s)) via fdot2; 640 dot2 vs 1280 FMA before.
  // Output packed half2 (c-pairs) into sHs.
  {
    const int cg = tid >> 2, kg = tid & 3;
    float acc[4][5];
#pragma unroll
    for (int i = 0; i < 4; ++i)
#pragma unroll
      for (int t = 0; t < 5; ++t) acc[i][t] = 0.f;
    const unsigned* w = (const unsigned*)(wf + OAW1) + cg * 4;
#pragma unroll 4
    for (int o4 = 0; o4 < 16; ++o4) {
      uint2 s2[5];
#pragma unroll
      for (int t = 0; t < 5; ++t)
        s2[t] = *(const uint2*)(sS_h + (kg * 5 + t) * 34 + 2 * o4);
      uint4 wlo = *(const uint4*)(w + (2 * o4) * 256);
      uint4 whi = *(const uint4*)(w + (2 * o4 + 1) * 256);
      const unsigned wl[4] = {wlo.x, wlo.y, wlo.z, wlo.w};
      const unsigned wh[4] = {whi.x, whi.y, whi.z, whi.w};
#pragma unroll
      for (int t = 0; t < 5; ++t) {
        half2_t slo = h2u(s2[t].x), shi = h2u(s2[t].y);
#pragma unroll
        for (int i = 0; i < 4; ++i) {
          acc[i][t] = fdot2_(slo, h2u(wl[i]), acc[i][t]);
          acc[i][t] = fdot2_(shi, h2u(wh[i]), acc[i][t]);
        }
      }
    }
    float4 b4 = *(const float4*)(wf + OAB1 + cg * 4);
    float4 s4 = *(const float4*)(wf + OASC + cg * 4);
    float4 h4 = *(const float4*)(wf + OASH + cg * 4);
    const float bb[4] = {b4.x, b4.y, b4.z, b4.w};
    const float ss[4] = {s4.x, s4.y, s4.z, s4.w};
    const float hh[4] = {h4.x, h4.y, h4.z, h4.w};
#pragma unroll
    for (int t = 0; t < 5; ++t) {
      float hv[4];
#pragma unroll
      for (int i = 0; i < 4; ++i)
        hv[i] = fmaxf((acc[i][t] + bb[i]) * ss[i] + hh[i], 0.f);
      uint2 p;
      p.x = pkh2(hv[0], hv[1]);
      p.y = pkh2(hv[2], hv[3]);
      *(uint2*)(sHs + (kg * 5 + t) * 132 + cg * 2) = p;
    }
  }
  __syncthreads();

  // P5: logits via fdot2; 1280 dot2 vs 2560 FMA before. wt is packed f16
  // (64 KB stream vs 128 KB).
  {
    const int og = tid >> 2, kg = tid & 3;
    const int or0 = og * 2;
    float acc0[5], acc1[5];
#pragma unroll
    for (int t = 0; t < 5; ++t) { acc0[t] = 0.f; acc1[t] = 0.f; }
    const unsigned* wt = (const unsigned*)(wf + OWTC) + or0 * 2;
#pragma unroll 2
    for (int cq = 0; cq < 32; ++cq) {
      uint4 hq[5];
#pragma unroll
      for (int t = 0; t < 5; ++t)
        hq[t] = *(const uint4*)(sHs + (kg * 5 + t) * 132 + cq * 4);
      uint4 wA = *(const uint4*)(wt + cq * 512);
      uint4 wB = *(const uint4*)(wt + cq * 512 + 256);
#pragma unroll
      for (int t = 0; t < 5; ++t) {
        acc0[t] = fdot2_(h2u(hq[t].x), h2u(wA.x), acc0[t]);
        acc0[t] = fdot2_(h2u(hq[t].y), h2u(wA.y), acc0[t]);
        acc0[t] = fdot2_(h2u(hq[t].z), h2u(wB.x), acc0[t]);
        acc0[t] = fdot2_(h2u(hq[t].w), h2u(wB.y), acc0[t]);
        acc1[t] = fdot2_(h2u(hq[t].x), h2u(wA.z), acc1[t]);
        acc1[t] = fdot2_(h2u(hq[t].y), h2u(wA.w), acc1[t]);
        acc1[t] = fdot2_(h2u(hq[t].z), h2u(wB.z), acc1[t]);
        acc1[t] = fdot2_(h2u(hq[t].w), h2u(wB.w), acc1[t]);
      }
    }
#pragma unroll
    for (int t = 0; t < 5; ++t) {
      lg[(kg * 5 + t) * 129 + or0] = acc0[t];
      lg[(kg * 5 + t) * 129 + or0 + 1] = acc1[t];
    }
  }
  __syncthreads();

  // P6: softmax over k + aggregate with val
  if (tid < 128) {
    int orr = tid, o = orr >> 1;
    float l[20];
#pragma unroll
    for (int kk = 0; kk < 20; ++kk) l[kk] = lg[kk * 129 + orr];
    float bt = wf[OABT + o];
    float m = -3.4e38f;
#pragma unroll
    for (int kk = 0; kk < 20; ++kk) { l[kk] += bt; m = fmaxf(m, l[kk]); }
    float s = 0.f;
#pragma unroll
    for (int kk = 0; kk < 20; ++kk) { l[kk] = expf(l[kk] - m); s += l[kk]; }
    float inv = 1.f / s;
    float a = 0.f;
#pragma unroll
    for (int kk = 0; kk < 20; ++kk) a += l[kk] * sVal[kk * 65 + o];
    aggs[orr] = a * inv;
  }
  __syncthreads();

  // P7: y = we @ agg + be + iden
  {
    int co = tid & 127, r = tid >> 7;
    float idv = idenb[((size_t)b * N_ + n) * 128 + co];
    float y = wf[OBE + co];
    const float* w = wf + OWET + co;
#pragma unroll 4
    for (int o = 0; o < 64; ++o) y += w[o * 128] * aggs[o * 2 + r];
    out[((size_t)b * 128 + co) * (size_t)(2 * N_) + 2 * n + r] = y + idv;
  }
}

extern "C" void kernel_launch(void* const* d_in, const int* in_sizes, int n_in,
                              void* d_out, int out_size, void* d_ws, size_t ws_size,
                              hipStream_t stream) {
  (void)in_sizes; (void)n_in; (void)out_size; (void)ws_size;
  InPtrs ip;
  for (int i = 0; i < 38; ++i) ip.p[i] = (const float*)d_in[i];
  char* ws = (char*)d_ws;
  float* wf    = (float*)(ws + OFFB_WF);
  int*   idxb  = (int*)(ws + OFFB_IDX);
  float* qb    = (float*)(ws + OFFB_Q);
  float* kb    = (float*)(ws + OFFB_K);
  float* ubuf  = (float*)(ws + OFFB_U);
  float* vbuf  = (float*)(ws + OFFB_V);
  float* idenb = (float*)(ws + OFFB_IDEN);

  k_prep<<<dim3(256), dim3(256), 0, stream>>>(ip, wf);
  k_mv<<<dim3(128, 8), dim3(256), 0, stream>>>(wf, ip.p[1], ip.p[2], vbuf, idenb);
  Gx g{ip.p[2], ip.p[1], ip.p[3], qb, kb, ubuf};
  k_gemm64x3<<<dim3(32, 3, 8), dim3(256), 0, stream>>>(wf, g);
  k_knn<<<dim3(B_ * N_), dim3(256), 0, stream>>>(ip.p[0], idxb);
  k_attn<<<dim3(B_ * N_), dim3(256), 0, stream>>>(wf, qb, kb, vbuf, ubuf, idenb, idxb,
                                                  ip.p[0], (float*)d_out);
}

// Round 3
// 1100.739 us; speedup vs baseline: 1.7119x; 1.4337x over previous
//
#include <hip/hip_runtime.h>
#include <hip/hip_bf16.h>

constexpr int B_ = 8, N_ = 2048, K_ = 20;
constexpr float EPS_ = 1e-5f;

// ---- weight area offsets (in float slots; "u" = uint32 holding packed half2) ----
constexpr int OW1P = 0;                    // u [256 k2][256 ch]  W1 pairs over k
constexpr int OWSP = OW1P + 256 * 256;     // u [256][256]        Ws
constexpr int OW2P = OWSP + 256 * 256;     // u [128][256]        W2
constexpr int OWVP = OW2P + 128 * 256;     // u [128][64]         wv
constexpr int OWRP = OWVP + 128 * 64;      // u [128][128]        wr
constexpr int OWQT = OWRP + 128 * 128;     // f32 [256][64] wq^T
constexpr int OWKT = OWQT + 256 * 64;      // f32 wk^T
constexpr int OWUT = OWKT + 256 * 64;      // f32 wu^T
constexpr int OWET = OWUT + 256 * 64;      // f32 [o][co] 64x128
constexpr int OWTC = OWET + 64 * 128;      // u packed am_wt (attn P5) 64*128*2
constexpr int OAW1 = OWTC + 64 * 128 * 2;  // u packed am_w1^T (attn P4) 32*256
constexpr int OPW1 = OAW1 + 32 * 256;      // pm_w1 [ph][3]
constexpr int OPW2 = OPW1 + 64 * 3;        // pm_w2 [o][c] 64x64
constexpr int OB1  = OPW2 + 64 * 64;       // mv_b1 [256]
constexpr int OBS2 = OB1 + 256;            // mv_bs + mv_b2 [256]
constexpr int OBQ  = OBS2 + 256;
constexpr int OBK  = OBQ + 64;
constexpr int OBV  = OBK + 64;
constexpr int OBU  = OBV + 64;
constexpr int OBR  = OBU + 64;             // [128]
constexpr int OBE  = OBR + 128;            // [128]
constexpr int OPB1 = OBE + 128;            // [64]
constexpr int OPSC = OPB1 + 64;
constexpr int OPSH = OPSC + 64;
constexpr int OPB2 = OPSH + 64;
constexpr int OASC = OPB2 + 64;            // [256]
constexpr int OASH = OASC + 256;
constexpr int OAB1 = OASH + 256;
constexpr int OABT = OAB1 + 256;           // [64]

// ---- workspace byte offsets (28 MiB total) ----
constexpr size_t OFFB_WF   = 0;
constexpr size_t OFFB_IDX  = (size_t)2 << 20;
constexpr size_t OFFB_Q    = (size_t)4 << 20;   // [b][n][64]
constexpr size_t OFFB_K    = (size_t)8 << 20;   // [b][n][64]
constexpr size_t OFFB_U    = (size_t)12 << 20;  // [b][n][64]
constexpr size_t OFFB_V    = (size_t)16 << 20;  // [b][n][64]
constexpr size_t OFFB_IDEN = (size_t)20 << 20;  // [b][n][128]

struct InPtrs { const float* p[38]; };

// ---- f16 pair helpers: v_dot2_f32_f16 (full-rate 2xFMA, f32 accumulate) ----
typedef _Float16 half2_t __attribute__((ext_vector_type(2)));

__device__ __forceinline__ float fdot2_(half2_t a, half2_t b, float c) {
  return __builtin_amdgcn_fdot2(a, b, c, false);
}
__device__ __forceinline__ unsigned pkh2(float a, float b) {
  union { unsigned u; half2_t h; } x;
  x.h = half2_t{(_Float16)a, (_Float16)b};
  return x.u;
}
__device__ __forceinline__ half2_t h2u(unsigned u) {
  union { unsigned u; half2_t h; } x;
  x.u = u;
  return x.h;
}

// ------------------------------------------------------------------
// Weight prep: f16 packs for mv + attn, f32 transposes, BN folds
// ------------------------------------------------------------------
__global__ __launch_bounds__(256) void k_prep(InPtrs in, float* __restrict__ wf) {
  const int tid = blockIdx.x * 256 + threadIdx.x;
  const int nth = gridDim.x * 256;
  const float *mv_w1 = in.p[4], *mv_b1 = in.p[5], *mv_w2 = in.p[6], *mv_b2 = in.p[7],
              *mv_ws = in.p[8], *mv_bs = in.p[9], *wk = in.p[10], *bk = in.p[11],
              *wq = in.p[12], *bq = in.p[13], *wv = in.p[14], *bv = in.p[15],
              *wu = in.p[16], *bu = in.p[17], *pm_w1 = in.p[18], *pm_b1 = in.p[19],
              *pm_g = in.p[20], *pm_be = in.p[21], *pm_m = in.p[22], *pm_v = in.p[23],
              *pm_w2 = in.p[24], *pm_b2 = in.p[25], *am_w1 = in.p[26], *am_b1 = in.p[27],
              *am_g = in.p[28], *am_be = in.p[29], *am_m = in.p[30], *am_v = in.p[31],
              *am_wt = in.p[32], *am_bt = in.p[33], *we = in.p[34], *be = in.p[35],
              *wr = in.p[36], *br = in.p[37];

  // mv-path packed weights: [k2][ch] = half2(W[ch][2k2], W[ch][2k2+1])
  {
    unsigned* w1p = (unsigned*)(wf + OW1P);
    for (int i = tid; i < 256 * 256; i += nth) {
      int k2 = i >> 8, ch = i & 255;
      w1p[i] = pkh2(mv_w1[ch * 512 + 2 * k2], mv_w1[ch * 512 + 2 * k2 + 1]);
    }
    unsigned* wsp = (unsigned*)(wf + OWSP);
    for (int i = tid; i < 256 * 256; i += nth) {
      int k2 = i >> 8, ch = i & 255;
      wsp[i] = pkh2(mv_ws[ch * 512 + 2 * k2], mv_ws[ch * 512 + 2 * k2 + 1]);
    }
    unsigned* w2p = (unsigned*)(wf + OW2P);
    for (int i = tid; i < 128 * 256; i += nth) {
      int k2 = i >> 8, ch = i & 255;
      w2p[i] = pkh2(mv_w2[ch * 256 + 2 * k2], mv_w2[ch * 256 + 2 * k2 + 1]);
    }
    unsigned* wvp = (unsigned*)(wf + OWVP);
    for (int i = tid; i < 128 * 64; i += nth) {
      int k2 = i >> 6, ch = i & 63;
      wvp[i] = pkh2(wv[ch * 256 + 2 * k2], wv[ch * 256 + 2 * k2 + 1]);
    }
    unsigned* wrp = (unsigned*)(wf + OWRP);
    for (int i = tid; i < 128 * 128; i += nth) {
      int k2 = i >> 7, ch = i & 127;
      wrp[i] = pkh2(wr[ch * 256 + 2 * k2], wr[ch * 256 + 2 * k2 + 1]);
    }
  }
  for (int i = tid; i < 256 * 64; i += nth) { int c = i >> 6, m = i & 63; wf[OWQT + i] = wq[m * 256 + c]; }
  for (int i = tid; i < 256 * 64; i += nth) { int c = i >> 6, m = i & 63; wf[OWKT + i] = wk[m * 256 + c]; }
  for (int i = tid; i < 256 * 64; i += nth) { int c = i >> 6, m = i & 63; wf[OWUT + i] = wu[m * 256 + c]; }
  for (int i = tid; i < 64 * 128; i += nth) { int o = i >> 7, co = i & 127; wf[OWET + i] = we[co * 64 + o]; }
  // wtp[c4][or][j]: half2 over channel pair (c, c+1) with c = 4*c4 + 2*j.
  {
    unsigned* wtp = (unsigned*)(wf + OWTC);
    for (int i = tid; i < 64 * 128 * 2; i += nth) {
      int j = i & 1, orr = (i >> 1) & 127, c4 = i >> 8;
      int c = 4 * c4 + 2 * j;
      wtp[i] = pkh2(am_wt[c * 128 + orr], am_wt[(c + 1) * 128 + orr]);
    }
  }
  // aw1p[o2][c]: half2 over o-pair (2*o2, 2*o2+1) of am_w1^T
  {
    unsigned* aw1p = (unsigned*)(wf + OAW1);
    for (int i = tid; i < 32 * 256; i += nth) {
      int c = i & 255, o2 = i >> 8;
      aw1p[i] = pkh2(am_w1[c * 64 + 2 * o2], am_w1[c * 64 + 2 * o2 + 1]);
    }
  }
  for (int i = tid; i < 192; i += nth) wf[OPW1 + i] = pm_w1[i];
  for (int i = tid; i < 4096; i += nth) wf[OPW2 + i] = pm_w2[i];
  for (int i = tid; i < 256; i += nth) {
    wf[OB1 + i] = mv_b1[i];
    wf[OBS2 + i] = mv_bs[i] + mv_b2[i];
    float sc = am_g[i] / sqrtf(am_v[i] + EPS_);
    wf[OASC + i] = sc;
    wf[OASH + i] = am_be[i] - am_m[i] * sc;
    wf[OAB1 + i] = am_b1[i];
  }
  for (int i = tid; i < 64; i += nth) {
    wf[OBQ + i] = bq[i]; wf[OBK + i] = bk[i];
    wf[OBV + i] = bv[i]; wf[OBU + i] = bu[i];
    wf[OABT + i] = am_bt[i]; wf[OPB1 + i] = pm_b1[i]; wf[OPB2 + i] = pm_b2[i];
    float sc = pm_g[i] / sqrtf(pm_v[i] + EPS_);
    wf[OPSC + i] = sc;
    wf[OPSH + i] = pm_be[i] - pm_m[i] * sc;
  }
  for (int i = tid; i < 128; i += nth) { wf[OBR + i] = br[i]; wf[OBE + i] = be[i]; }
}

// ------------------------------------------------------------------
// Fused mv-MLP + v/iden projections, v2: f16 fdot2 everywhere,
// weights global->reg (L2-resident, tm-uniform broadcast loads),
// x staged once (W1+Ws fused), hid/sc/val packed half2 in LDS.
// 32-col tiles, 4ch x 8col register blocking. 33 KB LDS.
// ------------------------------------------------------------------
__global__ __launch_bounds__(256, 2) void k_mv(const float* __restrict__ wf,
                                               const float* __restrict__ keyf,
                                               const float* __restrict__ qryf,
                                               float* __restrict__ vout,
                                               float* __restrict__ idenout) {
  const int b = blockIdx.y;
  const int n0 = blockIdx.x * 32;
  __shared__ __align__(16) unsigned hidP[128][32];  // hid ch-pairs x col
  __shared__ __align__(16) unsigned scP[128][32];   // shortcut, then val (in place)
  __shared__ __align__(16) unsigned xsP[8][32];     // x k-pairs x col (per chunk)
  const int tid = threadIdx.x;
  const int tn = tid & 3, tm = tid >> 2;
  const int col8 = tn * 8, ch4 = tm * 4;

  // ---- Phase A: acc_h = W1@x, acc_s = Ws@x fused over K=512 (256 pairs) ----
  float acch[4][8] = {};
  float accs[4][8] = {};
  {
    const unsigned* w1g = (const unsigned*)(wf + OW1P) + ch4;
    const unsigned* wsg = (const unsigned*)(wf + OWSP) + ch4;
    const int k2l = tid >> 5, cstage = tid & 31;
    for (int kt2 = 0; kt2 < 256; kt2 += 8) {
      // global x loads issued before the barrier (latency overlaps barrier wait)
      int c = 2 * (kt2 + k2l);  // even, so c and c+1 are in the same tensor
      const float* s = (c < 256) ? keyf : qryf;
      size_t base = ((size_t)b * 256 + (c & 255)) * N_ + n0 + cstage;
      float xr0 = s[base], xr1 = s[base + N_];
      __syncthreads();  // previous chunk's xsP reads complete
      xsP[k2l][cstage] = pkh2(xr0, xr1);
      __syncthreads();  // xsP ready
#pragma unroll
      for (int k2 = 0; k2 < 8; ++k2) {
        uint4 w1v = *(const uint4*)(w1g + (size_t)(kt2 + k2) * 256);
        uint4 wsv = *(const uint4*)(wsg + (size_t)(kt2 + k2) * 256);
        uint4 xa = *(const uint4*)&xsP[k2][col8];
        uint4 xb = *(const uint4*)&xsP[k2][col8 + 4];
        const unsigned xu[8] = {xa.x, xa.y, xa.z, xa.w, xb.x, xb.y, xb.z, xb.w};
        const unsigned w1u[4] = {w1v.x, w1v.y, w1v.z, w1v.w};
        const unsigned wsu[4] = {wsv.x, wsv.y, wsv.z, wsv.w};
#pragma unroll
        for (int i = 0; i < 4; ++i) {
          half2_t w1h = h2u(w1u[i]), wsh = h2u(wsu[i]);
#pragma unroll
          for (int j = 0; j < 8; ++j) {
            half2_t xh = h2u(xu[j]);
            acch[i][j] = fdot2_(xh, w1h, acch[i][j]);
            accs[i][j] = fdot2_(xh, wsh, accs[i][j]);
          }
        }
      }
    }
  }
  // epilogue A: hid = relu(acc_h + b1) packed; sc = acc_s + (bs+b2) packed
  {
    float b1v[4], bsv[4];
#pragma unroll
    for (int i = 0; i < 4; ++i) { b1v[i] = wf[OB1 + ch4 + i]; bsv[i] = wf[OBS2 + ch4 + i]; }
#pragma unroll
    for (int j = 0; j < 8; ++j) {
      hidP[tm * 2][col8 + j] =
          pkh2(fmaxf(acch[0][j] + b1v[0], 0.f), fmaxf(acch[1][j] + b1v[1], 0.f));
      hidP[tm * 2 + 1][col8 + j] =
          pkh2(fmaxf(acch[2][j] + b1v[2], 0.f), fmaxf(acch[3][j] + b1v[3], 0.f));
      scP[tm * 2][col8 + j] = pkh2(accs[0][j] + bsv[0], accs[1][j] + bsv[1]);
      scP[tm * 2 + 1][col8 + j] = pkh2(accs[2][j] + bsv[2], accs[3][j] + bsv[3]);
    }
  }
  __syncthreads();

  // ---- Phase B: val = W2@hid + sc (in-place into scP) ----
  {
    float acc2[4][8] = {};
    const unsigned* w2g = (const unsigned*)(wf + OW2P) + ch4;
#pragma unroll 4
    for (int k2 = 0; k2 < 128; ++k2) {
      uint4 w2v = *(const uint4*)(w2g + (size_t)k2 * 256);
      uint4 xa = *(const uint4*)&hidP[k2][col8];
      uint4 xb = *(const uint4*)&hidP[k2][col8 + 4];
      const unsigned xu[8] = {xa.x, xa.y, xa.z, xa.w, xb.x, xb.y, xb.z, xb.w};
      const unsigned w2u[4] = {w2v.x, w2v.y, w2v.z, w2v.w};
#pragma unroll
      for (int i = 0; i < 4; ++i) {
        half2_t wh = h2u(w2u[i]);
#pragma unroll
        for (int j = 0; j < 8; ++j)
          acc2[i][j] = fdot2_(h2u(xu[j]), wh, acc2[i][j]);
      }
    }
#pragma unroll
    for (int j = 0; j < 8; ++j) {
      half2_t s0 = h2u(scP[tm * 2][col8 + j]);
      half2_t s1 = h2u(scP[tm * 2 + 1][col8 + j]);
      scP[tm * 2][col8 + j] = pkh2(acc2[0][j] + (float)s0.x, acc2[1][j] + (float)s0.y);
      scP[tm * 2 + 1][col8 + j] = pkh2(acc2[2][j] + (float)s1.x, acc2[3][j] + (float)s1.y);
    }
  }
  __syncthreads();

  // ---- Phase C-R: iden = wr@val + br ----
  {
    const int tnR = tid & 7, tmR = tid >> 3;
    const int colR = tnR * 4, chR = tmR * 4;
    float accr[4][4] = {};
    const unsigned* wrg = (const unsigned*)(wf + OWRP) + chR;
#pragma unroll 8
    for (int k2 = 0; k2 < 128; ++k2) {
      uint4 wv4 = *(const uint4*)(wrg + (size_t)k2 * 128);
      uint4 xv = *(const uint4*)&scP[k2][colR];
      const unsigned xu[4] = {xv.x, xv.y, xv.z, xv.w};
      const unsigned wu_[4] = {wv4.x, wv4.y, wv4.z, wv4.w};
#pragma unroll
      for (int i = 0; i < 4; ++i) {
        half2_t wh = h2u(wu_[i]);
#pragma unroll
        for (int j = 0; j < 4; ++j)
          accr[i][j] = fdot2_(h2u(xu[j]), wh, accr[i][j]);
      }
    }
#pragma unroll
    for (int j = 0; j < 4; ++j) {
      *(float4*)(idenout + ((size_t)b * N_ + n0 + colR + j) * 128 + chR) =
          make_float4(accr[0][j] + wf[OBR + chR], accr[1][j] + wf[OBR + chR + 1],
                      accr[2][j] + wf[OBR + chR + 2], accr[3][j] + wf[OBR + chR + 3]);
    }
  }

  // ---- Phase C-V: v = wv@val + bv ----
  {
    const int tnV = tid & 15, tmV = tid >> 4;
    const int colV = tnV * 2, chV = tmV * 4;
    float accv[4][2] = {};
    const unsigned* wvg = (const unsigned*)(wf + OWVP) + chV;
#pragma unroll 8
    for (int k2 = 0; k2 < 128; ++k2) {
      uint4 wv4 = *(const uint4*)(wvg + (size_t)k2 * 64);
      uint2 xv = *(const uint2*)&scP[k2][colV];
      const unsigned wu_[4] = {wv4.x, wv4.y, wv4.z, wv4.w};
#pragma unroll
      for (int i = 0; i < 4; ++i) {
        half2_t wh = h2u(wu_[i]);
        accv[i][0] = fdot2_(h2u(xv.x), wh, accv[i][0]);
        accv[i][1] = fdot2_(h2u(xv.y), wh, accv[i][1]);
      }
    }
#pragma unroll
    for (int j = 0; j < 2; ++j) {
      *(float4*)(vout + ((size_t)b * N_ + n0 + colV + j) * 64 + chV) =
          make_float4(accv[0][j] + wf[OBV + chV], accv[1][j] + wf[OBV + chV + 1],
                      accv[2][j] + wf[OBV + chV + 2], accv[3][j] + wf[OBV + chV + 3]);
    }
  }
}

// ------------------------------------------------------------------
// q/k/u projections, one launch; outputs transposed [b][n][64].
// ------------------------------------------------------------------
struct Gx { const float* x0; const float* x1; const float* x2;
            float* o0; float* o1; float* o2; };

__global__ __launch_bounds__(256) void k_gemm64x3(const float* __restrict__ wf, Gx g) {
  const int b = blockIdx.z;
  const int n0 = blockIdx.x * 64;
  const int y = blockIdx.y;
  const float* Wt = wf + OWQT + y * (256 * 64);          // weights ordered q,k,u
  const float* bias = wf + OBQ + ((y == 2) ? 3 : y) * 64; // biases ordered q,k,v,u
  const float* x = (y == 0) ? g.x0 : (y == 1) ? g.x1 : g.x2;
  float* out = (y == 0) ? g.o0 : (y == 1) ? g.o1 : g.o2;
  __shared__ float ws_[16][64];
  __shared__ float xs_[16][64];
  const int tid = threadIdx.x, tm = tid & 15, tn = tid >> 4;
  float acc[4][4] = {};
  for (int kt = 0; kt < 256; kt += 16) {
    for (int i = tid; i < 1024; i += 256) {
      int kk = i >> 6, col = i & 63;
      ws_[kk][col] = Wt[(size_t)(kt + kk) * 64 + col];
      xs_[kk][col] = x[((size_t)b * 256 + kt + kk) * N_ + n0 + col];
    }
    __syncthreads();
#pragma unroll
    for (int kk = 0; kk < 16; ++kk) {
      float4 x4 = *(const float4*)&xs_[kk][tn * 4];
      float4 w4 = *(const float4*)&ws_[kk][tm * 4];
      float wv[4] = {w4.x, w4.y, w4.z, w4.w};
      float xv[4] = {x4.x, x4.y, x4.z, x4.w};
#pragma unroll
      for (int i = 0; i < 4; ++i)
#pragma unroll
        for (int j = 0; j < 4; ++j) acc[i][j] += wv[i] * xv[j];
    }
    __syncthreads();
  }
#pragma unroll
  for (int j = 0; j < 4; ++j) {
    *(float4*)(out + ((size_t)b * N_ + n0 + tn * 4 + j) * 64 + tm * 4) =
        make_float4(acc[0][j] + bias[tm * 4], acc[1][j] + bias[tm * 4 + 1],
                    acc[2][j] + bias[tm * 4 + 2], acc[3][j] + bias[tm * 4 + 3]);
  }
}

// ------------------------------------------------------------------
// Self-KNN, register-resident, 1 barrier per round.
// NOTE: the neighbor-kill uses a statically-unrolled index compare —
// a dynamic d2[mi>>8] write forces d2[] into scratch (HBM) and was
// costing ~850 us/launch.
// ------------------------------------------------------------------
__global__ __launch_bounds__(256, 4) void k_knn(const float* __restrict__ pos,
                                                int* __restrict__ idxout) {
  const int b = blockIdx.x >> 11, n = blockIdx.x & 2047;
  __shared__ double redd[2][4];
  __shared__ int redi[2][4];
  const int tid = threadIdx.x;
  const float* pb = pos + (size_t)b * 3 * N_;
  const double xq = pb[n], yq = pb[N_ + n], zq = pb[2 * N_ + n];
  const double sq = xq * xq + yq * yq + zq * zq;
  double d2[8];
#pragma unroll
  for (int s = 0; s < 8; ++s) {
    int i = tid + s * 256;
    double x = pb[i], y = pb[N_ + i], z = pb[2 * N_ + i];
    double psq = x * x + y * y + z * z;
    double dot = xq * x + yq * y + zq * z;
    d2[s] = (sq + psq) - 2.0 * dot;
  }
  const int lane = tid & 63, wv = tid >> 6;
  for (int r = 0; r < K_; ++r) {
    double bd = d2[0];
    int bi = tid;
#pragma unroll
    for (int s = 1; s < 8; ++s)
      if (d2[s] < bd) { bd = d2[s]; bi = tid + s * 256; }
#pragma unroll
    for (int off = 32; off; off >>= 1) {
      double od = __shfl_down(bd, off);
      int oi = __shfl_down(bi, off);
      if (od < bd || (od == bd && oi < bi)) { bd = od; bi = oi; }
    }
    int ph = r & 1;
    if (lane == 0) { redd[ph][wv] = bd; redi[ph][wv] = bi; }
    __syncthreads();
    double md = redd[ph][0];
    int mi = redi[ph][0];
#pragma unroll
    for (int w = 1; w < 4; ++w)
      if (redd[ph][w] < md || (redd[ph][w] == md && redi[ph][w] < mi)) { md = redd[ph][w]; mi = redi[ph][w]; }
    if (tid == 0) idxout[((size_t)b * N_ + n) * K_ + r] = mi;
    // static-index kill: keeps d2[] in VGPRs (no scratch)
#pragma unroll
    for (int s = 0; s < 8; ++s)
      if (mi == tid + s * 256) d2[s] = __builtin_inf();
  }
}

// ------------------------------------------------------------------
// Fused attention tail v4: P4/P5 in packed-f16 v_dot2_f32_f16,
// S/V carried in registers P1->P3, lg overlaid on dead t1s+sS_h.
// 26.9 KB LDS -> 6 blocks/CU.
// ------------------------------------------------------------------
__global__ __launch_bounds__(256, 6) void k_attn(
    const float* __restrict__ wf,
    const float* __restrict__ qb, const float* __restrict__ kb,
    const float* __restrict__ vb, const float* __restrict__ ub,
    const float* __restrict__ idenb, const int* __restrict__ idxb,
    const float* __restrict__ pos, float* __restrict__ out) {
  const int b = blockIdx.x >> 11, n = blockIdx.x & 2047;
  const int tid = threadIdx.x;
  // LDS map (floats). Liveness-based overlays:
  //   [0..1280)    t1s  [20][64]   P2->P3
  //   [1300..1980) sS_h [20][34]u  P3->P4 (packed half2 S, o-pairs)
  //   [0..2580)    lg   [20][129]  P5->P6 (overlays t1s+sS_h, both dead)
  //   [2580..3880) sVal [20][65]   P3->P6
  //   [3880..6520) sHs  [20][132]u P4->P5 (packed half2 h, c-pairs)
  //   [6520..6648) aggs [128]      P6->P7
  //   [6648..6728) idxs[20] + prx/pry/prz[20]
  __shared__ __align__(16) float smem[6728];
  float*    lg   = smem;
  float*    t1s  = smem;
  unsigned* sS_h = (unsigned*)(smem + 1300);
  float*    sVal = smem + 2580;
  unsigned* sHs  = (unsigned*)(smem + 3880);
  float*    aggs = smem + 6520;
  int*      idxs = (int*)(smem + 6648);
  float*    prx  = smem + 6668;
  float*    pry  = smem + 6688;
  float*    prz  = smem + 6708;

  if (tid < 20) idxs[tid] = idxb[((size_t)b * N_ + n) * K_ + tid] & 2047;
  __syncthreads();

  const int o64 = tid & 63, kslot = tid >> 6, kk0 = kslot * 5;

  // P1: coalesced gathers ([b][n][64] layouts); S and V stay in registers
  float sreg[5], vreg[5];
  {
    size_t rowq = ((size_t)b * N_ + n) * 64;
    float qvo = qb[rowq + o64];
    float ufo = ub[rowq + o64];
#pragma unroll
    for (int t = 0; t < 5; ++t) {
      int kk = kk0 + t;
      int j = idxs[kk];
      size_t rowj = ((size_t)b * N_ + j) * 64;
      float kvv = kb[rowj + o64], vvv = vb[rowj + o64], uvv = ub[rowj + o64];
      float ur = ufo - uvv;
      sreg[t] = (qvo - kvv) + ur;
      vreg[t] = vvv + ur;
    }
    if (tid < 20) {
      int j = idxs[tid];
      const float* pp = pos + (size_t)b * 3 * N_;
      prx[tid] = pp[n] - pp[j];
      pry[tid] = pp[N_ + n] - pp[N_ + j];
      prz[tid] = pp[2 * N_ + n] - pp[2 * N_ + j];
    }
  }
  __syncthreads();

  // P2: pos-MLP layer1 + BN + relu -> t1s[kk][ph]
  {
    int ph = o64;
    float w0 = wf[OPW1 + ph * 3], w1 = wf[OPW1 + ph * 3 + 1], w2 = wf[OPW1 + ph * 3 + 2];
    float pb1 = wf[OPB1 + ph], sc = wf[OPSC + ph], sh = wf[OPSH + ph];
#pragma unroll
    for (int t = 0; t < 5; ++t) {
      int kk = kk0 + t;
      float u = pb1 + w0 * prx[kk] + w1 * pry[kk] + w2 * prz[kk];
      t1s[kk * 64 + ph] = fmaxf(u * sc + sh, 0.f);
    }
  }
  __syncthreads();

  // P3: pos-MLP layer2 in registers; write sVal (f32) + sS_h (packed f16,
  // lane pair (o64, o64^1) packed by the even lane via shfl_xor)
  {
    float pes[5];
    float pb2 = wf[OPB2 + o64];
#pragma unroll
    for (int t = 0; t < 5; ++t) pes[t] = pb2;
    const float* w = wf + OPW2 + o64 * 64;
#pragma unroll 4
    for (int c4 = 0; c4 < 16; ++c4) {
      float4 w4 = *(const float4*)(w + c4 * 4);
#pragma unroll
      for (int t = 0; t < 5; ++t) {
        float4 tv = *(const float4*)(t1s + (kk0 + t) * 64 + c4 * 4);
        pes[t] += w4.x * tv.x + w4.y * tv.y + w4.z * tv.z + w4.w * tv.w;
      }
    }
#pragma unroll
    for (int t = 0; t < 5; ++t) {
      float sv = sreg[t] + pes[t];
      float vv = vreg[t] + pes[t];
      sVal[(kk0 + t) * 65 + o64] = vv;
      float so = __shfl_xor(sv, 1);
      if ((o64 & 1) == 0) sS_h[(kk0 + t) * 34 + (o64 >> 1)] = pkh2(sv, so);
    }
  }
  __syncthreads();

  // P4: h = relu(bn(am_w1 @ s)) via fdot2
  {
    const int cg = tid >> 2, kg = tid & 3;
    float acc[4][5];
#pragma unroll
    for (int i = 0; i < 4; ++i)
#pragma unroll
      for (int t = 0; t < 5; ++t) acc[i][t] = 0.f;
    const unsigned* w = (const unsigned*)(wf + OAW1) + cg * 4;
#pragma unroll 4
    for (int o4 = 0; o4 < 16; ++o4) {
      uint2 s2[5];
#pragma unroll
      for (int t = 0; t < 5; ++t)
        s2[t] = *(const uint2*)(sS_h + (kg * 5 + t) * 34 + 2 * o4);
      uint4 wlo = *(const uint4*)(w + (2 * o4) * 256);
      uint4 whi = *(const uint4*)(w + (2 * o4 + 1) * 256);
      const unsigned wl[4] = {wlo.x, wlo.y, wlo.z, wlo.w};
      const unsigned wh[4] = {whi.x, whi.y, whi.z, whi.w};
#pragma unroll
      for (int t = 0; t < 5; ++t) {
        half2_t slo = h2u(s2[t].x), shi = h2u(s2[t].y);
#pragma unroll
        for (int i = 0; i < 4; ++i) {
          acc[i][t] = fdot2_(slo, h2u(wl[i]), acc[i][t]);
          acc[i][t] = fdot2_(shi, h2u(wh[i]), acc[i][t]);
        }
      }
    }
    float4 b4 = *(const float4*)(wf + OAB1 + cg * 4);
    float4 s4 = *(const float4*)(wf + OASC + cg * 4);
    float4 h4 = *(const float4*)(wf + OASH + cg * 4);
    const float bb[4] = {b4.x, b4.y, b4.z, b4.w};
    const float ss[4] = {s4.x, s4.y, s4.z, s4.w};
    const float hh[4] = {h4.x, h4.y, h4.z, h4.w};
#pragma unroll
    for (int t = 0; t < 5; ++t) {
      float hv[4];
#pragma unroll
      for (int i = 0; i < 4; ++i)
        hv[i] = fmaxf((acc[i][t] + bb[i]) * ss[i] + hh[i], 0.f);
      uint2 p;
      p.x = pkh2(hv[0], hv[1]);
      p.y = pkh2(hv[2], hv[3]);
      *(uint2*)(sHs + (kg * 5 + t) * 132 + cg * 2) = p;
    }
  }
  __syncthreads();

  // P5: logits via fdot2; wt packed f16
  {
    const int og = tid >> 2, kg = tid & 3;
    const int or0 = og * 2;
    float acc0[5], acc1[5];
#pragma unroll
    for (int t = 0; t < 5; ++t) { acc0[t] = 0.f; acc1[t] = 0.f; }
    const unsigned* wt = (const unsigned*)(wf + OWTC) + or0 * 2;
#pragma unroll 2
    for (int cq = 0; cq < 32; ++cq) {
      uint4 hq[5];
#pragma unroll
      for (int t = 0; t < 5; ++t)
        hq[t] = *(const uint4*)(sHs + (kg * 5 + t) * 132 + cq * 4);
      uint4 wA = *(const uint4*)(wt + cq * 512);
      uint4 wB = *(const uint4*)(wt + cq * 512 + 256);
#pragma unroll
      for (int t = 0; t < 5; ++t) {
        acc0[t] = fdot2_(h2u(hq[t].x), h2u(wA.x), acc0[t]);
        acc0[t] = fdot2_(h2u(hq[t].y), h2u(wA.y), acc0[t]);
        acc0[t] = fdot2_(h2u(hq[t].z), h2u(wB.x), acc0[t]);
        acc0[t] = fdot2_(h2u(hq[t].w), h2u(wB.y), acc0[t]);
        acc1[t] = fdot2_(h2u(hq[t].x), h2u(wA.z), acc1[t]);
        acc1[t] = fdot2_(h2u(hq[t].y), h2u(wA.w), acc1[t]);
        acc1[t] = fdot2_(h2u(hq[t].z), h2u(wB.z), acc1[t]);
        acc1[t] = fdot2_(h2u(hq[t].w), h2u(wB.w), acc1[t]);
      }
    }
#pragma unroll
    for (int t = 0; t < 5; ++t) {
      lg[(kg * 5 + t) * 129 + or0] = acc0[t];
      lg[(kg * 5 + t) * 129 + or0 + 1] = acc1[t];
    }
  }
  __syncthreads();

  // P6: softmax over k + aggregate with val
  if (tid < 128) {
    int orr = tid, o = orr >> 1;
    float l[20];
#pragma unroll
    for (int kk = 0; kk < 20; ++kk) l[kk] = lg[kk * 129 + orr];
    float bt = wf[OABT + o];
    float m = -3.4e38f;
#pragma unroll
    for (int kk = 0; kk < 20; ++kk) { l[kk] += bt; m = fmaxf(m, l[kk]); }
    float s = 0.f;
#pragma unroll
    for (int kk = 0; kk < 20; ++kk) { l[kk] = expf(l[kk] - m); s += l[kk]; }
    float inv = 1.f / s;
    float a = 0.f;
#pragma unroll
    for (int kk = 0; kk < 20; ++kk) a += l[kk] * sVal[kk * 65 + o];
    aggs[orr] = a * inv;
  }
  __syncthreads();

  // P7: y = we @ agg + be + iden
  {
    int co = tid & 127, r = tid >> 7;
    float idv = idenb[((size_t)b * N_ + n) * 128 + co];
    float y = wf[OBE + co];
    const float* w = wf + OWET + co;
#pragma unroll 4
    for (int o = 0; o < 64; ++o) y += w[o * 128] * aggs[o * 2 + r];
    out[((size_t)b * 128 + co) * (size_t)(2 * N_) + 2 * n + r] = y + idv;
  }
}

extern "C" void kernel_launch(void* const* d_in, const int* in_sizes, int n_in,
                              void* d_out, int out_size, void* d_ws, size_t ws_size,
                              hipStream_t stream) {
  (void)in_sizes; (void)n_in; (void)out_size; (void)ws_size;
  InPtrs ip;
  for (int i = 0; i < 38; ++i) ip.p[i] = (const float*)d_in[i];
  char* ws = (char*)d_ws;
  float* wf    = (float*)(ws + OFFB_WF);
  int*   idxb  = (int*)(ws + OFFB_IDX);
  float* qb    = (float*)(ws + OFFB_Q);
  float* kb    = (float*)(ws + OFFB_K);
  float* ubuf  = (float*)(ws + OFFB_U);
  float* vbuf  = (float*)(ws + OFFB_V);
  float* idenb = (float*)(ws + OFFB_IDEN);

  k_prep<<<dim3(256), dim3(256), 0, stream>>>(ip, wf);
  k_mv<<<dim3(64, 8), dim3(256), 0, stream>>>(wf, ip.p[1], ip.p[2], vbuf, idenb);
  Gx g{ip.p[2], ip.p[1], ip.p[3], qb, kb, ubuf};
  k_gemm64x3<<<dim3(32, 3, 8), dim3(256), 0, stream>>>(wf, g);
  k_knn<<<dim3(B_ * N_), dim3(256), 0, stream>>>(ip.p[0], idxb);
  k_attn<<<dim3(B_ * N_), dim3(256), 0, stream>>>(wf, qb, kb, vbuf, ubuf, idenb, idxb,
                                                  ip.p[0], (float*)d_out);
}

// Round 4
// 782.829 us; speedup vs baseline: 2.4071x; 1.4061x over previous
//
#include <hip/hip_runtime.h>
#include <hip/hip_bf16.h>

constexpr int B_ = 8, N_ = 2048, K_ = 20;
constexpr float EPS_ = 1e-5f;

// ---- weight area offsets (float slots; "u" = uint32 of packed half2) ----
constexpr int OW1P = 0;                    // u [256 k2][256 ch]  W1 pairs over k
constexpr int OWSP = OW1P + 256 * 256;     // u [256][256]        Ws
constexpr int OW2P = OWSP + 256 * 256;     // u [128][256]        W2
constexpr int OWVP = OW2P + 128 * 256;     // u [128][64]         wv
constexpr int OWRP = OWVP + 128 * 64;      // u [128][128]        wr
constexpr int OWQT = OWRP + 128 * 128;     // f32 [256][64] wq^T
constexpr int OWKT = OWQT + 256 * 64;      // f32 wk^T
constexpr int OWUT = OWKT + 256 * 64;      // f32 wu^T
constexpr int OWET = OWUT + 256 * 64;      // f32 [o][co] 64x128
constexpr int OWTF = OWET + 64 * 128;      // u  wt A-frags  [mt8][ks8][l64]x4u
constexpr int OAWF = OWTF + 16384;         // u  am_w1 A-frags [mt16][ks2][l64]x4u
constexpr int OPWF = OAWF + 8192;          // u  pm_w2 A-frags [mt4][ks2][l64]x4u
constexpr int OPW1 = OPWF + 2048;          // pm_w1 [ph][3]
constexpr int OB1  = OPW1 + 192;           // mv_b1 [256]
constexpr int OBS2 = OB1 + 256;            // mv_bs + mv_b2 [256]
constexpr int OBQ  = OBS2 + 256;
constexpr int OBK  = OBQ + 64;
constexpr int OBV  = OBK + 64;
constexpr int OBU  = OBV + 64;
constexpr int OBR  = OBU + 64;             // [128]
constexpr int OBE  = OBR + 128;            // [128]
constexpr int OPB1 = OBE + 128;            // [64]
constexpr int OPSC = OPB1 + 64;
constexpr int OPSH = OPSC + 64;
constexpr int OPB2 = OPSH + 64;
constexpr int OASC = OPB2 + 64;            // [256]
constexpr int OASH = OASC + 256;
constexpr int OAB1 = OASH + 256;
constexpr int OABT = OAB1 + 256;           // [64]

// ---- workspace byte offsets (28 MiB total) ----
constexpr size_t OFFB_WF   = 0;
constexpr size_t OFFB_IDX  = (size_t)2 << 20;
constexpr size_t OFFB_Q    = (size_t)4 << 20;   // [b][n][64]
constexpr size_t OFFB_K    = (size_t)8 << 20;   // [b][n][64]
constexpr size_t OFFB_U    = (size_t)12 << 20;  // [b][n][64]
constexpr size_t OFFB_V    = (size_t)16 << 20;  // [b][n][64]
constexpr size_t OFFB_IDEN = (size_t)20 << 20;  // [b][n][128]

struct InPtrs { const float* p[38]; };

// ---- f16 helpers ----
typedef _Float16 half2_t __attribute__((ext_vector_type(2)));
typedef _Float16 f16x8_t __attribute__((ext_vector_type(8)));
typedef float    f32x4_t __attribute__((ext_vector_type(4)));

union U4H8 { uint4 u; f16x8_t h; };

__device__ __forceinline__ float fdot2_(half2_t a, half2_t b, float c) {
  return __builtin_amdgcn_fdot2(a, b, c, false);
}
__device__ __forceinline__ unsigned pkh2(float a, float b) {
  union { unsigned u; half2_t h; } x;
  x.h = half2_t{(_Float16)a, (_Float16)b};
  return x.u;
}
__device__ __forceinline__ half2_t h2u(unsigned u) {
  union { unsigned u; half2_t h; } x;
  x.u = u;
  return x.h;
}
__device__ __forceinline__ f32x4_t mfma_16x16x32(f16x8_t a, f16x8_t b, f32x4_t c) {
  return __builtin_amdgcn_mfma_f32_16x16x32_f16(a, b, c, 0, 0, 0);
}

// ------------------------------------------------------------------
// Weight prep: f16 packs for mv, MFMA A-fragment packs for attn,
// f32 transposes, BN folds.
// A-fragment order (16x16x32): lane l: row m = l&15, k = (l>>4)*8+j.
// Frag f stored as 4 consecutive u32 (8 f16).
// ------------------------------------------------------------------
__global__ __launch_bounds__(256) void k_prep(InPtrs in, float* __restrict__ wf) {
  const int tid = blockIdx.x * 256 + threadIdx.x;
  const int nth = gridDim.x * 256;
  const float *mv_w1 = in.p[4], *mv_b1 = in.p[5], *mv_w2 = in.p[6], *mv_b2 = in.p[7],
              *mv_ws = in.p[8], *mv_bs = in.p[9], *wk = in.p[10], *bk = in.p[11],
              *wq = in.p[12], *bq = in.p[13], *wv = in.p[14], *bv = in.p[15],
              *wu = in.p[16], *bu = in.p[17], *pm_w1 = in.p[18], *pm_b1 = in.p[19],
              *pm_g = in.p[20], *pm_be = in.p[21], *pm_m = in.p[22], *pm_v = in.p[23],
              *pm_w2 = in.p[24], *pm_b2 = in.p[25], *am_w1 = in.p[26], *am_b1 = in.p[27],
              *am_g = in.p[28], *am_be = in.p[29], *am_m = in.p[30], *am_v = in.p[31],
              *am_wt = in.p[32], *am_bt = in.p[33], *we = in.p[34], *be = in.p[35],
              *wr = in.p[36], *br = in.p[37];

  // mv-path packed weights: [k2][ch] = half2(W[ch][2k2], W[ch][2k2+1])
  {
    unsigned* w1p = (unsigned*)(wf + OW1P);
    for (int i = tid; i < 256 * 256; i += nth) {
      int k2 = i >> 8, ch = i & 255;
      w1p[i] = pkh2(mv_w1[ch * 512 + 2 * k2], mv_w1[ch * 512 + 2 * k2 + 1]);
    }
    unsigned* wsp = (unsigned*)(wf + OWSP);
    for (int i = tid; i < 256 * 256; i += nth) {
      int k2 = i >> 8, ch = i & 255;
      wsp[i] = pkh2(mv_ws[ch * 512 + 2 * k2], mv_ws[ch * 512 + 2 * k2 + 1]);
    }
    unsigned* w2p = (unsigned*)(wf + OW2P);
    for (int i = tid; i < 128 * 256; i += nth) {
      int k2 = i >> 8, ch = i & 255;
      w2p[i] = pkh2(mv_w2[ch * 256 + 2 * k2], mv_w2[ch * 256 + 2 * k2 + 1]);
    }
    unsigned* wvp = (unsigned*)(wf + OWVP);
    for (int i = tid; i < 128 * 64; i += nth) {
      int k2 = i >> 6, ch = i & 63;
      wvp[i] = pkh2(wv[ch * 256 + 2 * k2], wv[ch * 256 + 2 * k2 + 1]);
    }
    unsigned* wrp = (unsigned*)(wf + OWRP);
    for (int i = tid; i < 128 * 128; i += nth) {
      int k2 = i >> 7, ch = i & 127;
      wrp[i] = pkh2(wr[ch * 256 + 2 * k2], wr[ch * 256 + 2 * k2 + 1]);
    }
  }
  for (int i = tid; i < 256 * 64; i += nth) { int c = i >> 6, m = i & 63; wf[OWQT + i] = wq[m * 256 + c]; }
  for (int i = tid; i < 256 * 64; i += nth) { int c = i >> 6, m = i & 63; wf[OWKT + i] = wk[m * 256 + c]; }
  for (int i = tid; i < 256 * 64; i += nth) { int c = i >> 6, m = i & 63; wf[OWUT + i] = wu[m * 256 + c]; }
  for (int i = tid; i < 64 * 128; i += nth) { int o = i >> 7, co = i & 127; wf[OWET + i] = we[co * 64 + o]; }

  // wt A-frags: A[or(128)][c(256)], mt<8, ks<8: i = ((mt*8+ks)*64+l)*4+q
  {
    unsigned* wtf = (unsigned*)(wf + OWTF);
    for (int i = tid; i < 16384; i += nth) {
      int q = i & 3, l = (i >> 2) & 63, ks = (i >> 8) & 7, mt = i >> 11;
      int orr = mt * 16 + (l & 15);
      int c = ks * 32 + ((l >> 4) << 3) + 2 * q;
      wtf[i] = pkh2(am_wt[c * 128 + orr], am_wt[(c + 1) * 128 + orr]);
    }
  }
  // am_w1 A-frags: A[c(256)][o(64)], mt<16, ks<2: i = ((mt*2+ks)*64+l)*4+q
  {
    unsigned* awf = (unsigned*)(wf + OAWF);
    for (int i = tid; i < 8192; i += nth) {
      int q = i & 3, l = (i >> 2) & 63, ks = (i >> 8) & 1, mt = i >> 9;
      int c = mt * 16 + (l & 15);
      int o = ks * 32 + ((l >> 4) << 3) + 2 * q;
      awf[i] = pkh2(am_w1[c * 64 + o], am_w1[c * 64 + o + 1]);
    }
  }
  // pm_w2 A-frags: A[o(64)][ph(64)], mt<4, ks<2: i = ((mt*2+ks)*64+l)*4+q
  {
    unsigned* pwf = (unsigned*)(wf + OPWF);
    for (int i = tid; i < 2048; i += nth) {
      int q = i & 3, l = (i >> 2) & 63, ks = (i >> 8) & 1, mt = i >> 9;
      int o = mt * 16 + (l & 15);
      int ph = ks * 32 + ((l >> 4) << 3) + 2 * q;
      pwf[i] = pkh2(pm_w2[o * 64 + ph], pm_w2[o * 64 + ph + 1]);
    }
  }
  for (int i = tid; i < 192; i += nth) wf[OPW1 + i] = pm_w1[i];
  for (int i = tid; i < 256; i += nth) {
    wf[OB1 + i] = mv_b1[i];
    wf[OBS2 + i] = mv_bs[i] + mv_b2[i];
    float sc = am_g[i] / sqrtf(am_v[i] + EPS_);
    wf[OASC + i] = sc;
    wf[OASH + i] = am_be[i] - am_m[i] * sc;
    wf[OAB1 + i] = am_b1[i];
  }
  for (int i = tid; i < 64; i += nth) {
    wf[OBQ + i] = bq[i]; wf[OBK + i] = bk[i];
    wf[OBV + i] = bv[i]; wf[OBU + i] = bu[i];
    wf[OABT + i] = am_bt[i]; wf[OPB1 + i] = pm_b1[i]; wf[OPB2 + i] = pm_b2[i];
    float sc = pm_g[i] / sqrtf(pm_v[i] + EPS_);
    wf[OPSC + i] = sc;
    wf[OPSH + i] = pm_be[i] - pm_m[i] * sc;
  }
  for (int i = tid; i < 128; i += nth) { wf[OBR + i] = br[i]; wf[OBE + i] = be[i]; }
}

// ------------------------------------------------------------------
// Fused mv-MLP + v/iden projections (unchanged from r3 pass).
// ------------------------------------------------------------------
__global__ __launch_bounds__(256, 2) void k_mv(const float* __restrict__ wf,
                                               const float* __restrict__ keyf,
                                               const float* __restrict__ qryf,
                                               float* __restrict__ vout,
                                               float* __restrict__ idenout) {
  const int b = blockIdx.y;
  const int n0 = blockIdx.x * 32;
  __shared__ __align__(16) unsigned hidP[128][32];
  __shared__ __align__(16) unsigned scP[128][32];
  __shared__ __align__(16) unsigned xsP[8][32];
  const int tid = threadIdx.x;
  const int tn = tid & 3, tm = tid >> 2;
  const int col8 = tn * 8, ch4 = tm * 4;

  float acch[4][8] = {};
  float accs[4][8] = {};
  {
    const unsigned* w1g = (const unsigned*)(wf + OW1P) + ch4;
    const unsigned* wsg = (const unsigned*)(wf + OWSP) + ch4;
    const int k2l = tid >> 5, cstage = tid & 31;
    for (int kt2 = 0; kt2 < 256; kt2 += 8) {
      int c = 2 * (kt2 + k2l);
      const float* s = (c < 256) ? keyf : qryf;
      size_t base = ((size_t)b * 256 + (c & 255)) * N_ + n0 + cstage;
      float xr0 = s[base], xr1 = s[base + N_];
      __syncthreads();
      xsP[k2l][cstage] = pkh2(xr0, xr1);
      __syncthreads();
#pragma unroll
      for (int k2 = 0; k2 < 8; ++k2) {
        uint4 w1v = *(const uint4*)(w1g + (size_t)(kt2 + k2) * 256);
        uint4 wsv = *(const uint4*)(wsg + (size_t)(kt2 + k2) * 256);
        uint4 xa = *(const uint4*)&xsP[k2][col8];
        uint4 xb = *(const uint4*)&xsP[k2][col8 + 4];
        const unsigned xu[8] = {xa.x, xa.y, xa.z, xa.w, xb.x, xb.y, xb.z, xb.w};
        const unsigned w1u[4] = {w1v.x, w1v.y, w1v.z, w1v.w};
        const unsigned wsu[4] = {wsv.x, wsv.y, wsv.z, wsv.w};
#pragma unroll
        for (int i = 0; i < 4; ++i) {
          half2_t w1h = h2u(w1u[i]), wsh = h2u(wsu[i]);
#pragma unroll
          for (int j = 0; j < 8; ++j) {
            half2_t xh = h2u(xu[j]);
            acch[i][j] = fdot2_(xh, w1h, acch[i][j]);
            accs[i][j] = fdot2_(xh, wsh, accs[i][j]);
          }
        }
      }
    }
  }
  {
    float b1v[4], bsv[4];
#pragma unroll
    for (int i = 0; i < 4; ++i) { b1v[i] = wf[OB1 + ch4 + i]; bsv[i] = wf[OBS2 + ch4 + i]; }
#pragma unroll
    for (int j = 0; j < 8; ++j) {
      hidP[tm * 2][col8 + j] =
          pkh2(fmaxf(acch[0][j] + b1v[0], 0.f), fmaxf(acch[1][j] + b1v[1], 0.f));
      hidP[tm * 2 + 1][col8 + j] =
          pkh2(fmaxf(acch[2][j] + b1v[2], 0.f), fmaxf(acch[3][j] + b1v[3], 0.f));
      scP[tm * 2][col8 + j] = pkh2(accs[0][j] + bsv[0], accs[1][j] + bsv[1]);
      scP[tm * 2 + 1][col8 + j] = pkh2(accs[2][j] + bsv[2], accs[3][j] + bsv[3]);
    }
  }
  __syncthreads();

  {
    float acc2[4][8] = {};
    const unsigned* w2g = (const unsigned*)(wf + OW2P) + ch4;
#pragma unroll 4
    for (int k2 = 0; k2 < 128; ++k2) {
      uint4 w2v = *(const uint4*)(w2g + (size_t)k2 * 256);
      uint4 xa = *(const uint4*)&hidP[k2][col8];
      uint4 xb = *(const uint4*)&hidP[k2][col8 + 4];
      const unsigned xu[8] = {xa.x, xa.y, xa.z, xa.w, xb.x, xb.y, xb.z, xb.w};
      const unsigned w2u[4] = {w2v.x, w2v.y, w2v.z, w2v.w};
#pragma unroll
      for (int i = 0; i < 4; ++i) {
        half2_t wh = h2u(w2u[i]);
#pragma unroll
        for (int j = 0; j < 8; ++j)
          acc2[i][j] = fdot2_(h2u(xu[j]), wh, acc2[i][j]);
      }
    }
#pragma unroll
    for (int j = 0; j < 8; ++j) {
      half2_t s0 = h2u(scP[tm * 2][col8 + j]);
      half2_t s1 = h2u(scP[tm * 2 + 1][col8 + j]);
      scP[tm * 2][col8 + j] = pkh2(acc2[0][j] + (float)s0.x, acc2[1][j] + (float)s0.y);
      scP[tm * 2 + 1][col8 + j] = pkh2(acc2[2][j] + (float)s1.x, acc2[3][j] + (float)s1.y);
    }
  }
  __syncthreads();

  {
    const int tnR = tid & 7, tmR = tid >> 3;
    const int colR = tnR * 4, chR = tmR * 4;
    float accr[4][4] = {};
    const unsigned* wrg = (const unsigned*)(wf + OWRP) + chR;
#pragma unroll 8
    for (int k2 = 0; k2 < 128; ++k2) {
      uint4 wv4 = *(const uint4*)(wrg + (size_t)k2 * 128);
      uint4 xv = *(const uint4*)&scP[k2][colR];
      const unsigned xu[4] = {xv.x, xv.y, xv.z, xv.w};
      const unsigned wu_[4] = {wv4.x, wv4.y, wv4.z, wv4.w};
#pragma unroll
      for (int i = 0; i < 4; ++i) {
        half2_t wh = h2u(wu_[i]);
#pragma unroll
        for (int j = 0; j < 4; ++j)
          accr[i][j] = fdot2_(h2u(xu[j]), wh, accr[i][j]);
      }
    }
#pragma unroll
    for (int j = 0; j < 4; ++j) {
      *(float4*)(idenout + ((size_t)b * N_ + n0 + colR + j) * 128 + chR) =
          make_float4(accr[0][j] + wf[OBR + chR], accr[1][j] + wf[OBR + chR + 1],
                      accr[2][j] + wf[OBR + chR + 2], accr[3][j] + wf[OBR + chR + 3]);
    }
  }

  {
    const int tnV = tid & 15, tmV = tid >> 4;
    const int colV = tnV * 2, chV = tmV * 4;
    float accv[4][2] = {};
    const unsigned* wvg = (const unsigned*)(wf + OWVP) + chV;
#pragma unroll 8
    for (int k2 = 0; k2 < 128; ++k2) {
      uint4 wv4 = *(const uint4*)(wvg + (size_t)k2 * 64);
      uint2 xv = *(const uint2*)&scP[k2][colV];
      const unsigned wu_[4] = {wv4.x, wv4.y, wv4.z, wv4.w};
#pragma unroll
      for (int i = 0; i < 4; ++i) {
        half2_t wh = h2u(wu_[i]);
        accv[i][0] = fdot2_(h2u(xv.x), wh, accv[i][0]);
        accv[i][1] = fdot2_(h2u(xv.y), wh, accv[i][1]);
      }
    }
#pragma unroll
    for (int j = 0; j < 2; ++j) {
      *(float4*)(vout + ((size_t)b * N_ + n0 + colV + j) * 64 + chV) =
          make_float4(accv[0][j] + wf[OBV + chV], accv[1][j] + wf[OBV + chV + 1],
                      accv[2][j] + wf[OBV + chV + 2], accv[3][j] + wf[OBV + chV + 3]);
    }
  }
}

// ------------------------------------------------------------------
// q/k/u projections (unchanged).
// ------------------------------------------------------------------
struct Gx { const float* x0; const float* x1; const float* x2;
            float* o0; float* o1; float* o2; };

__global__ __launch_bounds__(256) void k_gemm64x3(const float* __restrict__ wf, Gx g) {
  const int b = blockIdx.z;
  const int n0 = blockIdx.x * 64;
  const int y = blockIdx.y;
  const float* Wt = wf + OWQT + y * (256 * 64);
  const float* bias = wf + OBQ + ((y == 2) ? 3 : y) * 64;
  const float* x = (y == 0) ? g.x0 : (y == 1) ? g.x1 : g.x2;
  float* out = (y == 0) ? g.o0 : (y == 1) ? g.o1 : g.o2;
  __shared__ float ws_[16][64];
  __shared__ float xs_[16][64];
  const int tid = threadIdx.x, tm = tid & 15, tn = tid >> 4;
  float acc[4][4] = {};
  for (int kt = 0; kt < 256; kt += 16) {
    for (int i = tid; i < 1024; i += 256) {
      int kk = i >> 6, col = i & 63;
      ws_[kk][col] = Wt[(size_t)(kt + kk) * 64 + col];
      xs_[kk][col] = x[((size_t)b * 256 + kt + kk) * N_ + n0 + col];
    }
    __syncthreads();
#pragma unroll
    for (int kk = 0; kk < 16; ++kk) {
      float4 x4 = *(const float4*)&xs_[kk][tn * 4];
      float4 w4 = *(const float4*)&ws_[kk][tm * 4];
      float wv[4] = {w4.x, w4.y, w4.z, w4.w};
      float xv[4] = {x4.x, x4.y, x4.z, x4.w};
#pragma unroll
      for (int i = 0; i < 4; ++i)
#pragma unroll
        for (int j = 0; j < 4; ++j) acc[i][j] += wv[i] * xv[j];
    }
    __syncthreads();
  }
#pragma unroll
  for (int j = 0; j < 4; ++j) {
    *(float4*)(out + ((size_t)b * N_ + n0 + tn * 4 + j) * 64 + tm * 4) =
        make_float4(acc[0][j] + bias[tm * 4], acc[1][j] + bias[tm * 4 + 1],
                    acc[2][j] + bias[tm * 4 + 2], acc[3][j] + bias[tm * 4 + 3]);
  }
}

// ------------------------------------------------------------------
// Self-KNN (unchanged).
// ------------------------------------------------------------------
__global__ __launch_bounds__(256, 4) void k_knn(const float* __restrict__ pos,
                                                int* __restrict__ idxout) {
  const int b = blockIdx.x >> 11, n = blockIdx.x & 2047;
  __shared__ double redd[2][4];
  __shared__ int redi[2][4];
  const int tid = threadIdx.x;
  const float* pb = pos + (size_t)b * 3 * N_;
  const double xq = pb[n], yq = pb[N_ + n], zq = pb[2 * N_ + n];
  const double sq = xq * xq + yq * yq + zq * zq;
  double d2[8];
#pragma unroll
  for (int s = 0; s < 8; ++s) {
    int i = tid + s * 256;
    double x = pb[i], y = pb[N_ + i], z = pb[2 * N_ + i];
    double psq = x * x + y * y + z * z;
    double dot = xq * x + yq * y + zq * z;
    d2[s] = (sq + psq) - 2.0 * dot;
  }
  const int lane = tid & 63, wv = tid >> 6;
  for (int r = 0; r < K_; ++r) {
    double bd = d2[0];
    int bi = tid;
#pragma unroll
    for (int s = 1; s < 8; ++s)
      if (d2[s] < bd) { bd = d2[s]; bi = tid + s * 256; }
#pragma unroll
    for (int off = 32; off; off >>= 1) {
      double od = __shfl_down(bd, off);
      int oi = __shfl_down(bi, off);
      if (od < bd || (od == bd && oi < bi)) { bd = od; bi = oi; }
    }
    int ph = r & 1;
    if (lane == 0) { redd[ph][wv] = bd; redi[ph][wv] = bi; }
    __syncthreads();
    double md = redd[ph][0];
    int mi = redi[ph][0];
#pragma unroll
    for (int w = 1; w < 4; ++w)
      if (redd[ph][w] < md || (redd[ph][w] == md && redi[ph][w] < mi)) { md = redd[ph][w]; mi = redi[ph][w]; }
    if (tid == 0) idxout[((size_t)b * N_ + n) * K_ + r] = mi;
#pragma unroll
    for (int s = 0; s < 8; ++s)
      if (mi == tid + s * 256) d2[s] = __builtin_inf();
  }
}

// ------------------------------------------------------------------
// Fused attention tail v5: P3/P4/P5 on MFMA (16x16x32 f16).
// B-operands (t1/S/h) in LDS as [N=k][K] f16 rows, XOR-swizzled
// (^(row&7)<<4) for conflict-free ds_read_b128. A-operands prepacked
// in fragment order (coalesced 16B/lane global loads). k>=20 columns
// are garbage and masked at stores. XCD swizzle: batch per XCD.
// 25.9 KB LDS.
// ------------------------------------------------------------------
__global__ __launch_bounds__(256, 4) void k_attn(
    const float* __restrict__ wf,
    const float* __restrict__ qb, const float* __restrict__ kb,
    const float* __restrict__ vb, const float* __restrict__ ub,
    const float* __restrict__ idenb, const int* __restrict__ idxb,
    const float* __restrict__ pos, float* __restrict__ out) {
  const int lb = ((int)blockIdx.x & 7) * 2048 + ((int)blockIdx.x >> 3);
  const int b = lb >> 11, n = lb & 2047;
  const int tid = threadIdx.x;
  const int lane = tid & 63, wid = tid >> 6;

  // LDS (bytes):
  //  [0,4096)      S_lds  f16[32][64] swz      (P3b -> P4)
  //  [4096,20480)  h_lds  f16[32][256] swz     (P4 -> P5)
  //    overlays: t1 f16[32][64] swz @4096 (P2->P3a)
  //              pe f32[20][64] swz @8192 (P3a->P3b)
  //              lg f32[20][129]    @4096 (P5epi->P6)
  //  [20480,25680) sVal f32[20][65]            (P3b -> P6)
  //  [25680,26192) aggs f32[128]               (P6 -> P7)
  //  [26192,26512) idxs[20], prx/pry/prz[20]
  __shared__ __align__(16) char smem[26512];
  char*  Sb   = smem;
  char*  hb   = smem + 4096;
  char*  t1b  = smem + 4096;
  char*  peb  = smem + 8192;
  float* lg   = (float*)(smem + 4096);
  float* sVal = (float*)(smem + 20480);
  float* aggs = (float*)(smem + 25680);
  int*   idxs = (int*)(smem + 26192);
  float* prx  = (float*)(smem + 26272);
  float* pry  = (float*)(smem + 26352);
  float* prz  = (float*)(smem + 26432);

  if (tid < 20) idxs[tid] = idxb[((size_t)b * N_ + n) * K_ + tid] & 2047;
  __syncthreads();

  // P1: coalesced gathers; S and V stay in registers until P3b
  float sreg[5], vreg[5];
  {
    size_t rowq = ((size_t)b * N_ + n) * 64;
    float qvo = qb[rowq + lane];
    float ufo = ub[rowq + lane];
#pragma unroll
    for (int t = 0; t < 5; ++t) {
      int kk = wid * 5 + t;
      int j = idxs[kk];
      size_t rowj = ((size_t)b * N_ + j) * 64;
      float kvv = kb[rowj + lane], vvv = vb[rowj + lane], uvv = ub[rowj + lane];
      float ur = ufo - uvv;
      sreg[t] = (qvo - kvv) + ur;
      vreg[t] = vvv + ur;
    }
    if (tid < 20) {
      int j = idxs[tid];
      const float* pp = pos + (size_t)b * 3 * N_;
      prx[tid] = pp[n] - pp[j];
      pry[tid] = pp[N_ + n] - pp[N_ + j];
      prz[tid] = pp[2 * N_ + n] - pp[2 * N_ + j];
    }
  }
  __syncthreads();

  // P2: pos-MLP layer1 + BN + relu -> t1 f16 [k][ph] swz
  {
    int ph = lane;
    float w0 = wf[OPW1 + ph * 3], w1 = wf[OPW1 + ph * 3 + 1], w2 = wf[OPW1 + ph * 3 + 2];
    float pb1 = wf[OPB1 + ph], sc = wf[OPSC + ph], sh = wf[OPSH + ph];
#pragma unroll
    for (int t = 0; t < 5; ++t) {
      int kk = wid * 5 + t;
      float u = pb1 + w0 * prx[kk] + w1 * pry[kk] + w2 * prz[kk];
      float tv = fmaxf(u * sc + sh, 0.f);
      *(_Float16*)(t1b + ((kk * 128 + ph * 2) ^ ((kk & 7) << 4))) = (_Float16)tv;
    }
  }
  __syncthreads();

  // P3a: pe = pm_w2 @ t1 via MFMA (M=64: mt=wid), write pe f32 [k][o] swz
  {
    f32x4_t pacc[2];
#pragma unroll
    for (int nt = 0; nt < 2; ++nt) pacc[nt] = f32x4_t{0.f, 0.f, 0.f, 0.f};
    const int mt = wid;
#pragma unroll
    for (int ks = 0; ks < 2; ++ks) {
      U4H8 a;
      a.u = ((const uint4*)((const unsigned*)(wf + OPWF)))[(mt * 2 + ks) * 64 + lane];
#pragma unroll
      for (int nt = 0; nt < 2; ++nt) {
        int kc = nt * 16 + (lane & 15);
        U4H8 bu;
        bu.u = *(const uint4*)(t1b + ((kc * 128 + (ks * 32 + ((lane >> 4) << 3)) * 2) ^ ((kc & 7) << 4)));
        pacc[nt] = mfma_16x16x32(a.h, bu.h, pacc[nt]);
      }
    }
    const int o0 = mt * 16 + ((lane >> 4) << 2);
    float4 pb2v = *(const float4*)(wf + OPB2 + o0);
#pragma unroll
    for (int nt = 0; nt < 2; ++nt) {
      int kc = nt * 16 + (lane & 15);
      if (kc < 20) {
        float4 o;
        o.x = pacc[nt][0] + pb2v.x; o.y = pacc[nt][1] + pb2v.y;
        o.z = pacc[nt][2] + pb2v.z; o.w = pacc[nt][3] + pb2v.w;
        *(float4*)(peb + ((kc * 256 + o0 * 4) ^ ((kc & 7) << 4))) = o;
      }
    }
  }
  __syncthreads();

  // P3b: fold pe into S (f16 [k][o] swz) and sVal (f32)
  {
#pragma unroll
    for (int t = 0; t < 5; ++t) {
      int kk = wid * 5 + t;
      float pe = *(const float*)(peb + ((kk * 256 + lane * 4) ^ ((kk & 7) << 4)));
      float sv = sreg[t] + pe;
      float vv = vreg[t] + pe;
      sVal[kk * 65 + lane] = vv;
      *(_Float16*)(Sb + ((kk * 128 + lane * 2) ^ ((kk & 7) << 4))) = (_Float16)sv;
    }
  }
  __syncthreads();

  // P4: h = relu(bn(am_w1 @ S)) via MFMA (M=256: 4 mt/wave, 2 passes)
#pragma unroll
  for (int pass = 0; pass < 2; ++pass) {
    const int mt0 = wid * 4 + pass * 2;
    f32x4_t acc[2][2];
#pragma unroll
    for (int m = 0; m < 2; ++m)
#pragma unroll
      for (int nt = 0; nt < 2; ++nt) acc[m][nt] = f32x4_t{0.f, 0.f, 0.f, 0.f};
#pragma unroll
    for (int ks = 0; ks < 2; ++ks) {
      U4H8 bfr[2];
#pragma unroll
      for (int nt = 0; nt < 2; ++nt) {
        int kc = nt * 16 + (lane & 15);
        bfr[nt].u = *(const uint4*)(Sb + ((kc * 128 + (ks * 32 + ((lane >> 4) << 3)) * 2) ^ ((kc & 7) << 4)));
      }
#pragma unroll
      for (int m = 0; m < 2; ++m) {
        U4H8 a;
        a.u = ((const uint4*)((const unsigned*)(wf + OAWF)))[((mt0 + m) * 2 + ks) * 64 + lane];
#pragma unroll
        for (int nt = 0; nt < 2; ++nt)
          acc[m][nt] = mfma_16x16x32(a.h, bfr[nt].h, acc[m][nt]);
      }
    }
#pragma unroll
    for (int m = 0; m < 2; ++m) {
      const int c0 = (mt0 + m) * 16 + ((lane >> 4) << 2);
      float4 ab1 = *(const float4*)(wf + OAB1 + c0);
      float4 asc = *(const float4*)(wf + OASC + c0);
      float4 ash = *(const float4*)(wf + OASH + c0);
#pragma unroll
      for (int nt = 0; nt < 2; ++nt) {
        int kc = nt * 16 + (lane & 15);
        if (kc < 20) {
          float h0 = fmaxf((acc[m][nt][0] + ab1.x) * asc.x + ash.x, 0.f);
          float h1 = fmaxf((acc[m][nt][1] + ab1.y) * asc.y + ash.y, 0.f);
          float h2 = fmaxf((acc[m][nt][2] + ab1.z) * asc.z + ash.z, 0.f);
          float h3 = fmaxf((acc[m][nt][3] + ab1.w) * asc.w + ash.w, 0.f);
          uint2 p;
          p.x = pkh2(h0, h1);
          p.y = pkh2(h2, h3);
          *(uint2*)(hb + ((kc * 512 + c0 * 2) ^ ((kc & 7) << 4))) = p;
        }
      }
    }
  }
  __syncthreads();

  // P5: lg = wt @ h via MFMA (M=128: 2 mt/wave, K=256: 8 ks)
  {
    f32x4_t acc5[2][2];
#pragma unroll
    for (int m = 0; m < 2; ++m)
#pragma unroll
      for (int nt = 0; nt < 2; ++nt) acc5[m][nt] = f32x4_t{0.f, 0.f, 0.f, 0.f};
#pragma unroll
    for (int ks = 0; ks < 8; ++ks) {
      U4H8 bfr[2];
#pragma unroll
      for (int nt = 0; nt < 2; ++nt) {
        int kc = nt * 16 + (lane & 15);
        bfr[nt].u = *(const uint4*)(hb + ((kc * 512 + (ks * 32 + ((lane >> 4) << 3)) * 2) ^ ((kc & 7) << 4)));
      }
#pragma unroll
      for (int m = 0; m < 2; ++m) {
        U4H8 a;
        a.u = ((const uint4*)((const unsigned*)(wf + OWTF)))[((wid * 2 + m) * 8 + ks) * 64 + lane];
#pragma unroll
        for (int nt = 0; nt < 2; ++nt)
          acc5[m][nt] = mfma_16x16x32(a.h, bfr[nt].h, acc5[m][nt]);
      }
    }
    __syncthreads();  // all h reads done before lg overlays the region
#pragma unroll
    for (int m = 0; m < 2; ++m) {
      const int or0 = (wid * 2 + m) * 16 + ((lane >> 4) << 2);
#pragma unroll
      for (int nt = 0; nt < 2; ++nt) {
        int kc = nt * 16 + (lane & 15);
        if (kc < 20) {
#pragma unroll
          for (int r = 0; r < 4; ++r) lg[kc * 129 + or0 + r] = acc5[m][nt][r];
        }
      }
    }
  }
  __syncthreads();

  // P6: softmax over k + aggregate with val
  if (tid < 128) {
    int orr = tid, o = orr >> 1;
    float l[20];
#pragma unroll
    for (int kk = 0; kk < 20; ++kk) l[kk] = lg[kk * 129 + orr];
    float bt = wf[OABT + o];
    float m = -3.4e38f;
#pragma unroll
    for (int kk = 0; kk < 20; ++kk) { l[kk] += bt; m = fmaxf(m, l[kk]); }
    float s = 0.f;
#pragma unroll
    for (int kk = 0; kk < 20; ++kk) { l[kk] = expf(l[kk] - m); s += l[kk]; }
    float inv = 1.f / s;
    float a = 0.f;
#pragma unroll
    for (int kk = 0; kk < 20; ++kk) a += l[kk] * sVal[kk * 65 + o];
    aggs[orr] = a * inv;
  }
  __syncthreads();

  // P7: y = we @ agg + be + iden
  {
    int co = tid & 127, r = tid >> 7;
    float idv = idenb[((size_t)b * N_ + n) * 128 + co];
    float y = wf[OBE + co];
    const float* w = wf + OWET + co;
#pragma unroll 4
    for (int o = 0; o < 64; ++o) y += w[o * 128] * aggs[o * 2 + r];
    out[((size_t)b * 128 + co) * (size_t)(2 * N_) + 2 * n + r] = y + idv;
  }
}

extern "C" void kernel_launch(void* const* d_in, const int* in_sizes, int n_in,
                              void* d_out, int out_size, void* d_ws, size_t ws_size,
                              hipStream_t stream) {
  (void)in_sizes; (void)n_in; (void)out_size; (void)ws_size;
  InPtrs ip;
  for (int i = 0; i < 38; ++i) ip.p[i] = (const float*)d_in[i];
  char* ws = (char*)d_ws;
  float* wf    = (float*)(ws + OFFB_WF);
  int*   idxb  = (int*)(ws + OFFB_IDX);
  float* qb    = (float*)(ws + OFFB_Q);
  float* kb    = (float*)(ws + OFFB_K);
  float* ubuf  = (float*)(ws + OFFB_U);
  float* vbuf  = (float*)(ws + OFFB_V);
  float* idenb = (float*)(ws + OFFB_IDEN);

  k_prep<<<dim3(256), dim3(256), 0, stream>>>(ip, wf);
  k_mv<<<dim3(64, 8), dim3(256), 0, stream>>>(wf, ip.p[1], ip.p[2], vbuf, idenb);
  Gx g{ip.p[2], ip.p[1], ip.p[3], qb, kb, ubuf};
  k_gemm64x3<<<dim3(32, 3, 8), dim3(256), 0, stream>>>(wf, g);
  k_knn<<<dim3(B_ * N_), dim3(256), 0, stream>>>(ip.p[0], idxb);
  k_attn<<<dim3(B_ * N_), dim3(256), 0, stream>>>(wf, qb, kb, vbuf, ubuf, idenb, idxb,
                                                  ip.p[0], (float*)d_out);
}

// Round 6
// 680.494 us; speedup vs baseline: 2.7690x; 1.1504x over previous
//
#include <hip/hip_runtime.h>
#include <hip/hip_bf16.h>

constexpr int B_ = 8, N_ = 2048, K_ = 20;
constexpr float EPS_ = 1e-5f;

// ---- weight area offsets (float slots; "u" = uint32 of packed half2) ----
constexpr int OW1P = 0;                    // u [256 k2][256 ch]  W1 pairs over k
constexpr int OWSP = OW1P + 256 * 256;     // u [256][256]        Ws
constexpr int OW2P = OWSP + 256 * 256;     // u [128][256]        W2
constexpr int OWVP = OW2P + 128 * 256;     // u [128][64]         wv
constexpr int OWRP = OWVP + 128 * 64;      // u [128][128]        wr
constexpr int OWQT = OWRP + 128 * 128;     // f32 [256][64] wq^T
constexpr int OWKT = OWQT + 256 * 64;      // f32 wk^T
constexpr int OWUT = OWKT + 256 * 64;      // f32 wu^T
constexpr int OWET = OWUT + 256 * 64;      // f32 [o][co] 64x128
constexpr int OWTF = OWET + 64 * 128;      // u  wt A-frags  [mt8][ks8][l64]x4u
constexpr int OAWF = OWTF + 16384;         // u  am_w1 A-frags [mt16][ks2][l64]x4u
constexpr int OPWF = OAWF + 8192;          // u  pm_w2 A-frags [mt4][ks2][l64]x4u
constexpr int OPW1 = OPWF + 2048;          // pm_w1 [ph][3]
constexpr int OB1  = OPW1 + 192;           // mv_b1 [256]
constexpr int OBS2 = OB1 + 256;            // mv_bs + mv_b2 [256]
constexpr int OBQ  = OBS2 + 256;
constexpr int OBK  = OBQ + 64;
constexpr int OBV  = OBK + 64;
constexpr int OBU  = OBV + 64;
constexpr int OBR  = OBU + 64;             // [128]
constexpr int OBE  = OBR + 128;            // [128]
constexpr int OPB1 = OBE + 128;            // [64]
constexpr int OPSC = OPB1 + 64;
constexpr int OPSH = OPSC + 64;
constexpr int OPB2 = OPSH + 64;
constexpr int OASC = OPB2 + 64;            // [256]
constexpr int OASH = OASC + 256;
constexpr int OAB1 = OASH + 256;
constexpr int OABT = OAB1 + 256;           // [64]

// ---- workspace byte offsets (28 MiB total) ----
constexpr size_t OFFB_WF   = 0;
constexpr size_t OFFB_IDX  = (size_t)2 << 20;
constexpr size_t OFFB_Q    = (size_t)4 << 20;   // [b][n][64]
constexpr size_t OFFB_K    = (size_t)8 << 20;   // [b][n][64]
constexpr size_t OFFB_U    = (size_t)12 << 20;  // [b][n][64]
constexpr size_t OFFB_V    = (size_t)16 << 20;  // [b][n][64]
constexpr size_t OFFB_IDEN = (size_t)20 << 20;  // [b][n][128]

struct InPtrs { const float* p[38]; };

// ---- f16 helpers ----
typedef _Float16 half2_t __attribute__((ext_vector_type(2)));
typedef _Float16 f16x8_t __attribute__((ext_vector_type(8)));
typedef float    f32x4_t __attribute__((ext_vector_type(4)));

union U4H8 { uint4 u; f16x8_t h; };

__device__ __forceinline__ float fdot2_(half2_t a, half2_t b, float c) {
  return __builtin_amdgcn_fdot2(a, b, c, false);
}
__device__ __forceinline__ unsigned pkh2(float a, float b) {
  union { unsigned u; half2_t h; } x;
  x.h = half2_t{(_Float16)a, (_Float16)b};
  return x.u;
}
__device__ __forceinline__ half2_t h2u(unsigned u) {
  union { unsigned u; half2_t h; } x;
  x.u = u;
  return x.h;
}
__device__ __forceinline__ f32x4_t mfma_16x16x32(f16x8_t a, f16x8_t b, f32x4_t c) {
  return __builtin_amdgcn_mfma_f32_16x16x32_f16(a, b, c, 0, 0, 0);
}

// ------------------------------------------------------------------
// Weight prep: f16 packs for mv, MFMA A-fragment packs for attn,
// f32 transposes, BN folds.
// A-fragment order (16x16x32): lane l: row m = l&15, k = (l>>4)*8+j.
// Frag f stored as 4 consecutive u32 (8 f16).
// ------------------------------------------------------------------
__global__ __launch_bounds__(256) void k_prep(InPtrs in, float* __restrict__ wf) {
  const int tid = blockIdx.x * 256 + threadIdx.x;
  const int nth = gridDim.x * 256;
  const float *mv_w1 = in.p[4], *mv_b1 = in.p[5], *mv_w2 = in.p[6], *mv_b2 = in.p[7],
              *mv_ws = in.p[8], *mv_bs = in.p[9], *wk = in.p[10], *bk = in.p[11],
              *wq = in.p[12], *bq = in.p[13], *wv = in.p[14], *bv = in.p[15],
              *wu = in.p[16], *bu = in.p[17], *pm_w1 = in.p[18], *pm_b1 = in.p[19],
              *pm_g = in.p[20], *pm_be = in.p[21], *pm_m = in.p[22], *pm_v = in.p[23],
              *pm_w2 = in.p[24], *pm_b2 = in.p[25], *am_w1 = in.p[26], *am_b1 = in.p[27],
              *am_g = in.p[28], *am_be = in.p[29], *am_m = in.p[30], *am_v = in.p[31],
              *am_wt = in.p[32], *am_bt = in.p[33], *we = in.p[34], *be = in.p[35],
              *wr = in.p[36], *br = in.p[37];

  // mv-path packed weights: [k2][ch] = half2(W[ch][2k2], W[ch][2k2+1])
  {
    unsigned* w1p = (unsigned*)(wf + OW1P);
    for (int i = tid; i < 256 * 256; i += nth) {
      int k2 = i >> 8, ch = i & 255;
      w1p[i] = pkh2(mv_w1[ch * 512 + 2 * k2], mv_w1[ch * 512 + 2 * k2 + 1]);
    }
    unsigned* wsp = (unsigned*)(wf + OWSP);
    for (int i = tid; i < 256 * 256; i += nth) {
      int k2 = i >> 8, ch = i & 255;
      wsp[i] = pkh2(mv_ws[ch * 512 + 2 * k2], mv_ws[ch * 512 + 2 * k2 + 1]);
    }
    unsigned* w2p = (unsigned*)(wf + OW2P);
    for (int i = tid; i < 128 * 256; i += nth) {
      int k2 = i >> 8, ch = i & 255;
      w2p[i] = pkh2(mv_w2[ch * 256 + 2 * k2], mv_w2[ch * 256 + 2 * k2 + 1]);
    }
    unsigned* wvp = (unsigned*)(wf + OWVP);
    for (int i = tid; i < 128 * 64; i += nth) {
      int k2 = i >> 6, ch = i & 63;
      wvp[i] = pkh2(wv[ch * 256 + 2 * k2], wv[ch * 256 + 2 * k2 + 1]);
    }
    unsigned* wrp = (unsigned*)(wf + OWRP);
    for (int i = tid; i < 128 * 128; i += nth) {
      int k2 = i >> 7, ch = i & 127;
      wrp[i] = pkh2(wr[ch * 256 + 2 * k2], wr[ch * 256 + 2 * k2 + 1]);
    }
  }
  for (int i = tid; i < 256 * 64; i += nth) { int c = i >> 6, m = i & 63; wf[OWQT + i] = wq[m * 256 + c]; }
  for (int i = tid; i < 256 * 64; i += nth) { int c = i >> 6, m = i & 63; wf[OWKT + i] = wk[m * 256 + c]; }
  for (int i = tid; i < 256 * 64; i += nth) { int c = i >> 6, m = i & 63; wf[OWUT + i] = wu[m * 256 + c]; }
  for (int i = tid; i < 64 * 128; i += nth) { int o = i >> 7, co = i & 127; wf[OWET + i] = we[co * 64 + o]; }

  // wt A-frags: A[or(128)][c(256)], mt<8, ks<8: i = ((mt*8+ks)*64+l)*4+q
  {
    unsigned* wtf = (unsigned*)(wf + OWTF);
    for (int i = tid; i < 16384; i += nth) {
      int q = i & 3, l = (i >> 2) & 63, ks = (i >> 8) & 7, mt = i >> 11;
      int orr = mt * 16 + (l & 15);
      int c = ks * 32 + ((l >> 4) << 3) + 2 * q;
      wtf[i] = pkh2(am_wt[c * 128 + orr], am_wt[(c + 1) * 128 + orr]);
    }
  }
  // am_w1 A-frags: A[c(256)][o(64)], mt<16, ks<2: i = ((mt*2+ks)*64+l)*4+q
  {
    unsigned* awf = (unsigned*)(wf + OAWF);
    for (int i = tid; i < 8192; i += nth) {
      int q = i & 3, l = (i >> 2) & 63, ks = (i >> 8) & 1, mt = i >> 9;
      int c = mt * 16 + (l & 15);
      int o = ks * 32 + ((l >> 4) << 3) + 2 * q;
      awf[i] = pkh2(am_w1[c * 64 + o], am_w1[c * 64 + o + 1]);
    }
  }
  // pm_w2 A-frags: A[o(64)][ph(64)], mt<4, ks<2: i = ((mt*2+ks)*64+l)*4+q
  {
    unsigned* pwf = (unsigned*)(wf + OPWF);
    for (int i = tid; i < 2048; i += nth) {
      int q = i & 3, l = (i >> 2) & 63, ks = (i >> 8) & 1, mt = i >> 9;
      int o = mt * 16 + (l & 15);
      int ph = ks * 32 + ((l >> 4) << 3) + 2 * q;
      pwf[i] = pkh2(pm_w2[o * 64 + ph], pm_w2[o * 64 + ph + 1]);
    }
  }
  for (int i = tid; i < 192; i += nth) wf[OPW1 + i] = pm_w1[i];
  for (int i = tid; i < 256; i += nth) {
    wf[OB1 + i] = mv_b1[i];
    wf[OBS2 + i] = mv_bs[i] + mv_b2[i];
    float sc = am_g[i] / sqrtf(am_v[i] + EPS_);
    wf[OASC + i] = sc;
    wf[OASH + i] = am_be[i] - am_m[i] * sc;
    wf[OAB1 + i] = am_b1[i];
  }
  for (int i = tid; i < 64; i += nth) {
    wf[OBQ + i] = bq[i]; wf[OBK + i] = bk[i];
    wf[OBV + i] = bv[i]; wf[OBU + i] = bu[i];
    wf[OABT + i] = am_bt[i]; wf[OPB1 + i] = pm_b1[i]; wf[OPB2 + i] = pm_b2[i];
    float sc = pm_g[i] / sqrtf(pm_v[i] + EPS_);
    wf[OPSC + i] = sc;
    wf[OPSH + i] = pm_be[i] - pm_m[i] * sc;
  }
  for (int i = tid; i < 128; i += nth) { wf[OBR + i] = br[i]; wf[OBE + i] = be[i]; }
}

// ------------------------------------------------------------------
// Fused mv-MLP + v/iden projections (unchanged).
// ------------------------------------------------------------------
__global__ __launch_bounds__(256, 2) void k_mv(const float* __restrict__ wf,
                                               const float* __restrict__ keyf,
                                               const float* __restrict__ qryf,
                                               float* __restrict__ vout,
                                               float* __restrict__ idenout) {
  const int b = blockIdx.y;
  const int n0 = blockIdx.x * 32;
  __shared__ __align__(16) unsigned hidP[128][32];
  __shared__ __align__(16) unsigned scP[128][32];
  __shared__ __align__(16) unsigned xsP[8][32];
  const int tid = threadIdx.x;
  const int tn = tid & 3, tm = tid >> 2;
  const int col8 = tn * 8, ch4 = tm * 4;

  float acch[4][8] = {};
  float accs[4][8] = {};
  {
    const unsigned* w1g = (const unsigned*)(wf + OW1P) + ch4;
    const unsigned* wsg = (const unsigned*)(wf + OWSP) + ch4;
    const int k2l = tid >> 5, cstage = tid & 31;
    for (int kt2 = 0; kt2 < 256; kt2 += 8) {
      int c = 2 * (kt2 + k2l);
      const float* s = (c < 256) ? keyf : qryf;
      size_t base = ((size_t)b * 256 + (c & 255)) * N_ + n0 + cstage;
      float xr0 = s[base], xr1 = s[base + N_];
      __syncthreads();
      xsP[k2l][cstage] = pkh2(xr0, xr1);
      __syncthreads();
#pragma unroll
      for (int k2 = 0; k2 < 8; ++k2) {
        uint4 w1v = *(const uint4*)(w1g + (size_t)(kt2 + k2) * 256);
        uint4 wsv = *(const uint4*)(wsg + (size_t)(kt2 + k2) * 256);
        uint4 xa = *(const uint4*)&xsP[k2][col8];
        uint4 xb = *(const uint4*)&xsP[k2][col8 + 4];
        const unsigned xu[8] = {xa.x, xa.y, xa.z, xa.w, xb.x, xb.y, xb.z, xb.w};
        const unsigned w1u[4] = {w1v.x, w1v.y, w1v.z, w1v.w};
        const unsigned wsu[4] = {wsv.x, wsv.y, wsv.z, wsv.w};
#pragma unroll
        for (int i = 0; i < 4; ++i) {
          half2_t w1h = h2u(w1u[i]), wsh = h2u(wsu[i]);
#pragma unroll
          for (int j = 0; j < 8; ++j) {
            half2_t xh = h2u(xu[j]);
            acch[i][j] = fdot2_(xh, w1h, acch[i][j]);
            accs[i][j] = fdot2_(xh, wsh, accs[i][j]);
          }
        }
      }
    }
  }
  {
    float b1v[4], bsv[4];
#pragma unroll
    for (int i = 0; i < 4; ++i) { b1v[i] = wf[OB1 + ch4 + i]; bsv[i] = wf[OBS2 + ch4 + i]; }
#pragma unroll
    for (int j = 0; j < 8; ++j) {
      hidP[tm * 2][col8 + j] =
          pkh2(fmaxf(acch[0][j] + b1v[0], 0.f), fmaxf(acch[1][j] + b1v[1], 0.f));
      hidP[tm * 2 + 1][col8 + j] =
          pkh2(fmaxf(acch[2][j] + b1v[2], 0.f), fmaxf(acch[3][j] + b1v[3], 0.f));
      scP[tm * 2][col8 + j] = pkh2(accs[0][j] + bsv[0], accs[1][j] + bsv[1]);
      scP[tm * 2 + 1][col8 + j] = pkh2(accs[2][j] + bsv[2], accs[3][j] + bsv[3]);
    }
  }
  __syncthreads();

  {
    float acc2[4][8] = {};
    const unsigned* w2g = (const unsigned*)(wf + OW2P) + ch4;
#pragma unroll 4
    for (int k2 = 0; k2 < 128; ++k2) {
      uint4 w2v = *(const uint4*)(w2g + (size_t)k2 * 256);
      uint4 xa = *(const uint4*)&hidP[k2][col8];
      uint4 xb = *(const uint4*)&hidP[k2][col8 + 4];
      const unsigned xu[8] = {xa.x, xa.y, xa.z, xa.w, xb.x, xb.y, xb.z, xb.w};
      const unsigned w2u[4] = {w2v.x, w2v.y, w2v.z, w2v.w};
#pragma unroll
      for (int i = 0; i < 4; ++i) {
        half2_t wh = h2u(w2u[i]);
#pragma unroll
        for (int j = 0; j < 8; ++j)
          acc2[i][j] = fdot2_(h2u(xu[j]), wh, acc2[i][j]);
      }
    }
#pragma unroll
    for (int j = 0; j < 8; ++j) {
      half2_t s0 = h2u(scP[tm * 2][col8 + j]);
      half2_t s1 = h2u(scP[tm * 2 + 1][col8 + j]);
      scP[tm * 2][col8 + j] = pkh2(acc2[0][j] + (float)s0.x, acc2[1][j] + (float)s0.y);
      scP[tm * 2 + 1][col8 + j] = pkh2(acc2[2][j] + (float)s1.x, acc2[3][j] + (float)s1.y);
    }
  }
  __syncthreads();

  {
    const int tnR = tid & 7, tmR = tid >> 3;
    const int colR = tnR * 4, chR = tmR * 4;
    float accr[4][4] = {};
    const unsigned* wrg = (const unsigned*)(wf + OWRP) + chR;
#pragma unroll 8
    for (int k2 = 0; k2 < 128; ++k2) {
      uint4 wv4 = *(const uint4*)(wrg + (size_t)k2 * 128);
      uint4 xv = *(const uint4*)&scP[k2][colR];
      const unsigned xu[4] = {xv.x, xv.y, xv.z, xv.w};
      const unsigned wu_[4] = {wv4.x, wv4.y, wv4.z, wv4.w};
#pragma unroll
      for (int i = 0; i < 4; ++i) {
        half2_t wh = h2u(wu_[i]);
#pragma unroll
        for (int j = 0; j < 4; ++j)
          accr[i][j] = fdot2_(h2u(xu[j]), wh, accr[i][j]);
      }
    }
#pragma unroll
    for (int j = 0; j < 4; ++j) {
      *(float4*)(idenout + ((size_t)b * N_ + n0 + colR + j) * 128 + chR) =
          make_float4(accr[0][j] + wf[OBR + chR], accr[1][j] + wf[OBR + chR + 1],
                      accr[2][j] + wf[OBR + chR + 2], accr[3][j] + wf[OBR + chR + 3]);
    }
  }

  {
    const int tnV = tid & 15, tmV = tid >> 4;
    const int colV = tnV * 2, chV = tmV * 4;
    float accv[4][2] = {};
    const unsigned* wvg = (const unsigned*)(wf + OWVP) + chV;
#pragma unroll 8
    for (int k2 = 0; k2 < 128; ++k2) {
      uint4 wv4 = *(const uint4*)(wvg + (size_t)k2 * 64);
      uint2 xv = *(const uint2*)&scP[k2][colV];
      const unsigned wu_[4] = {wv4.x, wv4.y, wv4.z, wv4.w};
#pragma unroll
      for (int i = 0; i < 4; ++i) {
        half2_t wh = h2u(wu_[i]);
        accv[i][0] = fdot2_(h2u(xv.x), wh, accv[i][0]);
        accv[i][1] = fdot2_(h2u(xv.y), wh, accv[i][1]);
      }
    }
#pragma unroll
    for (int j = 0; j < 2; ++j) {
      *(float4*)(vout + ((size_t)b * N_ + n0 + colV + j) * 64 + chV) =
          make_float4(accv[0][j] + wf[OBV + chV], accv[1][j] + wf[OBV + chV + 1],
                      accv[2][j] + wf[OBV + chV + 2], accv[3][j] + wf[OBV + chV + 3]);
    }
  }
}

// ------------------------------------------------------------------
// q/k/u projections (unchanged).
// ------------------------------------------------------------------
struct Gx { const float* x0; const float* x1; const float* x2;
            float* o0; float* o1; float* o2; };

__global__ __launch_bounds__(256) void k_gemm64x3(const float* __restrict__ wf, Gx g) {
  const int b = blockIdx.z;
  const int n0 = blockIdx.x * 64;
  const int y = blockIdx.y;
  const float* Wt = wf + OWQT + y * (256 * 64);
  const float* bias = wf + OBQ + ((y == 2) ? 3 : y) * 64;
  const float* x = (y == 0) ? g.x0 : (y == 1) ? g.x1 : g.x2;
  float* out = (y == 0) ? g.o0 : (y == 1) ? g.o1 : g.o2;
  __shared__ float ws_[16][64];
  __shared__ float xs_[16][64];
  const int tid = threadIdx.x, tm = tid & 15, tn = tid >> 4;
  float acc[4][4] = {};
  for (int kt = 0; kt < 256; kt += 16) {
    for (int i = tid; i < 1024; i += 256) {
      int kk = i >> 6, col = i & 63;
      ws_[kk][col] = Wt[(size_t)(kt + kk) * 64 + col];
      xs_[kk][col] = x[((size_t)b * 256 + kt + kk) * N_ + n0 + col];
    }
    __syncthreads();
#pragma unroll
    for (int kk = 0; kk < 16; ++kk) {
      float4 x4 = *(const float4*)&xs_[kk][tn * 4];
      float4 w4 = *(const float4*)&ws_[kk][tm * 4];
      float wv[4] = {w4.x, w4.y, w4.z, w4.w};
      float xv[4] = {x4.x, x4.y, x4.z, x4.w};
#pragma unroll
      for (int i = 0; i < 4; ++i)
#pragma unroll
        for (int j = 0; j < 4; ++j) acc[i][j] += wv[i] * xv[j];
    }
    __syncthreads();
  }
#pragma unroll
  for (int j = 0; j < 4; ++j) {
    *(float4*)(out + ((size_t)b * N_ + n0 + tn * 4 + j) * 64 + tm * 4) =
        make_float4(acc[0][j] + bias[tm * 4], acc[1][j] + bias[tm * 4 + 1],
                    acc[2][j] + bias[tm * 4 + 2], acc[3][j] + bias[tm * 4 + 3]);
  }
}

// ------------------------------------------------------------------
// Self-KNN v3: fp64 distances/selection (proven ordering-correct;
// fp32 failed r5 — cancellation error flips rank-20 orderings), plus
// the two exact structural cuts from v2:
//  - winner-only kill + rescan (one thread/round, was all 1024)
//  - dirty-wave reduce skip (only prev winner's wave re-reduces;
//    others copy cached per-wave min across the ph double-buffer)
// Kill/rescan statically unrolled (dynamic index -> scratch trap).
// ------------------------------------------------------------------
__global__ __launch_bounds__(256, 4) void k_knn(const float* __restrict__ pos,
                                                int* __restrict__ idxout) {
  const int b = blockIdx.x >> 11, n = blockIdx.x & 2047;
  __shared__ double redd[2][4];
  __shared__ int redi[2][4];
  const int tid = threadIdx.x;
  const float* pb = pos + (size_t)b * 3 * N_;
  const double xq = pb[n], yq = pb[N_ + n], zq = pb[2 * N_ + n];
  const double sq = xq * xq + yq * yq + zq * zq;
  double d2[8];
#pragma unroll
  for (int s = 0; s < 8; ++s) {
    int i = tid + s * 256;
    double x = pb[i], y = pb[N_ + i], z = pb[2 * N_ + i];
    double psq = x * x + y * y + z * z;
    double dot = xq * x + yq * y + zq * z;
    d2[s] = (sq + psq) - 2.0 * dot;
  }
  const int lane = tid & 63, wv = tid >> 6;
  // cached per-thread best (strict < keeps smallest index among ties)
  double bd = d2[0];
  int bi = tid;
#pragma unroll
  for (int s = 1; s < 8; ++s)
    if (d2[s] < bd) { bd = d2[s]; bi = tid + s * 256; }

  int mi = -1;
  for (int r = 0; r < K_; ++r) {
    const int ph = r & 1;
    const bool dirty = (r == 0) || (((mi & 255) >> 6) == wv);
    if (dirty) {
      double wd = bd;
      int wi = bi;
#pragma unroll
      for (int off = 32; off; off >>= 1) {
        double od = __shfl_down(wd, off);
        int oi = __shfl_down(wi, off);
        if (od < wd || (od == wd && oi < wi)) { wd = od; wi = oi; }
      }
      if (lane == 0) { redd[ph][wv] = wd; redi[ph][wv] = wi; }
    } else if (lane == 0) {
      redd[ph][wv] = redd[ph ^ 1][wv];
      redi[ph][wv] = redi[ph ^ 1][wv];
    }
    __syncthreads();
    double md = redd[ph][0];
    mi = redi[ph][0];
#pragma unroll
    for (int w = 1; w < 4; ++w) {
      double od = redd[ph][w];
      int oi = redi[ph][w];
      if (od < md || (od == md && oi < mi)) { md = od; mi = oi; }
    }
    if (tid == 0) idxout[((size_t)b * N_ + n) * K_ + r] = mi;
    // winner-only kill + rescan; static indexing keeps d2[] in VGPRs
    if ((mi & 255) == tid) {
#pragma unroll
      for (int s = 0; s < 8; ++s)
        if (mi == tid + s * 256) d2[s] = __builtin_inf();
      bd = d2[0];
      bi = tid;
#pragma unroll
      for (int s = 1; s < 8; ++s)
        if (d2[s] < bd) { bd = d2[s]; bi = tid + s * 256; }
    }
  }
}

// ------------------------------------------------------------------
// Fused attention tail v5 (unchanged): P3/P4/P5 on MFMA (16x16x32 f16).
// ------------------------------------------------------------------
__global__ __launch_bounds__(256, 4) void k_attn(
    const float* __restrict__ wf,
    const float* __restrict__ qb, const float* __restrict__ kb,
    const float* __restrict__ vb, const float* __restrict__ ub,
    const float* __restrict__ idenb, const int* __restrict__ idxb,
    const float* __restrict__ pos, float* __restrict__ out) {
  const int lb = ((int)blockIdx.x & 7) * 2048 + ((int)blockIdx.x >> 3);
  const int b = lb >> 11, n = lb & 2047;
  const int tid = threadIdx.x;
  const int lane = tid & 63, wid = tid >> 6;

  __shared__ __align__(16) char smem[26512];
  char*  Sb   = smem;
  char*  hb   = smem + 4096;
  char*  t1b  = smem + 4096;
  char*  peb  = smem + 8192;
  float* lg   = (float*)(smem + 4096);
  float* sVal = (float*)(smem + 20480);
  float* aggs = (float*)(smem + 25680);
  int*   idxs = (int*)(smem + 26192);
  float* prx  = (float*)(smem + 26272);
  float* pry  = (float*)(smem + 26352);
  float* prz  = (float*)(smem + 26432);

  if (tid < 20) idxs[tid] = idxb[((size_t)b * N_ + n) * K_ + tid] & 2047;
  __syncthreads();

  // P1: coalesced gathers; S and V stay in registers until P3b
  float sreg[5], vreg[5];
  {
    size_t rowq = ((size_t)b * N_ + n) * 64;
    float qvo = qb[rowq + lane];
    float ufo = ub[rowq + lane];
#pragma unroll
    for (int t = 0; t < 5; ++t) {
      int kk = wid * 5 + t;
      int j = idxs[kk];
      size_t rowj = ((size_t)b * N_ + j) * 64;
      float kvv = kb[rowj + lane], vvv = vb[rowj + lane], uvv = ub[rowj + lane];
      float ur = ufo - uvv;
      sreg[t] = (qvo - kvv) + ur;
      vreg[t] = vvv + ur;
    }
    if (tid < 20) {
      int j = idxs[tid];
      const float* pp = pos + (size_t)b * 3 * N_;
      prx[tid] = pp[n] - pp[j];
      pry[tid] = pp[N_ + n] - pp[N_ + j];
      prz[tid] = pp[2 * N_ + n] - pp[2 * N_ + j];
    }
  }
  __syncthreads();

  // P2: pos-MLP layer1 + BN + relu -> t1 f16 [k][ph] swz
  {
    int ph = lane;
    float w0 = wf[OPW1 + ph * 3], w1 = wf[OPW1 + ph * 3 + 1], w2 = wf[OPW1 + ph * 3 + 2];
    float pb1 = wf[OPB1 + ph], sc = wf[OPSC + ph], sh = wf[OPSH + ph];
#pragma unroll
    for (int t = 0; t < 5; ++t) {
      int kk = wid * 5 + t;
      float u = pb1 + w0 * prx[kk] + w1 * pry[kk] + w2 * prz[kk];
      float tv = fmaxf(u * sc + sh, 0.f);
      *(_Float16*)(t1b + ((kk * 128 + ph * 2) ^ ((kk & 7) << 4))) = (_Float16)tv;
    }
  }
  __syncthreads();

  // P3a: pe = pm_w2 @ t1 via MFMA (M=64: mt=wid), write pe f32 [k][o] swz
  {
    f32x4_t pacc[2];
#pragma unroll
    for (int nt = 0; nt < 2; ++nt) pacc[nt] = f32x4_t{0.f, 0.f, 0.f, 0.f};
    const int mt = wid;
#pragma unroll
    for (int ks = 0; ks < 2; ++ks) {
      U4H8 a;
      a.u = ((const uint4*)((const unsigned*)(wf + OPWF)))[(mt * 2 + ks) * 64 + lane];
#pragma unroll
      for (int nt = 0; nt < 2; ++nt) {
        int kc = nt * 16 + (lane & 15);
        U4H8 bu;
        bu.u = *(const uint4*)(t1b + ((kc * 128 + (ks * 32 + ((lane >> 4) << 3)) * 2) ^ ((kc & 7) << 4)));
        pacc[nt] = mfma_16x16x32(a.h, bu.h, pacc[nt]);
      }
    }
    const int o0 = mt * 16 + ((lane >> 4) << 2);
    float4 pb2v = *(const float4*)(wf + OPB2 + o0);
#pragma unroll
    for (int nt = 0; nt < 2; ++nt) {
      int kc = nt * 16 + (lane & 15);
      if (kc < 20) {
        float4 o;
        o.x = pacc[nt][0] + pb2v.x; o.y = pacc[nt][1] + pb2v.y;
        o.z = pacc[nt][2] + pb2v.z; o.w = pacc[nt][3] + pb2v.w;
        *(float4*)(peb + ((kc * 256 + o0 * 4) ^ ((kc & 7) << 4))) = o;
      }
    }
  }
  __syncthreads();

  // P3b: fold pe into S (f16 [k][o] swz) and sVal (f32)
  {
#pragma unroll
    for (int t = 0; t < 5; ++t) {
      int kk = wid * 5 + t;
      float pe = *(const float*)(peb + ((kk * 256 + lane * 4) ^ ((kk & 7) << 4)));
      float sv = sreg[t] + pe;
      float vv = vreg[t] + pe;
      sVal[kk * 65 + lane] = vv;
      *(_Float16*)(Sb + ((kk * 128 + lane * 2) ^ ((kk & 7) << 4))) = (_Float16)sv;
    }
  }
  __syncthreads();

  // P4: h = relu(bn(am_w1 @ S)) via MFMA (M=256: 4 mt/wave, 2 passes)
#pragma unroll
  for (int pass = 0; pass < 2; ++pass) {
    const int mt0 = wid * 4 + pass * 2;
    f32x4_t acc[2][2];
#pragma unroll
    for (int m = 0; m < 2; ++m)
#pragma unroll
      for (int nt = 0; nt < 2; ++nt) acc[m][nt] = f32x4_t{0.f, 0.f, 0.f, 0.f};
#pragma unroll
    for (int ks = 0; ks < 2; ++ks) {
      U4H8 bfr[2];
#pragma unroll
      for (int nt = 0; nt < 2; ++nt) {
        int kc = nt * 16 + (lane & 15);
        bfr[nt].u = *(const uint4*)(Sb + ((kc * 128 + (ks * 32 + ((lane >> 4) << 3)) * 2) ^ ((kc & 7) << 4)));
      }
#pragma unroll
      for (int m = 0; m < 2; ++m) {
        U4H8 a;
        a.u = ((const uint4*)((const unsigned*)(wf + OAWF)))[((mt0 + m) * 2 + ks) * 64 + lane];
#pragma unroll
        for (int nt = 0; nt < 2; ++nt)
          acc[m][nt] = mfma_16x16x32(a.h, bfr[nt].h, acc[m][nt]);
      }
    }
#pragma unroll
    for (int m = 0; m < 2; ++m) {
      const int c0 = (mt0 + m) * 16 + ((lane >> 4) << 2);
      float4 ab1 = *(const float4*)(wf + OAB1 + c0);
      float4 asc = *(const float4*)(wf + OASC + c0);
      float4 ash = *(const float4*)(wf + OASH + c0);
#pragma unroll
      for (int nt = 0; nt < 2; ++nt) {
        int kc = nt * 16 + (lane & 15);
        if (kc < 20) {
          float h0 = fmaxf((acc[m][nt][0] + ab1.x) * asc.x + ash.x, 0.f);
          float h1 = fmaxf((acc[m][nt][1] + ab1.y) * asc.y + ash.y, 0.f);
          float h2 = fmaxf((acc[m][nt][2] + ab1.z) * asc.z + ash.z, 0.f);
          float h3 = fmaxf((acc[m][nt][3] + ab1.w) * asc.w + ash.w, 0.f);
          uint2 p;
          p.x = pkh2(h0, h1);
          p.y = pkh2(h2, h3);
          *(uint2*)(hb + ((kc * 512 + c0 * 2) ^ ((kc & 7) << 4))) = p;
        }
      }
    }
  }
  __syncthreads();

  // P5: lg = wt @ h via MFMA (M=128: 2 mt/wave, K=256: 8 ks)
  {
    f32x4_t acc5[2][2];
#pragma unroll
    for (int m = 0; m < 2; ++m)
#pragma unroll
      for (int nt = 0; nt < 2; ++nt) acc5[m][nt] = f32x4_t{0.f, 0.f, 0.f, 0.f};
#pragma unroll
    for (int ks = 0; ks < 8; ++ks) {
      U4H8 bfr[2];
#pragma unroll
      for (int nt = 0; nt < 2; ++nt) {
        int kc = nt * 16 + (lane & 15);
        bfr[nt].u = *(const uint4*)(hb + ((kc * 512 + (ks * 32 + ((lane >> 4) << 3)) * 2) ^ ((kc & 7) << 4)));
      }
#pragma unroll
      for (int m = 0; m < 2; ++m) {
        U4H8 a;
        a.u = ((const uint4*)((const unsigned*)(wf + OWTF)))[((wid * 2 + m) * 8 + ks) * 64 + lane];
#pragma unroll
        for (int nt = 0; nt < 2; ++nt)
          acc5[m][nt] = mfma_16x16x32(a.h, bfr[nt].h, acc5[m][nt]);
      }
    }
    __syncthreads();  // all h reads done before lg overlays the region
#pragma unroll
    for (int m = 0; m < 2; ++m) {
      const int or0 = (wid * 2 + m) * 16 + ((lane >> 4) << 2);
#pragma unroll
      for (int nt = 0; nt < 2; ++nt) {
        int kc = nt * 16 + (lane & 15);
        if (kc < 20) {
#pragma unroll
          for (int r = 0; r < 4; ++r) lg[kc * 129 + or0 + r] = acc5[m][nt][r];
        }
      }
    }
  }
  __syncthreads();

  // P6: softmax over k + aggregate with val
  if (tid < 128) {
    int orr = tid, o = orr >> 1;
    float l[20];
#pragma unroll
    for (int kk = 0; kk < 20; ++kk) l[kk] = lg[kk * 129 + orr];
    float bt = wf[OABT + o];
    float m = -3.4e38f;
#pragma unroll
    for (int kk = 0; kk < 20; ++kk) { l[kk] += bt; m = fmaxf(m, l[kk]); }
    float s = 0.f;
#pragma unroll
    for (int kk = 0; kk < 20; ++kk) { l[kk] = expf(l[kk] - m); s += l[kk]; }
    float inv = 1.f / s;
    float a = 0.f;
#pragma unroll
    for (int kk = 0; kk < 20; ++kk) a += l[kk] * sVal[kk * 65 + o];
    aggs[orr] = a * inv;
  }
  __syncthreads();

  // P7: y = we @ agg + be + iden
  {
    int co = tid & 127, r = tid >> 7;
    float idv = idenb[((size_t)b * N_ + n) * 128 + co];
    float y = wf[OBE + co];
    const float* w = wf + OWET + co;
#pragma unroll 4
    for (int o = 0; o < 64; ++o) y += w[o * 128] * aggs[o * 2 + r];
    out[((size_t)b * 128 + co) * (size_t)(2 * N_) + 2 * n + r] = y + idv;
  }
}

extern "C" void kernel_launch(void* const* d_in, const int* in_sizes, int n_in,
                              void* d_out, int out_size, void* d_ws, size_t ws_size,
                              hipStream_t stream) {
  (void)in_sizes; (void)n_in; (void)out_size; (void)ws_size;
  InPtrs ip;
  for (int i = 0; i < 38; ++i) ip.p[i] = (const float*)d_in[i];
  char* ws = (char*)d_ws;
  float* wf    = (float*)(ws + OFFB_WF);
  int*   idxb  = (int*)(ws + OFFB_IDX);
  float* qb    = (float*)(ws + OFFB_Q);
  float* kb    = (float*)(ws + OFFB_K);
  float* ubuf  = (float*)(ws + OFFB_U);
  float* vbuf  = (float*)(ws + OFFB_V);
  float* idenb = (float*)(ws + OFFB_IDEN);

  k_prep<<<dim3(256), dim3(256), 0, stream>>>(ip, wf);
  k_mv<<<dim3(64, 8), dim3(256), 0, stream>>>(wf, ip.p[1], ip.p[2], vbuf, idenb);
  Gx g{ip.p[2], ip.p[1], ip.p[3], qb, kb, ubuf};
  k_gemm64x3<<<dim3(32, 3, 8), dim3(256), 0, stream>>>(wf, g);
  k_knn<<<dim3(B_ * N_), dim3(256), 0, stream>>>(ip.p[0], idxb);
  k_attn<<<dim3(B_ * N_), dim3(256), 0, stream>>>(wf, qb, kb, vbuf, ubuf, idenb, idxb,
                                                  ip.p[0], (float*)d_out);
}

// Round 8
// 653.483 us; speedup vs baseline: 2.8835x; 1.0413x over previous
//
#include <hip/hip_runtime.h>
#include <hip/hip_bf16.h>

constexpr int B_ = 8, N_ = 2048, K_ = 20;
constexpr float EPS_ = 1e-5f;

// ---- weight area offsets (float slots; "u" = uint32 of packed half2) ----
constexpr int OW1P = 0;                    // u [256 k2][256 ch]  W1 pairs over k
constexpr int OWSP = OW1P + 256 * 256;     // u [256][256]        Ws
constexpr int OW2P = OWSP + 256 * 256;     // u [128][256]        W2
constexpr int OWVP = OW2P + 128 * 256;     // u [128][64]         wv
constexpr int OWRP = OWVP + 128 * 64;      // u [128][128]        wr
constexpr int OWQT = OWRP + 128 * 128;     // f32 [256][64] wq^T
constexpr int OWKT = OWQT + 256 * 64;      // f32 wk^T
constexpr int OWUT = OWKT + 256 * 64;      // f32 wu^T
constexpr int OWET = OWUT + 256 * 64;      // f32 [o][co] 64x128
constexpr int OWTF = OWET + 64 * 128;      // u  wt A-frags  [mt8][ks8][l64]x4u
constexpr int OAWF = OWTF + 16384;         // u  am_w1 A-frags [mt16][ks2][l64]x4u
constexpr int OPWF = OAWF + 8192;          // u  pm_w2 A-frags [mt4][ks2][l64]x4u
constexpr int OPW1 = OPWF + 2048;          // pm_w1 [ph][3]
constexpr int OB1  = OPW1 + 192;           // mv_b1 [256]
constexpr int OBS2 = OB1 + 256;            // mv_bs + mv_b2 [256]
constexpr int OBQ  = OBS2 + 256;
constexpr int OBK  = OBQ + 64;
constexpr int OBV  = OBK + 64;
constexpr int OBU  = OBV + 64;
constexpr int OBR  = OBU + 64;             // [128]
constexpr int OBE  = OBR + 128;            // [128]
constexpr int OPB1 = OBE + 128;            // [64]
constexpr int OPSC = OPB1 + 64;
constexpr int OPSH = OPSC + 64;
constexpr int OPB2 = OPSH + 64;
constexpr int OASC = OPB2 + 64;            // [256]
constexpr int OASH = OASC + 256;
constexpr int OAB1 = OASH + 256;
constexpr int OABT = OAB1 + 256;           // [64]

// ---- workspace byte offsets (28 MiB total) ----
constexpr size_t OFFB_WF   = 0;
constexpr size_t OFFB_IDX  = (size_t)2 << 20;
constexpr size_t OFFB_Q    = (size_t)4 << 20;   // [b][n][64]
constexpr size_t OFFB_K    = (size_t)8 << 20;   // [b][n][64]
constexpr size_t OFFB_U    = (size_t)12 << 20;  // [b][n][64]
constexpr size_t OFFB_V    = (size_t)16 << 20;  // [b][n][64]
constexpr size_t OFFB_IDEN = (size_t)20 << 20;  // [b][n][128]

struct InPtrs { const float* p[38]; };

// ---- f16 helpers ----
typedef _Float16 half2_t __attribute__((ext_vector_type(2)));
typedef _Float16 f16x8_t __attribute__((ext_vector_type(8)));
typedef float    f32x4_t __attribute__((ext_vector_type(4)));

union U4H8 { uint4 u; f16x8_t h; };

__device__ __forceinline__ float fdot2_(half2_t a, half2_t b, float c) {
  return __builtin_amdgcn_fdot2(a, b, c, false);
}
__device__ __forceinline__ unsigned pkh2(float a, float b) {
  union { unsigned u; half2_t h; } x;
  x.h = half2_t{(_Float16)a, (_Float16)b};
  return x.u;
}
__device__ __forceinline__ half2_t h2u(unsigned u) {
  union { unsigned u; half2_t h; } x;
  x.u = u;
  return x.h;
}
__device__ __forceinline__ f32x4_t mfma_16x16x32(f16x8_t a, f16x8_t b, f32x4_t c) {
  return __builtin_amdgcn_mfma_f32_16x16x32_f16(a, b, c, 0, 0, 0);
}

// ------------------------------------------------------------------
// Weight prep: f16 packs for mv, MFMA A-fragment packs for attn,
// f32 transposes, BN folds.
// A-fragment order (16x16x32): lane l: row m = l&15, k = (l>>4)*8+j.
// Frag f stored as 4 consecutive u32 (8 f16).
// ------------------------------------------------------------------
__global__ __launch_bounds__(256) void k_prep(InPtrs in, float* __restrict__ wf) {
  const int tid = blockIdx.x * 256 + threadIdx.x;
  const int nth = gridDim.x * 256;
  const float *mv_w1 = in.p[4], *mv_b1 = in.p[5], *mv_w2 = in.p[6], *mv_b2 = in.p[7],
              *mv_ws = in.p[8], *mv_bs = in.p[9], *wk = in.p[10], *bk = in.p[11],
              *wq = in.p[12], *bq = in.p[13], *wv = in.p[14], *bv = in.p[15],
              *wu = in.p[16], *bu = in.p[17], *pm_w1 = in.p[18], *pm_b1 = in.p[19],
              *pm_g = in.p[20], *pm_be = in.p[21], *pm_m = in.p[22], *pm_v = in.p[23],
              *pm_w2 = in.p[24], *pm_b2 = in.p[25], *am_w1 = in.p[26], *am_b1 = in.p[27],
              *am_g = in.p[28], *am_be = in.p[29], *am_m = in.p[30], *am_v = in.p[31],
              *am_wt = in.p[32], *am_bt = in.p[33], *we = in.p[34], *be = in.p[35],
              *wr = in.p[36], *br = in.p[37];

  // mv-path packed weights: [k2][ch] = half2(W[ch][2k2], W[ch][2k2+1])
  {
    unsigned* w1p = (unsigned*)(wf + OW1P);
    for (int i = tid; i < 256 * 256; i += nth) {
      int k2 = i >> 8, ch = i & 255;
      w1p[i] = pkh2(mv_w1[ch * 512 + 2 * k2], mv_w1[ch * 512 + 2 * k2 + 1]);
    }
    unsigned* wsp = (unsigned*)(wf + OWSP);
    for (int i = tid; i < 256 * 256; i += nth) {
      int k2 = i >> 8, ch = i & 255;
      wsp[i] = pkh2(mv_ws[ch * 512 + 2 * k2], mv_ws[ch * 512 + 2 * k2 + 1]);
    }
    unsigned* w2p = (unsigned*)(wf + OW2P);
    for (int i = tid; i < 128 * 256; i += nth) {
      int k2 = i >> 8, ch = i & 255;
      w2p[i] = pkh2(mv_w2[ch * 256 + 2 * k2], mv_w2[ch * 256 + 2 * k2 + 1]);
    }
    unsigned* wvp = (unsigned*)(wf + OWVP);
    for (int i = tid; i < 128 * 64; i += nth) {
      int k2 = i >> 6, ch = i & 63;
      wvp[i] = pkh2(wv[ch * 256 + 2 * k2], wv[ch * 256 + 2 * k2 + 1]);
    }
    unsigned* wrp = (unsigned*)(wf + OWRP);
    for (int i = tid; i < 128 * 128; i += nth) {
      int k2 = i >> 7, ch = i & 127;
      wrp[i] = pkh2(wr[ch * 256 + 2 * k2], wr[ch * 256 + 2 * k2 + 1]);
    }
  }
  for (int i = tid; i < 256 * 64; i += nth) { int c = i >> 6, m = i & 63; wf[OWQT + i] = wq[m * 256 + c]; }
  for (int i = tid; i < 256 * 64; i += nth) { int c = i >> 6, m = i & 63; wf[OWKT + i] = wk[m * 256 + c]; }
  for (int i = tid; i < 256 * 64; i += nth) { int c = i >> 6, m = i & 63; wf[OWUT + i] = wu[m * 256 + c]; }
  for (int i = tid; i < 64 * 128; i += nth) { int o = i >> 7, co = i & 127; wf[OWET + i] = we[co * 64 + o]; }

  // wt A-frags: A[or(128)][c(256)], mt<8, ks<8: i = ((mt*8+ks)*64+l)*4+q
  {
    unsigned* wtf = (unsigned*)(wf + OWTF);
    for (int i = tid; i < 16384; i += nth) {
      int q = i & 3, l = (i >> 2) & 63, ks = (i >> 8) & 7, mt = i >> 11;
      int orr = mt * 16 + (l & 15);
      int c = ks * 32 + ((l >> 4) << 3) + 2 * q;
      wtf[i] = pkh2(am_wt[c * 128 + orr], am_wt[(c + 1) * 128 + orr]);
    }
  }
  // am_w1 A-frags: A[c(256)][o(64)], mt<16, ks<2: i = ((mt*2+ks)*64+l)*4+q
  {
    unsigned* awf = (unsigned*)(wf + OAWF);
    for (int i = tid; i < 8192; i += nth) {
      int q = i & 3, l = (i >> 2) & 63, ks = (i >> 8) & 1, mt = i >> 9;
      int c = mt * 16 + (l & 15);
      int o = ks * 32 + ((l >> 4) << 3) + 2 * q;
      awf[i] = pkh2(am_w1[c * 64 + o], am_w1[c * 64 + o + 1]);
    }
  }
  // pm_w2 A-frags: A[o(64)][ph(64)], mt<4, ks<2: i = ((mt*2+ks)*64+l)*4+q
  {
    unsigned* pwf = (unsigned*)(wf + OPWF);
    for (int i = tid; i < 2048; i += nth) {
      int q = i & 3, l = (i >> 2) & 63, ks = (i >> 8) & 1, mt = i >> 9;
      int o = mt * 16 + (l & 15);
      int ph = ks * 32 + ((l >> 4) << 3) + 2 * q;
      pwf[i] = pkh2(pm_w2[o * 64 + ph], pm_w2[o * 64 + ph + 1]);
    }
  }
  for (int i = tid; i < 192; i += nth) wf[OPW1 + i] = pm_w1[i];
  for (int i = tid; i < 256; i += nth) {
    wf[OB1 + i] = mv_b1[i];
    wf[OBS2 + i] = mv_bs[i] + mv_b2[i];
    float sc = am_g[i] / sqrtf(am_v[i] + EPS_);
    wf[OASC + i] = sc;
    wf[OASH + i] = am_be[i] - am_m[i] * sc;
    wf[OAB1 + i] = am_b1[i];
  }
  for (int i = tid; i < 64; i += nth) {
    wf[OBQ + i] = bq[i]; wf[OBK + i] = bk[i];
    wf[OBV + i] = bv[i]; wf[OBU + i] = bu[i];
    wf[OABT + i] = am_bt[i]; wf[OPB1 + i] = pm_b1[i]; wf[OPB2 + i] = pm_b2[i];
    float sc = pm_g[i] / sqrtf(pm_v[i] + EPS_);
    wf[OPSC + i] = sc;
    wf[OPSH + i] = pm_be[i] - pm_m[i] * sc;
  }
  for (int i = tid; i < 128; i += nth) { wf[OBR + i] = br[i]; wf[OBE + i] = be[i]; }
}

// ------------------------------------------------------------------
// Fused mv-MLP + v/iden projections (unchanged).
// ------------------------------------------------------------------
__global__ __launch_bounds__(256, 2) void k_mv(const float* __restrict__ wf,
                                               const float* __restrict__ keyf,
                                               const float* __restrict__ qryf,
                                               float* __restrict__ vout,
                                               float* __restrict__ idenout) {
  const int b = blockIdx.y;
  const int n0 = blockIdx.x * 32;
  __shared__ __align__(16) unsigned hidP[128][32];
  __shared__ __align__(16) unsigned scP[128][32];
  __shared__ __align__(16) unsigned xsP[8][32];
  const int tid = threadIdx.x;
  const int tn = tid & 3, tm = tid >> 2;
  const int col8 = tn * 8, ch4 = tm * 4;

  float acch[4][8] = {};
  float accs[4][8] = {};
  {
    const unsigned* w1g = (const unsigned*)(wf + OW1P) + ch4;
    const unsigned* wsg = (const unsigned*)(wf + OWSP) + ch4;
    const int k2l = tid >> 5, cstage = tid & 31;
    for (int kt2 = 0; kt2 < 256; kt2 += 8) {
      int c = 2 * (kt2 + k2l);
      const float* s = (c < 256) ? keyf : qryf;
      size_t base = ((size_t)b * 256 + (c & 255)) * N_ + n0 + cstage;
      float xr0 = s[base], xr1 = s[base + N_];
      __syncthreads();
      xsP[k2l][cstage] = pkh2(xr0, xr1);
      __syncthreads();
#pragma unroll
      for (int k2 = 0; k2 < 8; ++k2) {
        uint4 w1v = *(const uint4*)(w1g + (size_t)(kt2 + k2) * 256);
        uint4 wsv = *(const uint4*)(wsg + (size_t)(kt2 + k2) * 256);
        uint4 xa = *(const uint4*)&xsP[k2][col8];
        uint4 xb = *(const uint4*)&xsP[k2][col8 + 4];
        const unsigned xu[8] = {xa.x, xa.y, xa.z, xa.w, xb.x, xb.y, xb.z, xb.w};
        const unsigned w1u[4] = {w1v.x, w1v.y, w1v.z, w1v.w};
        const unsigned wsu[4] = {wsv.x, wsv.y, wsv.z, wsv.w};
#pragma unroll
        for (int i = 0; i < 4; ++i) {
          half2_t w1h = h2u(w1u[i]), wsh = h2u(wsu[i]);
#pragma unroll
          for (int j = 0; j < 8; ++j) {
            half2_t xh = h2u(xu[j]);
            acch[i][j] = fdot2_(xh, w1h, acch[i][j]);
            accs[i][j] = fdot2_(xh, wsh, accs[i][j]);
          }
        }
      }
    }
  }
  {
    float b1v[4], bsv[4];
#pragma unroll
    for (int i = 0; i < 4; ++i) { b1v[i] = wf[OB1 + ch4 + i]; bsv[i] = wf[OBS2 + ch4 + i]; }
#pragma unroll
    for (int j = 0; j < 8; ++j) {
      hidP[tm * 2][col8 + j] =
          pkh2(fmaxf(acch[0][j] + b1v[0], 0.f), fmaxf(acch[1][j] + b1v[1], 0.f));
      hidP[tm * 2 + 1][col8 + j] =
          pkh2(fmaxf(acch[2][j] + b1v[2], 0.f), fmaxf(acch[3][j] + b1v[3], 0.f));
      scP[tm * 2][col8 + j] = pkh2(accs[0][j] + bsv[0], accs[1][j] + bsv[1]);
      scP[tm * 2 + 1][col8 + j] = pkh2(accs[2][j] + bsv[2], accs[3][j] + bsv[3]);
    }
  }
  __syncthreads();

  {
    float acc2[4][8] = {};
    const unsigned* w2g = (const unsigned*)(wf + OW2P) + ch4;
#pragma unroll 4
    for (int k2 = 0; k2 < 128; ++k2) {
      uint4 w2v = *(const uint4*)(w2g + (size_t)k2 * 256);
      uint4 xa = *(const uint4*)&hidP[k2][col8];
      uint4 xb = *(const uint4*)&hidP[k2][col8 + 4];
      const unsigned xu[8] = {xa.x, xa.y, xa.z, xa.w, xb.x, xb.y, xb.z, xb.w};
      const unsigned w2u[4] = {w2v.x, w2v.y, w2v.z, w2v.w};
#pragma unroll
      for (int i = 0; i < 4; ++i) {
        half2_t wh = h2u(w2u[i]);
#pragma unroll
        for (int j = 0; j < 8; ++j)
          acc2[i][j] = fdot2_(h2u(xu[j]), wh, acc2[i][j]);
      }
    }
#pragma unroll
    for (int j = 0; j < 8; ++j) {
      half2_t s0 = h2u(scP[tm * 2][col8 + j]);
      half2_t s1 = h2u(scP[tm * 2 + 1][col8 + j]);
      scP[tm * 2][col8 + j] = pkh2(acc2[0][j] + (float)s0.x, acc2[1][j] + (float)s0.y);
      scP[tm * 2 + 1][col8 + j] = pkh2(acc2[2][j] + (float)s1.x, acc2[3][j] + (float)s1.y);
    }
  }
  __syncthreads();

  {
    const int tnR = tid & 7, tmR = tid >> 3;
    const int colR = tnR * 4, chR = tmR * 4;
    float accr[4][4] = {};
    const unsigned* wrg = (const unsigned*)(wf + OWRP) + chR;
#pragma unroll 8
    for (int k2 = 0; k2 < 128; ++k2) {
      uint4 wv4 = *(const uint4*)(wrg + (size_t)k2 * 128);
      uint4 xv = *(const uint4*)&scP[k2][colR];
      const unsigned xu[4] = {xv.x, xv.y, xv.z, xv.w};
      const unsigned wu_[4] = {wv4.x, wv4.y, wv4.z, wv4.w};
#pragma unroll
      for (int i = 0; i < 4; ++i) {
        half2_t wh = h2u(wu_[i]);
#pragma unroll
        for (int j = 0; j < 4; ++j)
          accr[i][j] = fdot2_(h2u(xu[j]), wh, accr[i][j]);
      }
    }
#pragma unroll
    for (int j = 0; j < 4; ++j) {
      *(float4*)(idenout + ((size_t)b * N_ + n0 + colR + j) * 128 + chR) =
          make_float4(accr[0][j] + wf[OBR + chR], accr[1][j] + wf[OBR + chR + 1],
                      accr[2][j] + wf[OBR + chR + 2], accr[3][j] + wf[OBR + chR + 3]);
    }
  }

  {
    const int tnV = tid & 15, tmV = tid >> 4;
    const int colV = tnV * 2, chV = tmV * 4;
    float accv[4][2] = {};
    const unsigned* wvg = (const unsigned*)(wf + OWVP) + chV;
#pragma unroll 8
    for (int k2 = 0; k2 < 128; ++k2) {
      uint4 wv4 = *(const uint4*)(wvg + (size_t)k2 * 64);
      uint2 xv = *(const uint2*)&scP[k2][colV];
      const unsigned wu_[4] = {wv4.x, wv4.y, wv4.z, wv4.w};
#pragma unroll
      for (int i = 0; i < 4; ++i) {
        half2_t wh = h2u(wu_[i]);
        accv[i][0] = fdot2_(h2u(xv.x), wh, accv[i][0]);
        accv[i][1] = fdot2_(h2u(xv.y), wh, accv[i][1]);
      }
    }
#pragma unroll
    for (int j = 0; j < 2; ++j) {
      *(float4*)(vout + ((size_t)b * N_ + n0 + colV + j) * 64 + chV) =
          make_float4(accv[0][j] + wf[OBV + chV], accv[1][j] + wf[OBV + chV + 1],
                      accv[2][j] + wf[OBV + chV + 2], accv[3][j] + wf[OBV + chV + 3]);
    }
  }
}

// ------------------------------------------------------------------
// q/k/u projections (unchanged).
// ------------------------------------------------------------------
struct Gx { const float* x0; const float* x1; const float* x2;
            float* o0; float* o1; float* o2; };

__global__ __launch_bounds__(256) void k_gemm64x3(const float* __restrict__ wf, Gx g) {
  const int b = blockIdx.z;
  const int n0 = blockIdx.x * 64;
  const int y = blockIdx.y;
  const float* Wt = wf + OWQT + y * (256 * 64);
  const float* bias = wf + OBQ + ((y == 2) ? 3 : y) * 64;
  const float* x = (y == 0) ? g.x0 : (y == 1) ? g.x1 : g.x2;
  float* out = (y == 0) ? g.o0 : (y == 1) ? g.o1 : g.o2;
  __shared__ float ws_[16][64];
  __shared__ float xs_[16][64];
  const int tid = threadIdx.x, tm = tid & 15, tn = tid >> 4;
  float acc[4][4] = {};
  for (int kt = 0; kt < 256; kt += 16) {
    for (int i = tid; i < 1024; i += 256) {
      int kk = i >> 6, col = i & 63;
      ws_[kk][col] = Wt[(size_t)(kt + kk) * 64 + col];
      xs_[kk][col] = x[((size_t)b * 256 + kt + kk) * N_ + n0 + col];
    }
    __syncthreads();
#pragma unroll
    for (int kk = 0; kk < 16; ++kk) {
      float4 x4 = *(const float4*)&xs_[kk][tn * 4];
      float4 w4 = *(const float4*)&ws_[kk][tm * 4];
      float wv[4] = {w4.x, w4.y, w4.z, w4.w};
      float xv[4] = {x4.x, x4.y, x4.z, x4.w};
#pragma unroll
      for (int i = 0; i < 4; ++i)
#pragma unroll
        for (int j = 0; j < 4; ++j) acc[i][j] += wv[i] * xv[j];
    }
    __syncthreads();
  }
#pragma unroll
  for (int j = 0; j < 4; ++j) {
    *(float4*)(out + ((size_t)b * N_ + n0 + tn * 4 + j) * 64 + tm * 4) =
        make_float4(acc[0][j] + bias[tm * 4], acc[1][j] + bias[tm * 4 + 1],
                    acc[2][j] + bias[tm * 4 + 2], acc[3][j] + bias[tm * 4 + 3]);
  }
}

// ------------------------------------------------------------------
// Self-KNN v4: downstream is permutation-invariant in k (softmax+sum
// over k), so only the neighbor SET matters. Selection via sortable
// u64 keys: d2>=0 -> fp64 bits monotone as u64; truncate low 11
// mantissa bits (2^-41 rel precision, 1e5x finer than the f32 noise
// that failed r5) and pack the 11-bit index -> unique keys.
//  Phase A: per-wave top-20, 20 butterfly-min rounds (5 instr/stage),
//           ZERO barriers; lane0 appends to sorted LDS list.
//  Phase B: one barrier; rank-merge of 4x20 sorted lists via binary
//           search; write idx to slot=rank if rank<20 (exactly once).
// ------------------------------------------------------------------
__global__ __launch_bounds__(256, 8) void k_knn(const float* __restrict__ pos,
                                                int* __restrict__ idxout) {
  const int b = blockIdx.x >> 11, n = blockIdx.x & 2047;
  __shared__ unsigned long long wkeys[4][20];
  const int tid = threadIdx.x;
  const float* pb = pos + (size_t)b * 3 * N_;
  const double xq = pb[n], yq = pb[N_ + n], zq = pb[2 * N_ + n];
  const double sq = xq * xq + yq * yq + zq * zq;
  unsigned long long key[8];
#pragma unroll
  for (int s = 0; s < 8; ++s) {
    int i = tid + s * 256;
    double x = pb[i], y = pb[N_ + i], z = pb[2 * N_ + i];
    double psq = x * x + y * y + z * z;
    double dot = xq * x + yq * y + zq * z;
    double d2 = fmax((sq + psq) - 2.0 * dot, 0.0);
    key[s] = ((unsigned long long)__double_as_longlong(d2) & ~0x7FFull) |
             (unsigned long long)i;
  }
  const int lane = tid & 63, wv = tid >> 6;
  unsigned long long bk = key[0];
#pragma unroll
  for (int s = 1; s < 8; ++s)
    if (key[s] < bk) bk = key[s];

  // Phase A: per-wave top-20, no barriers
  for (int r = 0; r < K_; ++r) {
    unsigned long long wk = bk;
#pragma unroll
    for (int m = 32; m; m >>= 1) {
      unsigned long long ok =
          (unsigned long long)__shfl_xor((long long)wk, m);
      if (ok < wk) wk = ok;
    }
    if (lane == 0) wkeys[wv][r] = wk;
    const int widx = (int)(wk & 0x7FF);
    if ((widx & 255) == tid) {
#pragma unroll
      for (int s = 0; s < 8; ++s)
        if (widx == tid + s * 256) key[s] = ~0ull;
      bk = key[0];
#pragma unroll
      for (int s = 1; s < 8; ++s)
        if (key[s] < bk) bk = key[s];
    }
  }
  __syncthreads();

  // Phase B: rank-merge of 4 sorted 20-lists (all keys unique)
  if (tid < 128) {
    const int w = tid >> 5, p = tid & 31;
    if (p < 20) {
      const unsigned long long Kk = wkeys[w][p];
      int rank = p;
#pragma unroll
      for (int w2 = 0; w2 < 4; ++w2) {
        if (w2 == w) continue;
        int lo = 0, hi = 20;
        while (lo < hi) {
          int mid = (lo + hi) >> 1;
          if (wkeys[w2][mid] < Kk) lo = mid + 1; else hi = mid;
        }
        rank += lo;
      }
      if (rank < K_)
        idxout[((size_t)b * N_ + n) * K_ + rank] = (int)(Kk & 0x7FF);
    }
  }
}

// ------------------------------------------------------------------
// Fused attention tail v5 (unchanged): P3/P4/P5 on MFMA (16x16x32 f16).
// ------------------------------------------------------------------
__global__ __launch_bounds__(256, 4) void k_attn(
    const float* __restrict__ wf,
    const float* __restrict__ qb, const float* __restrict__ kb,
    const float* __restrict__ vb, const float* __restrict__ ub,
    const float* __restrict__ idenb, const int* __restrict__ idxb,
    const float* __restrict__ pos, float* __restrict__ out) {
  const int lb = ((int)blockIdx.x & 7) * 2048 + ((int)blockIdx.x >> 3);
  const int b = lb >> 11, n = lb & 2047;
  const int tid = threadIdx.x;
  const int lane = tid & 63, wid = tid >> 6;

  __shared__ __align__(16) char smem[26512];
  char*  Sb   = smem;
  char*  hb   = smem + 4096;
  char*  t1b  = smem + 4096;
  char*  peb  = smem + 8192;
  float* lg   = (float*)(smem + 4096);
  float* sVal = (float*)(smem + 20480);
  float* aggs = (float*)(smem + 25680);
  int*   idxs = (int*)(smem + 26192);
  float* prx  = (float*)(smem + 26272);
  float* pry  = (float*)(smem + 26352);
  float* prz  = (float*)(smem + 26432);

  if (tid < 20) idxs[tid] = idxb[((size_t)b * N_ + n) * K_ + tid] & 2047;
  __syncthreads();

  // P1: coalesced gathers; S and V stay in registers until P3b
  float sreg[5], vreg[5];
  {
    size_t rowq = ((size_t)b * N_ + n) * 64;
    float qvo = qb[rowq + lane];
    float ufo = ub[rowq + lane];
#pragma unroll
    for (int t = 0; t < 5; ++t) {
      int kk = wid * 5 + t;
      int j = idxs[kk];
      size_t rowj = ((size_t)b * N_ + j) * 64;
      float kvv = kb[rowj + lane], vvv = vb[rowj + lane], uvv = ub[rowj + lane];
      float ur = ufo - uvv;
      sreg[t] = (qvo - kvv) + ur;
      vreg[t] = vvv + ur;
    }
    if (tid < 20) {
      int j = idxs[tid];
      const float* pp = pos + (size_t)b * 3 * N_;
      prx[tid] = pp[n] - pp[j];
      pry[tid] = pp[N_ + n] - pp[N_ + j];
      prz[tid] = pp[2 * N_ + n] - pp[2 * N_ + j];
    }
  }
  __syncthreads();

  // P2: pos-MLP layer1 + BN + relu -> t1 f16 [k][ph] swz
  {
    int ph = lane;
    float w0 = wf[OPW1 + ph * 3], w1 = wf[OPW1 + ph * 3 + 1], w2 = wf[OPW1 + ph * 3 + 2];
    float pb1 = wf[OPB1 + ph], sc = wf[OPSC + ph], sh = wf[OPSH + ph];
#pragma unroll
    for (int t = 0; t < 5; ++t) {
      int kk = wid * 5 + t;
      float u = pb1 + w0 * prx[kk] + w1 * pry[kk] + w2 * prz[kk];
      float tv = fmaxf(u * sc + sh, 0.f);
      *(_Float16*)(t1b + ((kk * 128 + ph * 2) ^ ((kk & 7) << 4))) = (_Float16)tv;
    }
  }
  __syncthreads();

  // P3a: pe = pm_w2 @ t1 via MFMA (M=64: mt=wid), write pe f32 [k][o] swz
  {
    f32x4_t pacc[2];
#pragma unroll
    for (int nt = 0; nt < 2; ++nt) pacc[nt] = f32x4_t{0.f, 0.f, 0.f, 0.f};
    const int mt = wid;
#pragma unroll
    for (int ks = 0; ks < 2; ++ks) {
      U4H8 a;
      a.u = ((const uint4*)((const unsigned*)(wf + OPWF)))[(mt * 2 + ks) * 64 + lane];
#pragma unroll
      for (int nt = 0; nt < 2; ++nt) {
        int kc = nt * 16 + (lane & 15);
        U4H8 bu;
        bu.u = *(const uint4*)(t1b + ((kc * 128 + (ks * 32 + ((lane >> 4) << 3)) * 2) ^ ((kc & 7) << 4)));
        pacc[nt] = mfma_16x16x32(a.h, bu.h, pacc[nt]);
      }
    }
    const int o0 = mt * 16 + ((lane >> 4) << 2);
    float4 pb2v = *(const float4*)(wf + OPB2 + o0);
#pragma unroll
    for (int nt = 0; nt < 2; ++nt) {
      int kc = nt * 16 + (lane & 15);
      if (kc < 20) {
        float4 o;
        o.x = pacc[nt][0] + pb2v.x; o.y = pacc[nt][1] + pb2v.y;
        o.z = pacc[nt][2] + pb2v.z; o.w = pacc[nt][3] + pb2v.w;
        *(float4*)(peb + ((kc * 256 + o0 * 4) ^ ((kc & 7) << 4))) = o;
      }
    }
  }
  __syncthreads();

  // P3b: fold pe into S (f16 [k][o] swz) and sVal (f32)
  {
#pragma unroll
    for (int t = 0; t < 5; ++t) {
      int kk = wid * 5 + t;
      float pe = *(const float*)(peb + ((kk * 256 + lane * 4) ^ ((kk & 7) << 4)));
      float sv = sreg[t] + pe;
      float vv = vreg[t] + pe;
      sVal[kk * 65 + lane] = vv;
      *(_Float16*)(Sb + ((kk * 128 + lane * 2) ^ ((kk & 7) << 4))) = (_Float16)sv;
    }
  }
  __syncthreads();

  // P4: h = relu(bn(am_w1 @ S)) via MFMA (M=256: 4 mt/wave, 2 passes)
#pragma unroll
  for (int pass = 0; pass < 2; ++pass) {
    const int mt0 = wid * 4 + pass * 2;
    f32x4_t acc[2][2];
#pragma unroll
    for (int m = 0; m < 2; ++m)
#pragma unroll
      for (int nt = 0; nt < 2; ++nt) acc[m][nt] = f32x4_t{0.f, 0.f, 0.f, 0.f};
#pragma unroll
    for (int ks = 0; ks < 2; ++ks) {
      U4H8 bfr[2];
#pragma unroll
      for (int nt = 0; nt < 2; ++nt) {
        int kc = nt * 16 + (lane & 15);
        bfr[nt].u = *(const uint4*)(Sb + ((kc * 128 + (ks * 32 + ((lane >> 4) << 3)) * 2) ^ ((kc & 7) << 4)));
      }
#pragma unroll
      for (int m = 0; m < 2; ++m) {
        U4H8 a;
        a.u = ((const uint4*)((const unsigned*)(wf + OAWF)))[((mt0 + m) * 2 + ks) * 64 + lane];
#pragma unroll
        for (int nt = 0; nt < 2; ++nt)
          acc[m][nt] = mfma_16x16x32(a.h, bfr[nt].h, acc[m][nt]);
      }
    }
#pragma unroll
    for (int m = 0; m < 2; ++m) {
      const int c0 = (mt0 + m) * 16 + ((lane >> 4) << 2);
      float4 ab1 = *(const float4*)(wf + OAB1 + c0);
      float4 asc = *(const float4*)(wf + OASC + c0);
      float4 ash = *(const float4*)(wf + OASH + c0);
#pragma unroll
      for (int nt = 0; nt < 2; ++nt) {
        int kc = nt * 16 + (lane & 15);
        if (kc < 20) {
          float h0 = fmaxf((acc[m][nt][0] + ab1.x) * asc.x + ash.x, 0.f);
          float h1 = fmaxf((acc[m][nt][1] + ab1.y) * asc.y + ash.y, 0.f);
          float h2 = fmaxf((acc[m][nt][2] + ab1.z) * asc.z + ash.z, 0.f);
          float h3 = fmaxf((acc[m][nt][3] + ab1.w) * asc.w + ash.w, 0.f);
          uint2 p;
          p.x = pkh2(h0, h1);
          p.y = pkh2(h2, h3);
          *(uint2*)(hb + ((kc * 512 + c0 * 2) ^ ((kc & 7) << 4))) = p;
        }
      }
    }
  }
  __syncthreads();

  // P5: lg = wt @ h via MFMA (M=128: 2 mt/wave, K=256: 8 ks)
  {
    f32x4_t acc5[2][2];
#pragma unroll
    for (int m = 0; m < 2; ++m)
#pragma unroll
      for (int nt = 0; nt < 2; ++nt) acc5[m][nt] = f32x4_t{0.f, 0.f, 0.f, 0.f};
#pragma unroll
    for (int ks = 0; ks < 8; ++ks) {
      U4H8 bfr[2];
#pragma unroll
      for (int nt = 0; nt < 2; ++nt) {
        int kc = nt * 16 + (lane & 15);
        bfr[nt].u = *(const uint4*)(hb + ((kc * 512 + (ks * 32 + ((lane >> 4) << 3)) * 2) ^ ((kc & 7) << 4)));
      }
#pragma unroll
      for (int m = 0; m < 2; ++m) {
        U4H8 a;
        a.u = ((const uint4*)((const unsigned*)(wf + OWTF)))[((wid * 2 + m) * 8 + ks) * 64 + lane];
#pragma unroll
        for (int nt = 0; nt < 2; ++nt)
          acc5[m][nt] = mfma_16x16x32(a.h, bfr[nt].h, acc5[m][nt]);
      }
    }
    __syncthreads();  // all h reads done before lg overlays the region
#pragma unroll
    for (int m = 0; m < 2; ++m) {
      const int or0 = (wid * 2 + m) * 16 + ((lane >> 4) << 2);
#pragma unroll
      for (int nt = 0; nt < 2; ++nt) {
        int kc = nt * 16 + (lane & 15);
        if (kc < 20) {
#pragma unroll
          for (int r = 0; r < 4; ++r) lg[kc * 129 + or0 + r] = acc5[m][nt][r];
        }
      }
    }
  }
  __syncthreads();

  // P6: softmax over k + aggregate with val
  if (tid < 128) {
    int orr = tid, o = orr >> 1;
    float l[20];
#pragma unroll
    for (int kk = 0; kk < 20; ++kk) l[kk] = lg[kk * 129 + orr];
    float bt = wf[OABT + o];
    float m = -3.4e38f;
#pragma unroll
    for (int kk = 0; kk < 20; ++kk) { l[kk] += bt; m = fmaxf(m, l[kk]); }
    float s = 0.f;
#pragma unroll
    for (int kk = 0; kk < 20; ++kk) { l[kk] = expf(l[kk] - m); s += l[kk]; }
    float inv = 1.f / s;
    float a = 0.f;
#pragma unroll
    for (int kk = 0; kk < 20; ++kk) a += l[kk] * sVal[kk * 65 + o];
    aggs[orr] = a * inv;
  }
  __syncthreads();

  // P7: y = we @ agg + be + iden
  {
    int co = tid & 127, r = tid >> 7;
    float idv = idenb[((size_t)b * N_ + n) * 128 + co];
    float y = wf[OBE + co];
    const float* w = wf + OWET + co;
#pragma unroll 4
    for (int o = 0; o < 64; ++o) y += w[o * 128] * aggs[o * 2 + r];
    out[((size_t)b * 128 + co) * (size_t)(2 * N_) + 2 * n + r] = y + idv;
  }
}

extern "C" void kernel_launch(void* const* d_in, const int* in_sizes, int n_in,
                              void* d_out, int out_size, void* d_ws, size_t ws_size,
                              hipStream_t stream) {
  (void)in_sizes; (void)n_in; (void)out_size; (void)ws_size;
  InPtrs ip;
  for (int i = 0; i < 38; ++i) ip.p[i] = (const float*)d_in[i];
  char* ws = (char*)d_ws;
  float* wf    = (float*)(ws + OFFB_WF);
  int*   idxb  = (int*)(ws + OFFB_IDX);
  float* qb    = (float*)(ws + OFFB_Q);
  float* kb    = (float*)(ws + OFFB_K);
  float* ubuf  = (float*)(ws + OFFB_U);
  float* vbuf  = (float*)(ws + OFFB_V);
  float* idenb = (float*)(ws + OFFB_IDEN);

  k_prep<<<dim3(256), dim3(256), 0, stream>>>(ip, wf);
  k_mv<<<dim3(64, 8), dim3(256), 0, stream>>>(wf, ip.p[1], ip.p[2], vbuf, idenb);
  Gx g{ip.p[2], ip.p[1], ip.p[3], qb, kb, ubuf};
  k_gemm64x3<<<dim3(32, 3, 8), dim3(256), 0, stream>>>(wf, g);
  k_knn<<<dim3(B_ * N_), dim3(256), 0, stream>>>(ip.p[0], idxb);
  k_attn<<<dim3(B_ * N_), dim3(256), 0, stream>>>(wf, qb, kb, vbuf, ubuf, idenb, idxb,
                                                  ip.p[0], (float*)d_out);
}

// Round 9
// 546.768 us; speedup vs baseline: 3.4463x; 1.1952x over previous
//
#include <hip/hip_runtime.h>
#include <hip/hip_bf16.h>

constexpr int B_ = 8, N_ = 2048, K_ = 20;
constexpr float EPS_ = 1e-5f;

// ---- weight area offsets (float slots; "u" = uint32 of packed half2) ----
constexpr int OW1P = 0;                    // u [256 k2][256 ch]  W1 pairs over k
constexpr int OWSP = OW1P + 256 * 256;     // u [256][256]        Ws
constexpr int OW2P = OWSP + 256 * 256;     // u [128][256]        W2
constexpr int OWVP = OW2P + 128 * 256;     // u [128][64]         wv
constexpr int OWRP = OWVP + 128 * 64;      // u [128][128]        wr
constexpr int OWQT = OWRP + 128 * 128;     // f32 [256][64] wq^T
constexpr int OWKT = OWQT + 256 * 64;      // f32 wk^T
constexpr int OWUT = OWKT + 256 * 64;      // f32 wu^T
constexpr int OWET = OWUT + 256 * 64;      // f32 [o][co] 64x128
constexpr int OWTF = OWET + 64 * 128;      // u  wt A-frags  [mt8][ks8][l64]x4u
constexpr int OAWF = OWTF + 16384;         // u  am_w1 A-frags [mt16][ks2][l64]x4u
constexpr int OPWF = OAWF + 8192;          // u  pm_w2 A-frags [mt4][ks2][l64]x4u
constexpr int OPW1 = OPWF + 2048;          // pm_w1 [ph][3]
constexpr int OB1  = OPW1 + 192;           // mv_b1 [256]
constexpr int OBS2 = OB1 + 256;            // mv_bs + mv_b2 [256]
constexpr int OBQ  = OBS2 + 256;
constexpr int OBK  = OBQ + 64;
constexpr int OBV  = OBK + 64;
constexpr int OBU  = OBV + 64;
constexpr int OBR  = OBU + 64;             // [128]
constexpr int OBE  = OBR + 128;            // [128]
constexpr int OPB1 = OBE + 128;            // [64]
constexpr int OPSC = OPB1 + 64;
constexpr int OPSH = OPSC + 64;
constexpr int OPB2 = OPSH + 64;
constexpr int OASC = OPB2 + 64;            // [256]
constexpr int OASH = OASC + 256;
constexpr int OAB1 = OASH + 256;
constexpr int OABT = OAB1 + 256;           // [64]

// ---- workspace byte offsets (28 MiB total) ----
constexpr size_t OFFB_WF   = 0;
constexpr size_t OFFB_IDX  = (size_t)2 << 20;
constexpr size_t OFFB_Q    = (size_t)4 << 20;   // [b][n][64]
constexpr size_t OFFB_K    = (size_t)8 << 20;   // [b][n][64]
constexpr size_t OFFB_U    = (size_t)12 << 20;  // [b][n][64]
constexpr size_t OFFB_V    = (size_t)16 << 20;  // [b][n][64]
constexpr size_t OFFB_IDEN = (size_t)20 << 20;  // [b][n][128]

struct InPtrs { const float* p[38]; };

// ---- f16 helpers ----
typedef _Float16 half2_t __attribute__((ext_vector_type(2)));
typedef _Float16 f16x8_t __attribute__((ext_vector_type(8)));
typedef float    f32x4_t __attribute__((ext_vector_type(4)));

union U4H8 { uint4 u; f16x8_t h; };

__device__ __forceinline__ float fdot2_(half2_t a, half2_t b, float c) {
  return __builtin_amdgcn_fdot2(a, b, c, false);
}
__device__ __forceinline__ unsigned pkh2(float a, float b) {
  union { unsigned u; half2_t h; } x;
  x.h = half2_t{(_Float16)a, (_Float16)b};
  return x.u;
}
__device__ __forceinline__ half2_t h2u(unsigned u) {
  union { unsigned u; half2_t h; } x;
  x.u = u;
  return x.h;
}
__device__ __forceinline__ f32x4_t mfma_16x16x32(f16x8_t a, f16x8_t b, f32x4_t c) {
  return __builtin_amdgcn_mfma_f32_16x16x32_f16(a, b, c, 0, 0, 0);
}

// ------------------------------------------------------------------
// Weight prep: f16 packs for mv, MFMA A-fragment packs for attn,
// f32 transposes, BN folds.
// A-fragment order (16x16x32): lane l: row m = l&15, k = (l>>4)*8+j.
// Frag f stored as 4 consecutive u32 (8 f16).
// ------------------------------------------------------------------
__global__ __launch_bounds__(256) void k_prep(InPtrs in, float* __restrict__ wf) {
  const int tid = blockIdx.x * 256 + threadIdx.x;
  const int nth = gridDim.x * 256;
  const float *mv_w1 = in.p[4], *mv_b1 = in.p[5], *mv_w2 = in.p[6], *mv_b2 = in.p[7],
              *mv_ws = in.p[8], *mv_bs = in.p[9], *wk = in.p[10], *bk = in.p[11],
              *wq = in.p[12], *bq = in.p[13], *wv = in.p[14], *bv = in.p[15],
              *wu = in.p[16], *bu = in.p[17], *pm_w1 = in.p[18], *pm_b1 = in.p[19],
              *pm_g = in.p[20], *pm_be = in.p[21], *pm_m = in.p[22], *pm_v = in.p[23],
              *pm_w2 = in.p[24], *pm_b2 = in.p[25], *am_w1 = in.p[26], *am_b1 = in.p[27],
              *am_g = in.p[28], *am_be = in.p[29], *am_m = in.p[30], *am_v = in.p[31],
              *am_wt = in.p[32], *am_bt = in.p[33], *we = in.p[34], *be = in.p[35],
              *wr = in.p[36], *br = in.p[37];

  // mv-path packed weights: [k2][ch] = half2(W[ch][2k2], W[ch][2k2+1])
  {
    unsigned* w1p = (unsigned*)(wf + OW1P);
    for (int i = tid; i < 256 * 256; i += nth) {
      int k2 = i >> 8, ch = i & 255;
      w1p[i] = pkh2(mv_w1[ch * 512 + 2 * k2], mv_w1[ch * 512 + 2 * k2 + 1]);
    }
    unsigned* wsp = (unsigned*)(wf + OWSP);
    for (int i = tid; i < 256 * 256; i += nth) {
      int k2 = i >> 8, ch = i & 255;
      wsp[i] = pkh2(mv_ws[ch * 512 + 2 * k2], mv_ws[ch * 512 + 2 * k2 + 1]);
    }
    unsigned* w2p = (unsigned*)(wf + OW2P);
    for (int i = tid; i < 128 * 256; i += nth) {
      int k2 = i >> 8, ch = i & 255;
      w2p[i] = pkh2(mv_w2[ch * 256 + 2 * k2], mv_w2[ch * 256 + 2 * k2 + 1]);
    }
    unsigned* wvp = (unsigned*)(wf + OWVP);
    for (int i = tid; i < 128 * 64; i += nth) {
      int k2 = i >> 6, ch = i & 63;
      wvp[i] = pkh2(wv[ch * 256 + 2 * k2], wv[ch * 256 + 2 * k2 + 1]);
    }
    unsigned* wrp = (unsigned*)(wf + OWRP);
    for (int i = tid; i < 128 * 128; i += nth) {
      int k2 = i >> 7, ch = i & 127;
      wrp[i] = pkh2(wr[ch * 256 + 2 * k2], wr[ch * 256 + 2 * k2 + 1]);
    }
  }
  for (int i = tid; i < 256 * 64; i += nth) { int c = i >> 6, m = i & 63; wf[OWQT + i] = wq[m * 256 + c]; }
  for (int i = tid; i < 256 * 64; i += nth) { int c = i >> 6, m = i & 63; wf[OWKT + i] = wk[m * 256 + c]; }
  for (int i = tid; i < 256 * 64; i += nth) { int c = i >> 6, m = i & 63; wf[OWUT + i] = wu[m * 256 + c]; }
  for (int i = tid; i < 64 * 128; i += nth) { int o = i >> 7, co = i & 127; wf[OWET + i] = we[co * 64 + o]; }

  // wt A-frags: A[or(128)][c(256)], mt<8, ks<8: i = ((mt*8+ks)*64+l)*4+q
  {
    unsigned* wtf = (unsigned*)(wf + OWTF);
    for (int i = tid; i < 16384; i += nth) {
      int q = i & 3, l = (i >> 2) & 63, ks = (i >> 8) & 7, mt = i >> 11;
      int orr = mt * 16 + (l & 15);
      int c = ks * 32 + ((l >> 4) << 3) + 2 * q;
      wtf[i] = pkh2(am_wt[c * 128 + orr], am_wt[(c + 1) * 128 + orr]);
    }
  }
  // am_w1 A-frags: A[c(256)][o(64)], mt<16, ks<2: i = ((mt*2+ks)*64+l)*4+q
  {
    unsigned* awf = (unsigned*)(wf + OAWF);
    for (int i = tid; i < 8192; i += nth) {
      int q = i & 3, l = (i >> 2) & 63, ks = (i >> 8) & 1, mt = i >> 9;
      int c = mt * 16 + (l & 15);
      int o = ks * 32 + ((l >> 4) << 3) + 2 * q;
      awf[i] = pkh2(am_w1[c * 64 + o], am_w1[c * 64 + o + 1]);
    }
  }
  // pm_w2 A-frags: A[o(64)][ph(64)], mt<4, ks<2: i = ((mt*2+ks)*64+l)*4+q
  {
    unsigned* pwf = (unsigned*)(wf + OPWF);
    for (int i = tid; i < 2048; i += nth) {
      int q = i & 3, l = (i >> 2) & 63, ks = (i >> 8) & 1, mt = i >> 9;
      int o = mt * 16 + (l & 15);
      int ph = ks * 32 + ((l >> 4) << 3) + 2 * q;
      pwf[i] = pkh2(pm_w2[o * 64 + ph], pm_w2[o * 64 + ph + 1]);
    }
  }
  for (int i = tid; i < 192; i += nth) wf[OPW1 + i] = pm_w1[i];
  for (int i = tid; i < 256; i += nth) {
    wf[OB1 + i] = mv_b1[i];
    wf[OBS2 + i] = mv_bs[i] + mv_b2[i];
    float sc = am_g[i] / sqrtf(am_v[i] + EPS_);
    wf[OASC + i] = sc;
    wf[OASH + i] = am_be[i] - am_m[i] * sc;
    wf[OAB1 + i] = am_b1[i];
  }
  for (int i = tid; i < 64; i += nth) {
    wf[OBQ + i] = bq[i]; wf[OBK + i] = bk[i];
    wf[OBV + i] = bv[i]; wf[OBU + i] = bu[i];
    wf[OABT + i] = am_bt[i]; wf[OPB1 + i] = pm_b1[i]; wf[OPB2 + i] = pm_b2[i];
    float sc = pm_g[i] / sqrtf(pm_v[i] + EPS_);
    wf[OPSC + i] = sc;
    wf[OPSH + i] = pm_be[i] - pm_m[i] * sc;
  }
  for (int i = tid; i < 128; i += nth) { wf[OBR + i] = br[i]; wf[OBE + i] = be[i]; }
}

// ------------------------------------------------------------------
// Fused mv-MLP + v/iden projections (unchanged).
// ------------------------------------------------------------------
__global__ __launch_bounds__(256, 2) void k_mv(const float* __restrict__ wf,
                                               const float* __restrict__ keyf,
                                               const float* __restrict__ qryf,
                                               float* __restrict__ vout,
                                               float* __restrict__ idenout) {
  const int b = blockIdx.y;
  const int n0 = blockIdx.x * 32;
  __shared__ __align__(16) unsigned hidP[128][32];
  __shared__ __align__(16) unsigned scP[128][32];
  __shared__ __align__(16) unsigned xsP[8][32];
  const int tid = threadIdx.x;
  const int tn = tid & 3, tm = tid >> 2;
  const int col8 = tn * 8, ch4 = tm * 4;

  float acch[4][8] = {};
  float accs[4][8] = {};
  {
    const unsigned* w1g = (const unsigned*)(wf + OW1P) + ch4;
    const unsigned* wsg = (const unsigned*)(wf + OWSP) + ch4;
    const int k2l = tid >> 5, cstage = tid & 31;
    for (int kt2 = 0; kt2 < 256; kt2 += 8) {
      int c = 2 * (kt2 + k2l);
      const float* s = (c < 256) ? keyf : qryf;
      size_t base = ((size_t)b * 256 + (c & 255)) * N_ + n0 + cstage;
      float xr0 = s[base], xr1 = s[base + N_];
      __syncthreads();
      xsP[k2l][cstage] = pkh2(xr0, xr1);
      __syncthreads();
#pragma unroll
      for (int k2 = 0; k2 < 8; ++k2) {
        uint4 w1v = *(const uint4*)(w1g + (size_t)(kt2 + k2) * 256);
        uint4 wsv = *(const uint4*)(wsg + (size_t)(kt2 + k2) * 256);
        uint4 xa = *(const uint4*)&xsP[k2][col8];
        uint4 xb = *(const uint4*)&xsP[k2][col8 + 4];
        const unsigned xu[8] = {xa.x, xa.y, xa.z, xa.w, xb.x, xb.y, xb.z, xb.w};
        const unsigned w1u[4] = {w1v.x, w1v.y, w1v.z, w1v.w};
        const unsigned wsu[4] = {wsv.x, wsv.y, wsv.z, wsv.w};
#pragma unroll
        for (int i = 0; i < 4; ++i) {
          half2_t w1h = h2u(w1u[i]), wsh = h2u(wsu[i]);
#pragma unroll
          for (int j = 0; j < 8; ++j) {
            half2_t xh = h2u(xu[j]);
            acch[i][j] = fdot2_(xh, w1h, acch[i][j]);
            accs[i][j] = fdot2_(xh, wsh, accs[i][j]);
          }
        }
      }
    }
  }
  {
    float b1v[4], bsv[4];
#pragma unroll
    for (int i = 0; i < 4; ++i) { b1v[i] = wf[OB1 + ch4 + i]; bsv[i] = wf[OBS2 + ch4 + i]; }
#pragma unroll
    for (int j = 0; j < 8; ++j) {
      hidP[tm * 2][col8 + j] =
          pkh2(fmaxf(acch[0][j] + b1v[0], 0.f), fmaxf(acch[1][j] + b1v[1], 0.f));
      hidP[tm * 2 + 1][col8 + j] =
          pkh2(fmaxf(acch[2][j] + b1v[2], 0.f), fmaxf(acch[3][j] + b1v[3], 0.f));
      scP[tm * 2][col8 + j] = pkh2(accs[0][j] + bsv[0], accs[1][j] + bsv[1]);
      scP[tm * 2 + 1][col8 + j] = pkh2(accs[2][j] + bsv[2], accs[3][j] + bsv[3]);
    }
  }
  __syncthreads();

  {
    float acc2[4][8] = {};
    const unsigned* w2g = (const unsigned*)(wf + OW2P) + ch4;
#pragma unroll 4
    for (int k2 = 0; k2 < 128; ++k2) {
      uint4 w2v = *(const uint4*)(w2g + (size_t)k2 * 256);
      uint4 xa = *(const uint4*)&hidP[k2][col8];
      uint4 xb = *(const uint4*)&hidP[k2][col8 + 4];
      const unsigned xu[8] = {xa.x, xa.y, xa.z, xa.w, xb.x, xb.y, xb.z, xb.w};
      const unsigned w2u[4] = {w2v.x, w2v.y, w2v.z, w2v.w};
#pragma unroll
      for (int i = 0; i < 4; ++i) {
        half2_t wh = h2u(w2u[i]);
#pragma unroll
        for (int j = 0; j < 8; ++j)
          acc2[i][j] = fdot2_(h2u(xu[j]), wh, acc2[i][j]);
      }
    }
#pragma unroll
    for (int j = 0; j < 8; ++j) {
      half2_t s0 = h2u(scP[tm * 2][col8 + j]);
      half2_t s1 = h2u(scP[tm * 2 + 1][col8 + j]);
      scP[tm * 2][col8 + j] = pkh2(acc2[0][j] + (float)s0.x, acc2[1][j] + (float)s0.y);
      scP[tm * 2 + 1][col8 + j] = pkh2(acc2[2][j] + (float)s1.x, acc2[3][j] + (float)s1.y);
    }
  }
  __syncthreads();

  {
    const int tnR = tid & 7, tmR = tid >> 3;
    const int colR = tnR * 4, chR = tmR * 4;
    float accr[4][4] = {};
    const unsigned* wrg = (const unsigned*)(wf + OWRP) + chR;
#pragma unroll 8
    for (int k2 = 0; k2 < 128; ++k2) {
      uint4 wv4 = *(const uint4*)(wrg + (size_t)k2 * 128);
      uint4 xv = *(const uint4*)&scP[k2][colR];
      const unsigned xu[4] = {xv.x, xv.y, xv.z, xv.w};
      const unsigned wu_[4] = {wv4.x, wv4.y, wv4.z, wv4.w};
#pragma unroll
      for (int i = 0; i < 4; ++i) {
        half2_t wh = h2u(wu_[i]);
#pragma unroll
        for (int j = 0; j < 4; ++j)
          accr[i][j] = fdot2_(h2u(xu[j]), wh, accr[i][j]);
      }
    }
#pragma unroll
    for (int j = 0; j < 4; ++j) {
      *(float4*)(idenout + ((size_t)b * N_ + n0 + colR + j) * 128 + chR) =
          make_float4(accr[0][j] + wf[OBR + chR], accr[1][j] + wf[OBR + chR + 1],
                      accr[2][j] + wf[OBR + chR + 2], accr[3][j] + wf[OBR + chR + 3]);
    }
  }

  {
    const int tnV = tid & 15, tmV = tid >> 4;
    const int colV = tnV * 2, chV = tmV * 4;
    float accv[4][2] = {};
    const unsigned* wvg = (const unsigned*)(wf + OWVP) + chV;
#pragma unroll 8
    for (int k2 = 0; k2 < 128; ++k2) {
      uint4 wv4 = *(const uint4*)(wvg + (size_t)k2 * 64);
      uint2 xv = *(const uint2*)&scP[k2][colV];
      const unsigned wu_[4] = {wv4.x, wv4.y, wv4.z, wv4.w};
#pragma unroll
      for (int i = 0; i < 4; ++i) {
        half2_t wh = h2u(wu_[i]);
        accv[i][0] = fdot2_(h2u(xv.x), wh, accv[i][0]);
        accv[i][1] = fdot2_(h2u(xv.y), wh, accv[i][1]);
      }
    }
#pragma unroll
    for (int j = 0; j < 2; ++j) {
      *(float4*)(vout + ((size_t)b * N_ + n0 + colV + j) * 64 + chV) =
          make_float4(accv[0][j] + wf[OBV + chV], accv[1][j] + wf[OBV + chV + 1],
                      accv[2][j] + wf[OBV + chV + 2], accv[3][j] + wf[OBV + chV + 3]);
    }
  }
}

// ------------------------------------------------------------------
// q/k/u projections (unchanged).
// ------------------------------------------------------------------
struct Gx { const float* x0; const float* x1; const float* x2;
            float* o0; float* o1; float* o2; };

__global__ __launch_bounds__(256) void k_gemm64x3(const float* __restrict__ wf, Gx g) {
  const int b = blockIdx.z;
  const int n0 = blockIdx.x * 64;
  const int y = blockIdx.y;
  const float* Wt = wf + OWQT + y * (256 * 64);
  const float* bias = wf + OBQ + ((y == 2) ? 3 : y) * 64;
  const float* x = (y == 0) ? g.x0 : (y == 1) ? g.x1 : g.x2;
  float* out = (y == 0) ? g.o0 : (y == 1) ? g.o1 : g.o2;
  __shared__ float ws_[16][64];
  __shared__ float xs_[16][64];
  const int tid = threadIdx.x, tm = tid & 15, tn = tid >> 4;
  float acc[4][4] = {};
  for (int kt = 0; kt < 256; kt += 16) {
    for (int i = tid; i < 1024; i += 256) {
      int kk = i >> 6, col = i & 63;
      ws_[kk][col] = Wt[(size_t)(kt + kk) * 64 + col];
      xs_[kk][col] = x[((size_t)b * 256 + kt + kk) * N_ + n0 + col];
    }
    __syncthreads();
#pragma unroll
    for (int kk = 0; kk < 16; ++kk) {
      float4 x4 = *(const float4*)&xs_[kk][tn * 4];
      float4 w4 = *(const float4*)&ws_[kk][tm * 4];
      float wv[4] = {w4.x, w4.y, w4.z, w4.w};
      float xv[4] = {x4.x, x4.y, x4.z, x4.w};
#pragma unroll
      for (int i = 0; i < 4; ++i)
#pragma unroll
        for (int j = 0; j < 4; ++j) acc[i][j] += wv[i] * xv[j];
    }
    __syncthreads();
  }
#pragma unroll
  for (int j = 0; j < 4; ++j) {
    *(float4*)(out + ((size_t)b * N_ + n0 + tn * 4 + j) * 64 + tm * 4) =
        make_float4(acc[0][j] + bias[tm * 4], acc[1][j] + bias[tm * 4 + 1],
                    acc[2][j] + bias[tm * 4 + 2], acc[3][j] + bias[tm * 4 + 3]);
  }
}

// ------------------------------------------------------------------
// Self-KNN v5: threshold+sort replaces 20 serial extractions.
// Keys as v4 (fp64-bit monotone u64, low 11 bits = index, unique).
//  1) lane-min of 8 keys; bitonic-sort 64 lane-mins; T = s[19].
//     The 20 sorted minima are 20 distinct actual keys <= T, so any
//     key > T has >=20 keys below it => all true top-20 keys <= T.
//  2) count+scan {keys<=T}; compact C candidates (C>=20, ~25-35)
//     to LDS; pad to 64 with ~0; bitonic-sort; lanes 0-19 emit.
//  3) C>64 (pathological): per-wave fallback to 20-round extraction
//     (no block barrier in divergent region; join at __syncthreads).
// Phase B rank-merge unchanged.
// ------------------------------------------------------------------
__device__ __forceinline__ unsigned long long bitonic64_(unsigned long long v,
                                                         int lane) {
#pragma unroll
  for (int k = 2; k <= 64; k <<= 1) {
#pragma unroll
    for (int j = k >> 1; j > 0; j >>= 1) {
      unsigned long long o = (unsigned long long)__shfl_xor((long long)v, j);
      bool up = (lane & k) == 0;       // k==64: always true -> ascending
      bool lower = (lane & j) == 0;
      bool keepmin = (lower == up);
      unsigned long long mn = o < v ? o : v;
      unsigned long long mx = o < v ? v : o;
      v = keepmin ? mn : mx;
    }
  }
  return v;
}

__global__ __launch_bounds__(256, 8) void k_knn(const float* __restrict__ pos,
                                                int* __restrict__ idxout) {
  const int b = blockIdx.x >> 11, n = blockIdx.x & 2047;
  __shared__ unsigned long long wkeys[4][20];
  __shared__ unsigned long long cand[4][64];
  const int tid = threadIdx.x;
  const int lane = tid & 63, wv = tid >> 6;
  const float* pb = pos + (size_t)b * 3 * N_;
  const double xq = pb[n], yq = pb[N_ + n], zq = pb[2 * N_ + n];
  const double sq = xq * xq + yq * yq + zq * zq;
  unsigned long long key[8];
#pragma unroll
  for (int s = 0; s < 8; ++s) {
    int i = tid + s * 256;
    double x = pb[i], y = pb[N_ + i], z = pb[2 * N_ + i];
    double psq = x * x + y * y + z * z;
    double dot = xq * x + yq * y + zq * z;
    double d2 = fmax((sq + psq) - 2.0 * dot, 0.0);
    key[s] = ((unsigned long long)__double_as_longlong(d2) & ~0x7FFull) |
             (unsigned long long)i;
  }
  // lane-min of 8
  unsigned long long m = key[0];
#pragma unroll
  for (int s = 1; s < 8; ++s) m = key[s] < m ? key[s] : m;

  // sort 64 lane-mins; T = 20th smallest
  unsigned long long v = bitonic64_(m, lane);
  unsigned long long T = (unsigned long long)__shfl((long long)v, 19);

  // count keys <= T, wave prefix-scan
  int c = 0;
#pragma unroll
  for (int s = 0; s < 8; ++s) c += (key[s] <= T) ? 1 : 0;
  int inc = c;
#pragma unroll
  for (int d = 1; d < 64; d <<= 1) {
    int t = __shfl_up(inc, d);
    if (lane >= d) inc += t;
  }
  const int C = __shfl(inc, 63);
  const int off = inc - c;

  if (C <= 64) {
    int o2 = off;
#pragma unroll
    for (int s = 0; s < 8; ++s) {
      if (key[s] <= T) { cand[wv][o2] = key[s]; ++o2; }
    }
    __builtin_amdgcn_wave_barrier();
    asm volatile("s_waitcnt lgkmcnt(0)" ::: "memory");
    unsigned long long cv = (lane < C) ? cand[wv][lane] : ~0ull;
    cv = bitonic64_(cv, lane);
    if (lane < K_) wkeys[wv][lane] = cv;
  } else {
    // rare fallback: plain 20-round extraction (exact, same output)
    for (int r = 0; r < K_; ++r) {
      unsigned long long bk = key[0];
#pragma unroll
      for (int s = 1; s < 8; ++s) bk = key[s] < bk ? key[s] : bk;
      unsigned long long wk = bk;
#pragma unroll
      for (int mm = 32; mm; mm >>= 1) {
        unsigned long long ok = (unsigned long long)__shfl_xor((long long)wk, mm);
        if (ok < wk) wk = ok;
      }
      if (lane == 0) wkeys[wv][r] = wk;
      const int widx = (int)(wk & 0x7FF);
#pragma unroll
      for (int s = 0; s < 8; ++s)
        if (widx == tid + s * 256) key[s] = ~0ull;
    }
  }
  __syncthreads();

  // Phase B: rank-merge of 4 sorted 20-lists (all keys unique)
  if (tid < 128) {
    const int w = tid >> 5, p = tid & 31;
    if (p < 20) {
      const unsigned long long Kk = wkeys[w][p];
      int rank = p;
#pragma unroll
      for (int w2 = 0; w2 < 4; ++w2) {
        if (w2 == w) continue;
        int lo = 0, hi = 20;
        while (lo < hi) {
          int mid = (lo + hi) >> 1;
          if (wkeys[w2][mid] < Kk) lo = mid + 1; else hi = mid;
        }
        rank += lo;
      }
      if (rank < K_)
        idxout[((size_t)b * N_ + n) * K_ + rank] = (int)(Kk & 0x7FF);
    }
  }
}

// ------------------------------------------------------------------
// Fused attention tail v5 (unchanged): P3/P4/P5 on MFMA (16x16x32 f16).
// ------------------------------------------------------------------
__global__ __launch_bounds__(256, 4) void k_attn(
    const float* __restrict__ wf,
    const float* __restrict__ qb, const float* __restrict__ kb,
    const float* __restrict__ vb, const float* __restrict__ ub,
    const float* __restrict__ idenb, const int* __restrict__ idxb,
    const float* __restrict__ pos, float* __restrict__ out) {
  const int lb = ((int)blockIdx.x & 7) * 2048 + ((int)blockIdx.x >> 3);
  const int b = lb >> 11, n = lb & 2047;
  const int tid = threadIdx.x;
  const int lane = tid & 63, wid = tid >> 6;

  __shared__ __align__(16) char smem[26512];
  char*  Sb   = smem;
  char*  hb   = smem + 4096;
  char*  t1b  = smem + 4096;
  char*  peb  = smem + 8192;
  float* lg   = (float*)(smem + 4096);
  float* sVal = (float*)(smem + 20480);
  float* aggs = (float*)(smem + 25680);
  int*   idxs = (int*)(smem + 26192);
  float* prx  = (float*)(smem + 26272);
  float* pry  = (float*)(smem + 26352);
  float* prz  = (float*)(smem + 26432);

  if (tid < 20) idxs[tid] = idxb[((size_t)b * N_ + n) * K_ + tid] & 2047;
  __syncthreads();

  // P1: coalesced gathers; S and V stay in registers until P3b
  float sreg[5], vreg[5];
  {
    size_t rowq = ((size_t)b * N_ + n) * 64;
    float qvo = qb[rowq + lane];
    float ufo = ub[rowq + lane];
#pragma unroll
    for (int t = 0; t < 5; ++t) {
      int kk = wid * 5 + t;
      int j = idxs[kk];
      size_t rowj = ((size_t)b * N_ + j) * 64;
      float kvv = kb[rowj + lane], vvv = vb[rowj + lane], uvv = ub[rowj + lane];
      float ur = ufo - uvv;
      sreg[t] = (qvo - kvv) + ur;
      vreg[t] = vvv + ur;
    }
    if (tid < 20) {
      int j = idxs[tid];
      const float* pp = pos + (size_t)b * 3 * N_;
      prx[tid] = pp[n] - pp[j];
      pry[tid] = pp[N_ + n] - pp[N_ + j];
      prz[tid] = pp[2 * N_ + n] - pp[2 * N_ + j];
    }
  }
  __syncthreads();

  // P2: pos-MLP layer1 + BN + relu -> t1 f16 [k][ph] swz
  {
    int ph = lane;
    float w0 = wf[OPW1 + ph * 3], w1 = wf[OPW1 + ph * 3 + 1], w2 = wf[OPW1 + ph * 3 + 2];
    float pb1 = wf[OPB1 + ph], sc = wf[OPSC + ph], sh = wf[OPSH + ph];
#pragma unroll
    for (int t = 0; t < 5; ++t) {
      int kk = wid * 5 + t;
      float u = pb1 + w0 * prx[kk] + w1 * pry[kk] + w2 * prz[kk];
      float tv = fmaxf(u * sc + sh, 0.f);
      *(_Float16*)(t1b + ((kk * 128 + ph * 2) ^ ((kk & 7) << 4))) = (_Float16)tv;
    }
  }
  __syncthreads();

  // P3a: pe = pm_w2 @ t1 via MFMA (M=64: mt=wid), write pe f32 [k][o] swz
  {
    f32x4_t pacc[2];
#pragma unroll
    for (int nt = 0; nt < 2; ++nt) pacc[nt] = f32x4_t{0.f, 0.f, 0.f, 0.f};
    const int mt = wid;
#pragma unroll
    for (int ks = 0; ks < 2; ++ks) {
      U4H8 a;
      a.u = ((const uint4*)((const unsigned*)(wf + OPWF)))[(mt * 2 + ks) * 64 + lane];
#pragma unroll
      for (int nt = 0; nt < 2; ++nt) {
        int kc = nt * 16 + (lane & 15);
        U4H8 bu;
        bu.u = *(const uint4*)(t1b + ((kc * 128 + (ks * 32 + ((lane >> 4) << 3)) * 2) ^ ((kc & 7) << 4)));
        pacc[nt] = mfma_16x16x32(a.h, bu.h, pacc[nt]);
      }
    }
    const int o0 = mt * 16 + ((lane >> 4) << 2);
    float4 pb2v = *(const float4*)(wf + OPB2 + o0);
#pragma unroll
    for (int nt = 0; nt < 2; ++nt) {
      int kc = nt * 16 + (lane & 15);
      if (kc < 20) {
        float4 o;
        o.x = pacc[nt][0] + pb2v.x; o.y = pacc[nt][1] + pb2v.y;
        o.z = pacc[nt][2] + pb2v.z; o.w = pacc[nt][3] + pb2v.w;
        *(float4*)(peb + ((kc * 256 + o0 * 4) ^ ((kc & 7) << 4))) = o;
      }
    }
  }
  __syncthreads();

  // P3b: fold pe into S (f16 [k][o] swz) and sVal (f32)
  {
#pragma unroll
    for (int t = 0; t < 5; ++t) {
      int kk = wid * 5 + t;
      float pe = *(const float*)(peb + ((kk * 256 + lane * 4) ^ ((kk & 7) << 4)));
      float sv = sreg[t] + pe;
      float vv = vreg[t] + pe;
      sVal[kk * 65 + lane] = vv;
      *(_Float16*)(Sb + ((kk * 128 + lane * 2) ^ ((kk & 7) << 4))) = (_Float16)sv;
    }
  }
  __syncthreads();

  // P4: h = relu(bn(am_w1 @ S)) via MFMA (M=256: 4 mt/wave, 2 passes)
#pragma unroll
  for (int pass = 0; pass < 2; ++pass) {
    const int mt0 = wid * 4 + pass * 2;
    f32x4_t acc[2][2];
#pragma unroll
    for (int m = 0; m < 2; ++m)
#pragma unroll
      for (int nt = 0; nt < 2; ++nt) acc[m][nt] = f32x4_t{0.f, 0.f, 0.f, 0.f};
#pragma unroll
    for (int ks = 0; ks < 2; ++ks) {
      U4H8 bfr[2];
#pragma unroll
      for (int nt = 0; nt < 2; ++nt) {
        int kc = nt * 16 + (lane & 15);
        bfr[nt].u = *(const uint4*)(Sb + ((kc * 128 + (ks * 32 + ((lane >> 4) << 3)) * 2) ^ ((kc & 7) << 4)));
      }
#pragma unroll
      for (int m = 0; m < 2; ++m) {
        U4H8 a;
        a.u = ((const uint4*)((const unsigned*)(wf + OAWF)))[((mt0 + m) * 2 + ks) * 64 + lane];
#pragma unroll
        for (int nt = 0; nt < 2; ++nt)
          acc[m][nt] = mfma_16x16x32(a.h, bfr[nt].h, acc[m][nt]);
      }
    }
#pragma unroll
    for (int m = 0; m < 2; ++m) {
      const int c0 = (mt0 + m) * 16 + ((lane >> 4) << 2);
      float4 ab1 = *(const float4*)(wf + OAB1 + c0);
      float4 asc = *(const float4*)(wf + OASC + c0);
      float4 ash = *(const float4*)(wf + OASH + c0);
#pragma unroll
      for (int nt = 0; nt < 2; ++nt) {
        int kc = nt * 16 + (lane & 15);
        if (kc < 20) {
          float h0 = fmaxf((acc[m][nt][0] + ab1.x) * asc.x + ash.x, 0.f);
          float h1 = fmaxf((acc[m][nt][1] + ab1.y) * asc.y + ash.y, 0.f);
          float h2 = fmaxf((acc[m][nt][2] + ab1.z) * asc.z + ash.z, 0.f);
          float h3 = fmaxf((acc[m][nt][3] + ab1.w) * asc.w + ash.w, 0.f);
          uint2 p;
          p.x = pkh2(h0, h1);
          p.y = pkh2(h2, h3);
          *(uint2*)(hb + ((kc * 512 + c0 * 2) ^ ((kc & 7) << 4))) = p;
        }
      }
    }
  }
  __syncthreads();

  // P5: lg = wt @ h via MFMA (M=128: 2 mt/wave, K=256: 8 ks)
  {
    f32x4_t acc5[2][2];
#pragma unroll
    for (int m = 0; m < 2; ++m)
#pragma unroll
      for (int nt = 0; nt < 2; ++nt) acc5[m][nt] = f32x4_t{0.f, 0.f, 0.f, 0.f};
#pragma unroll
    for (int ks = 0; ks < 8; ++ks) {
      U4H8 bfr[2];
#pragma unroll
      for (int nt = 0; nt < 2; ++nt) {
        int kc = nt * 16 + (lane & 15);
        bfr[nt].u = *(const uint4*)(hb + ((kc * 512 + (ks * 32 + ((lane >> 4) << 3)) * 2) ^ ((kc & 7) << 4)));
      }
#pragma unroll
      for (int m = 0; m < 2; ++m) {
        U4H8 a;
        a.u = ((const uint4*)((const unsigned*)(wf + OWTF)))[((wid * 2 + m) * 8 + ks) * 64 + lane];
#pragma unroll
        for (int nt = 0; nt < 2; ++nt)
          acc5[m][nt] = mfma_16x16x32(a.h, bfr[nt].h, acc5[m][nt]);
      }
    }
    __syncthreads();  // all h reads done before lg overlays the region
#pragma unroll
    for (int m = 0; m < 2; ++m) {
      const int or0 = (wid * 2 + m) * 16 + ((lane >> 4) << 2);
#pragma unroll
      for (int nt = 0; nt < 2; ++nt) {
        int kc = nt * 16 + (lane & 15);
        if (kc < 20) {
#pragma unroll
          for (int r = 0; r < 4; ++r) lg[kc * 129 + or0 + r] = acc5[m][nt][r];
        }
      }
    }
  }
  __syncthreads();

  // P6: softmax over k + aggregate with val
  if (tid < 128) {
    int orr = tid, o = orr >> 1;
    float l[20];
#pragma unroll
    for (int kk = 0; kk < 20; ++kk) l[kk] = lg[kk * 129 + orr];
    float bt = wf[OABT + o];
    float m = -3.4e38f;
#pragma unroll
    for (int kk = 0; kk < 20; ++kk) { l[kk] += bt; m = fmaxf(m, l[kk]); }
    float s = 0.f;
#pragma unroll
    for (int kk = 0; kk < 20; ++kk) { l[kk] = expf(l[kk] - m); s += l[kk]; }
    float inv = 1.f / s;
    float a = 0.f;
#pragma unroll
    for (int kk = 0; kk < 20; ++kk) a += l[kk] * sVal[kk * 65 + o];
    aggs[orr] = a * inv;
  }
  __syncthreads();

  // P7: y = we @ agg + be + iden
  {
    int co = tid & 127, r = tid >> 7;
    float idv = idenb[((size_t)b * N_ + n) * 128 + co];
    float y = wf[OBE + co];
    const float* w = wf + OWET + co;
#pragma unroll 4
    for (int o = 0; o < 64; ++o) y += w[o * 128] * aggs[o * 2 + r];
    out[((size_t)b * 128 + co) * (size_t)(2 * N_) + 2 * n + r] = y + idv;
  }
}

extern "C" void kernel_launch(void* const* d_in, const int* in_sizes, int n_in,
                              void* d_out, int out_size, void* d_ws, size_t ws_size,
                              hipStream_t stream) {
  (void)in_sizes; (void)n_in; (void)out_size; (void)ws_size;
  InPtrs ip;
  for (int i = 0; i < 38; ++i) ip.p[i] = (const float*)d_in[i];
  char* ws = (char*)d_ws;
  float* wf    = (float*)(ws + OFFB_WF);
  int*   idxb  = (int*)(ws + OFFB_IDX);
  float* qb    = (float*)(ws + OFFB_Q);
  float* kb    = (float*)(ws + OFFB_K);
  float* ubuf  = (float*)(ws + OFFB_U);
  float* vbuf  = (float*)(ws + OFFB_V);
  float* idenb = (float*)(ws + OFFB_IDEN);

  k_prep<<<dim3(256), dim3(256), 0, stream>>>(ip, wf);
  k_mv<<<dim3(64, 8), dim3(256), 0, stream>>>(wf, ip.p[1], ip.p[2], vbuf, idenb);
  Gx g{ip.p[2], ip.p[1], ip.p[3], qb, kb, ubuf};
  k_gemm64x3<<<dim3(32, 3, 8), dim3(256), 0, stream>>>(wf, g);
  k_knn<<<dim3(B_ * N_), dim3(256), 0, stream>>>(ip.p[0], idxb);
  k_attn<<<dim3(B_ * N_), dim3(256), 0, stream>>>(wf, qb, kb, vbuf, ubuf, idenb, idxb,
                                                  ip.p[0], (float*)d_out);
}

// Round 10
// 448.446 us; speedup vs baseline: 4.2019x; 1.2193x over previous
//
#include <hip/hip_runtime.h>
#include <hip/hip_bf16.h>

constexpr int B_ = 8, N_ = 2048, K_ = 20;
constexpr float EPS_ = 1e-5f;

// ---- weight area offsets (float slots; "u" = uint32 of packed half2) ----
// mv/q/k matrices stored as MFMA A-fragments (16x16x32 f16):
// frag index ((mt*KS+ks)*64+l)*4+q -> m = mt*16+(l&15), k = ks*32+(l>>4)*8+2q
constexpr int OW1P = 0;                    // u W1 frags  mt16 ks16 = 65536u
constexpr int OWSP = OW1P + 256 * 256;     // u Ws frags  65536u
constexpr int OW2P = OWSP + 256 * 256;     // u W2 frags  mt16 ks8 = 32768u
constexpr int OWVP = OW2P + 128 * 256;     // u wv frags  mt4 ks8 = 8192u
constexpr int OWRP = OWVP + 128 * 64;      // u wr frags  mt8 ks8 = 16384u
constexpr int OWQT = OWRP + 128 * 128;     // u wq frags  mt4 ks8 = 8192u (slot 16384)
constexpr int OWKT = OWQT + 256 * 64;      // u wk frags  8192u (slot 16384)
constexpr int OWUT = OWKT + 256 * 64;      // f32 wu^T [256][64]
constexpr int OWET = OWUT + 256 * 64;      // f32 [o][co] 64x128
constexpr int OWTF = OWET + 64 * 128;      // u  wt A-frags  [mt8][ks8][l64]x4u
constexpr int OAWF = OWTF + 16384;         // u  am_w1 A-frags [mt16][ks2][l64]x4u
constexpr int OPWF = OAWF + 8192;          // u  pm_w2 A-frags [mt4][ks2][l64]x4u
constexpr int OPW1 = OPWF + 2048;          // pm_w1 [ph][3]
constexpr int OB1  = OPW1 + 192;           // mv_b1 [256]
constexpr int OBS2 = OB1 + 256;            // mv_bs + mv_b2 [256]
constexpr int OBQ  = OBS2 + 256;
constexpr int OBK  = OBQ + 64;
constexpr int OBV  = OBK + 64;
constexpr int OBU  = OBV + 64;
constexpr int OBR  = OBU + 64;             // [128]
constexpr int OBE  = OBR + 128;            // [128]
constexpr int OPB1 = OBE + 128;            // [64]
constexpr int OPSC = OPB1 + 64;
constexpr int OPSH = OPSC + 64;
constexpr int OPB2 = OPSH + 64;
constexpr int OASC = OPB2 + 64;            // [256]
constexpr int OASH = OASC + 256;
constexpr int OAB1 = OASH + 256;
constexpr int OABT = OAB1 + 256;           // [64]

// ---- workspace byte offsets (28 MiB total) ----
constexpr size_t OFFB_WF   = 0;
constexpr size_t OFFB_IDX  = (size_t)2 << 20;
constexpr size_t OFFB_Q    = (size_t)4 << 20;   // [b][n][64]
constexpr size_t OFFB_K    = (size_t)8 << 20;   // [b][n][64]
constexpr size_t OFFB_U    = (size_t)12 << 20;  // [b][n][64]
constexpr size_t OFFB_V    = (size_t)16 << 20;  // [b][n][64]
constexpr size_t OFFB_IDEN = (size_t)20 << 20;  // [b][n][128]

struct InPtrs { const float* p[38]; };

// ---- f16 helpers ----
typedef _Float16 half2_t __attribute__((ext_vector_type(2)));
typedef _Float16 f16x8_t __attribute__((ext_vector_type(8)));
typedef float    f32x4_t __attribute__((ext_vector_type(4)));

union U4H8 { uint4 u; f16x8_t h; };

__device__ __forceinline__ unsigned pkh2(float a, float b) {
  union { unsigned u; half2_t h; } x;
  x.h = half2_t{(_Float16)a, (_Float16)b};
  return x.u;
}
__device__ __forceinline__ f32x4_t mfma_16x16x32(f16x8_t a, f16x8_t b, f32x4_t c) {
  return __builtin_amdgcn_mfma_f32_16x16x32_f16(a, b, c, 0, 0, 0);
}

// ------------------------------------------------------------------
// Weight prep: MFMA A-fragment packs for mv/q/k/attn, f32 transposes,
// BN folds. A-fragment order (16x16x32): lane l: m = l&15,
// k = (l>>4)*8+2q{,+1}. Frag = 4 consecutive u32 (8 f16).
// ------------------------------------------------------------------
__global__ __launch_bounds__(256) void k_prep(InPtrs in, float* __restrict__ wf) {
  const int tid = blockIdx.x * 256 + threadIdx.x;
  const int nth = gridDim.x * 256;
  const float *mv_w1 = in.p[4], *mv_b1 = in.p[5], *mv_w2 = in.p[6], *mv_b2 = in.p[7],
              *mv_ws = in.p[8], *mv_bs = in.p[9], *wk = in.p[10], *bk = in.p[11],
              *wq = in.p[12], *bq = in.p[13], *wv = in.p[14], *bv = in.p[15],
              *wu = in.p[16], *bu = in.p[17], *pm_w1 = in.p[18], *pm_b1 = in.p[19],
              *pm_g = in.p[20], *pm_be = in.p[21], *pm_m = in.p[22], *pm_v = in.p[23],
              *pm_w2 = in.p[24], *pm_b2 = in.p[25], *am_w1 = in.p[26], *am_b1 = in.p[27],
              *am_g = in.p[28], *am_be = in.p[29], *am_m = in.p[30], *am_v = in.p[31],
              *am_wt = in.p[32], *am_bt = in.p[33], *we = in.p[34], *be = in.p[35],
              *wr = in.p[36], *br = in.p[37];

  // W1 (256x512): mt16 ks16
  {
    unsigned* w1f = (unsigned*)(wf + OW1P);
    for (int i = tid; i < 65536; i += nth) {
      int q = i & 3, l = (i >> 2) & 63, ks = (i >> 8) & 15, mt = i >> 12;
      int m = mt * 16 + (l & 15);
      int k = ks * 32 + ((l >> 4) << 3) + 2 * q;
      w1f[i] = pkh2(mv_w1[m * 512 + k], mv_w1[m * 512 + k + 1]);
    }
    unsigned* wsf = (unsigned*)(wf + OWSP);
    for (int i = tid; i < 65536; i += nth) {
      int q = i & 3, l = (i >> 2) & 63, ks = (i >> 8) & 15, mt = i >> 12;
      int m = mt * 16 + (l & 15);
      int k = ks * 32 + ((l >> 4) << 3) + 2 * q;
      wsf[i] = pkh2(mv_ws[m * 512 + k], mv_ws[m * 512 + k + 1]);
    }
    unsigned* w2f = (unsigned*)(wf + OW2P);
    for (int i = tid; i < 32768; i += nth) {
      int q = i & 3, l = (i >> 2) & 63, ks = (i >> 8) & 7, mt = i >> 11;
      int m = mt * 16 + (l & 15);
      int k = ks * 32 + ((l >> 4) << 3) + 2 * q;
      w2f[i] = pkh2(mv_w2[m * 256 + k], mv_w2[m * 256 + k + 1]);
    }
    unsigned* wvf = (unsigned*)(wf + OWVP);
    for (int i = tid; i < 8192; i += nth) {
      int q = i & 3, l = (i >> 2) & 63, ks = (i >> 8) & 7, mt = i >> 11;
      int m = mt * 16 + (l & 15);
      int k = ks * 32 + ((l >> 4) << 3) + 2 * q;
      wvf[i] = pkh2(wv[m * 256 + k], wv[m * 256 + k + 1]);
    }
    unsigned* wrf = (unsigned*)(wf + OWRP);
    for (int i = tid; i < 16384; i += nth) {
      int q = i & 3, l = (i >> 2) & 63, ks = (i >> 8) & 7, mt = i >> 11;
      int m = mt * 16 + (l & 15);
      int k = ks * 32 + ((l >> 4) << 3) + 2 * q;
      wrf[i] = pkh2(wr[m * 256 + k], wr[m * 256 + k + 1]);
    }
    unsigned* wqf = (unsigned*)(wf + OWQT);
    for (int i = tid; i < 8192; i += nth) {
      int q = i & 3, l = (i >> 2) & 63, ks = (i >> 8) & 7, mt = i >> 11;
      int m = mt * 16 + (l & 15);
      int k = ks * 32 + ((l >> 4) << 3) + 2 * q;
      wqf[i] = pkh2(wq[m * 256 + k], wq[m * 256 + k + 1]);
    }
    unsigned* wkf = (unsigned*)(wf + OWKT);
    for (int i = tid; i < 8192; i += nth) {
      int q = i & 3, l = (i >> 2) & 63, ks = (i >> 8) & 7, mt = i >> 11;
      int m = mt * 16 + (l & 15);
      int k = ks * 32 + ((l >> 4) << 3) + 2 * q;
      wkf[i] = pkh2(wk[m * 256 + k], wk[m * 256 + k + 1]);
    }
  }
  for (int i = tid; i < 256 * 64; i += nth) { int c = i >> 6, m = i & 63; wf[OWUT + i] = wu[m * 256 + c]; }
  for (int i = tid; i < 64 * 128; i += nth) { int o = i >> 7, co = i & 127; wf[OWET + i] = we[co * 64 + o]; }

  // wt A-frags: A[or(128)][c(256)], mt<8, ks<8
  {
    unsigned* wtf = (unsigned*)(wf + OWTF);
    for (int i = tid; i < 16384; i += nth) {
      int q = i & 3, l = (i >> 2) & 63, ks = (i >> 8) & 7, mt = i >> 11;
      int orr = mt * 16 + (l & 15);
      int c = ks * 32 + ((l >> 4) << 3) + 2 * q;
      wtf[i] = pkh2(am_wt[c * 128 + orr], am_wt[(c + 1) * 128 + orr]);
    }
  }
  // am_w1 A-frags: A[c(256)][o(64)], mt<16, ks<2
  {
    unsigned* awf = (unsigned*)(wf + OAWF);
    for (int i = tid; i < 8192; i += nth) {
      int q = i & 3, l = (i >> 2) & 63, ks = (i >> 8) & 1, mt = i >> 9;
      int c = mt * 16 + (l & 15);
      int o = ks * 32 + ((l >> 4) << 3) + 2 * q;
      awf[i] = pkh2(am_w1[c * 64 + o], am_w1[c * 64 + o + 1]);
    }
  }
  // pm_w2 A-frags: A[o(64)][ph(64)], mt<4, ks<2
  {
    unsigned* pwf = (unsigned*)(wf + OPWF);
    for (int i = tid; i < 2048; i += nth) {
      int q = i & 3, l = (i >> 2) & 63, ks = (i >> 8) & 1, mt = i >> 9;
      int o = mt * 16 + (l & 15);
      int ph = ks * 32 + ((l >> 4) << 3) + 2 * q;
      pwf[i] = pkh2(pm_w2[o * 64 + ph], pm_w2[o * 64 + ph + 1]);
    }
  }
  for (int i = tid; i < 192; i += nth) wf[OPW1 + i] = pm_w1[i];
  for (int i = tid; i < 256; i += nth) {
    wf[OB1 + i] = mv_b1[i];
    wf[OBS2 + i] = mv_bs[i] + mv_b2[i];
    float sc = am_g[i] / sqrtf(am_v[i] + EPS_);
    wf[OASC + i] = sc;
    wf[OASH + i] = am_be[i] - am_m[i] * sc;
    wf[OAB1 + i] = am_b1[i];
  }
  for (int i = tid; i < 64; i += nth) {
    wf[OBQ + i] = bq[i]; wf[OBK + i] = bk[i];
    wf[OBV + i] = bv[i]; wf[OBU + i] = bu[i];
    wf[OABT + i] = am_bt[i]; wf[OPB1 + i] = pm_b1[i]; wf[OPB2 + i] = pm_b2[i];
    float sc = pm_g[i] / sqrtf(pm_v[i] + EPS_);
    wf[OPSC + i] = sc;
    wf[OPSH + i] = pm_be[i] - pm_m[i] * sc;
  }
  for (int i = tid; i < 128; i += nth) { wf[OBR + i] = br[i]; wf[OBE + i] = be[i]; }
}

// ------------------------------------------------------------------
// Fused mv-MLP v3: all 5 mv GEMMs + q/k projections on MFMA.
// x staged once as f16 [32col][512k] swizzled B-tiles (32KB);
// GEMM1 W1+Ws fused (one xs read stream); q/k ride on xs for free
// (keyf = ks0-7, qryf = ks8-15); sc stays f32 in regs; hid/val f16
// LDS B-tiles. 48KB LDS -> 2 blocks/CU. Per wave ~400 MFMA vs
// ~23.5K fdot2 in v2.
// ------------------------------------------------------------------
__global__ __launch_bounds__(256, 2) void k_mv(const float* __restrict__ wf,
                                               const float* __restrict__ keyf,
                                               const float* __restrict__ qryf,
                                               float* __restrict__ vout,
                                               float* __restrict__ idenout,
                                               float* __restrict__ qout,
                                               float* __restrict__ kout) {
  const int b = blockIdx.y;
  const int n0 = blockIdx.x * 32;
  const int tid = threadIdx.x, lane = tid & 63, wid = tid >> 6;
  // LDS: xs f16[32][512] @0 (32KB, val overlays after GEMM2);
  //      hid f16[32][256] @32768 (16KB)
  __shared__ __align__(16) char smem[49152];
  char* xsb = smem;
  char* hbb = smem + 32768;
  char* vbb = smem;

  // stage xs: col = tid&31, kq = tid>>5; 32 iters over k-pairs
  {
    const int col = tid & 31, kq = tid >> 5;
    const int swz = (col & 7) << 4;
#pragma unroll 4
    for (int it = 0; it < 32; ++it) {
      int k2 = it * 8 + kq;
      int c = 2 * k2;  // even: c,c+1 same tensor
      const float* s = (c < 256) ? keyf : qryf;
      size_t base = ((size_t)b * 256 + (c & 255)) * N_ + n0 + col;
      float x0 = s[base], x1 = s[base + N_];
      *(unsigned*)(xsb + ((col * 1024 + k2 * 4) ^ swz)) = pkh2(x0, x1);
    }
  }
  __syncthreads();

  // GEMM1: acch = W1@x, accs = Ws@x (K=512, 16 ks)
  f32x4_t acch[4][2], accs[4][2];
#pragma unroll
  for (int m = 0; m < 4; ++m)
#pragma unroll
    for (int nt = 0; nt < 2; ++nt) {
      acch[m][nt] = f32x4_t{0.f, 0.f, 0.f, 0.f};
      accs[m][nt] = f32x4_t{0.f, 0.f, 0.f, 0.f};
    }
  {
    const uint4* w1f = (const uint4*)((const unsigned*)(wf + OW1P));
    const uint4* wsf = (const uint4*)((const unsigned*)(wf + OWSP));
#pragma unroll 2
    for (int ks = 0; ks < 16; ++ks) {
      U4H8 bu[2];
#pragma unroll
      for (int nt = 0; nt < 2; ++nt) {
        int col = nt * 16 + (lane & 15);
        bu[nt].u = *(const uint4*)(xsb + ((col * 1024 + ks * 64 + ((lane >> 4) << 4)) ^ ((col & 7) << 4)));
      }
#pragma unroll
      for (int m = 0; m < 4; ++m) {
        U4H8 a1, as_;
        a1.u = w1f[((wid * 4 + m) * 16 + ks) * 64 + lane];
        as_.u = wsf[((wid * 4 + m) * 16 + ks) * 64 + lane];
#pragma unroll
        for (int nt = 0; nt < 2; ++nt) {
          acch[m][nt] = mfma_16x16x32(a1.h, bu[nt].h, acch[m][nt]);
          accs[m][nt] = mfma_16x16x32(as_.h, bu[nt].h, accs[m][nt]);
        }
      }
    }
  }
  // epilogue1: hid = relu(acch + b1) -> hid LDS (f16, swz)
#pragma unroll
  for (int m = 0; m < 4; ++m) {
    int ch0 = (wid * 4 + m) * 16 + ((lane >> 4) << 2);
    float4 b1v = *(const float4*)(wf + OB1 + ch0);
#pragma unroll
    for (int nt = 0; nt < 2; ++nt) {
      int col = nt * 16 + (lane & 15);
      float h0 = fmaxf(acch[m][nt][0] + b1v.x, 0.f);
      float h1 = fmaxf(acch[m][nt][1] + b1v.y, 0.f);
      float h2 = fmaxf(acch[m][nt][2] + b1v.z, 0.f);
      float h3 = fmaxf(acch[m][nt][3] + b1v.w, 0.f);
      uint2 p;
      p.x = pkh2(h0, h1);
      p.y = pkh2(h2, h3);
      *(uint2*)(hbb + ((col * 512 + ch0 * 2) ^ ((col & 7) << 4))) = p;
    }
  }

  // q/k GEMMs while xs alive: k = wk@keyf (ks0-7), q = wq@qryf (ks8-15)
  {
    f32x4_t accq[2], acck[2];
#pragma unroll
    for (int nt = 0; nt < 2; ++nt) {
      accq[nt] = f32x4_t{0.f, 0.f, 0.f, 0.f};
      acck[nt] = f32x4_t{0.f, 0.f, 0.f, 0.f};
    }
    const uint4* wqf = (const uint4*)((const unsigned*)(wf + OWQT));
    const uint4* wkf = (const uint4*)((const unsigned*)(wf + OWKT));
#pragma unroll 2
    for (int ks8 = 0; ks8 < 8; ++ks8) {
      U4H8 bk_[2], bq_[2];
#pragma unroll
      for (int nt = 0; nt < 2; ++nt) {
        int col = nt * 16 + (lane & 15);
        int swz = (col & 7) << 4;
        bk_[nt].u = *(const uint4*)(xsb + ((col * 1024 + ks8 * 64 + ((lane >> 4) << 4)) ^ swz));
        bq_[nt].u = *(const uint4*)(xsb + ((col * 1024 + (8 + ks8) * 64 + ((lane >> 4) << 4)) ^ swz));
      }
      U4H8 aq, ak;
      aq.u = wqf[(wid * 8 + ks8) * 64 + lane];
      ak.u = wkf[(wid * 8 + ks8) * 64 + lane];
#pragma unroll
      for (int nt = 0; nt < 2; ++nt) {
        acck[nt] = mfma_16x16x32(ak.h, bk_[nt].h, acck[nt]);
        accq[nt] = mfma_16x16x32(aq.h, bq_[nt].h, accq[nt]);
      }
    }
    int ch0 = wid * 16 + ((lane >> 4) << 2);
    float4 bqv = *(const float4*)(wf + OBQ + ch0);
    float4 bkv = *(const float4*)(wf + OBK + ch0);
#pragma unroll
    for (int nt = 0; nt < 2; ++nt) {
      int col = nt * 16 + (lane & 15);
      *(float4*)(qout + ((size_t)b * N_ + n0 + col) * 64 + ch0) =
          make_float4(accq[nt][0] + bqv.x, accq[nt][1] + bqv.y,
                      accq[nt][2] + bqv.z, accq[nt][3] + bqv.w);
      *(float4*)(kout + ((size_t)b * N_ + n0 + col) * 64 + ch0) =
          make_float4(acck[nt][0] + bkv.x, acck[nt][1] + bkv.y,
                      acck[nt][2] + bkv.z, acck[nt][3] + bkv.w);
    }
  }
  __syncthreads();

  // GEMM2: acc2 = W2@hid (K=256, 8 ks); val = acc2 + accs + (bs+b2)
  {
    f32x4_t acc2[4][2];
#pragma unroll
    for (int m = 0; m < 4; ++m)
#pragma unroll
      for (int nt = 0; nt < 2; ++nt) acc2[m][nt] = f32x4_t{0.f, 0.f, 0.f, 0.f};
    const uint4* w2f = (const uint4*)((const unsigned*)(wf + OW2P));
#pragma unroll 2
    for (int ks = 0; ks < 8; ++ks) {
      U4H8 bu[2];
#pragma unroll
      for (int nt = 0; nt < 2; ++nt) {
        int col = nt * 16 + (lane & 15);
        bu[nt].u = *(const uint4*)(hbb + ((col * 512 + ks * 64 + ((lane >> 4) << 4)) ^ ((col & 7) << 4)));
      }
#pragma unroll
      for (int m = 0; m < 4; ++m) {
        U4H8 a2;
        a2.u = w2f[((wid * 4 + m) * 8 + ks) * 64 + lane];
#pragma unroll
        for (int nt = 0; nt < 2; ++nt)
          acc2[m][nt] = mfma_16x16x32(a2.h, bu[nt].h, acc2[m][nt]);
      }
    }
#pragma unroll
    for (int m = 0; m < 4; ++m) {
      int ch0 = (wid * 4 + m) * 16 + ((lane >> 4) << 2);
      float4 bsv = *(const float4*)(wf + OBS2 + ch0);
#pragma unroll
      for (int nt = 0; nt < 2; ++nt) {
        int col = nt * 16 + (lane & 15);
        float v0 = acc2[m][nt][0] + accs[m][nt][0] + bsv.x;
        float v1 = acc2[m][nt][1] + accs[m][nt][1] + bsv.y;
        float v2 = acc2[m][nt][2] + accs[m][nt][2] + bsv.z;
        float v3 = acc2[m][nt][3] + accs[m][nt][3] + bsv.w;
        uint2 p;
        p.x = pkh2(v0, v1);
        p.y = pkh2(v2, v3);
        *(uint2*)(vbb + ((col * 512 + ch0 * 2) ^ ((col & 7) << 4))) = p;
      }
    }
  }
  __syncthreads();

  // GEMM3 (v = wv@val, mt=wid) + GEMM4 (iden = wr@val, mt=wid*2+{0,1})
  {
    f32x4_t accv[2], accr[2][2];
#pragma unroll
    for (int nt = 0; nt < 2; ++nt) {
      accv[nt] = f32x4_t{0.f, 0.f, 0.f, 0.f};
      accr[0][nt] = f32x4_t{0.f, 0.f, 0.f, 0.f};
      accr[1][nt] = f32x4_t{0.f, 0.f, 0.f, 0.f};
    }
    const uint4* wvf = (const uint4*)((const unsigned*)(wf + OWVP));
    const uint4* wrf = (const uint4*)((const unsigned*)(wf + OWRP));
#pragma unroll 2
    for (int ks = 0; ks < 8; ++ks) {
      U4H8 bu[2];
#pragma unroll
      for (int nt = 0; nt < 2; ++nt) {
        int col = nt * 16 + (lane & 15);
        bu[nt].u = *(const uint4*)(vbb + ((col * 512 + ks * 64 + ((lane >> 4) << 4)) ^ ((col & 7) << 4)));
      }
      U4H8 av;
      av.u = wvf[(wid * 8 + ks) * 64 + lane];
#pragma unroll
      for (int nt = 0; nt < 2; ++nt)
        accv[nt] = mfma_16x16x32(av.h, bu[nt].h, accv[nt]);
#pragma unroll
      for (int m2 = 0; m2 < 2; ++m2) {
        U4H8 ar;
        ar.u = wrf[((wid * 2 + m2) * 8 + ks) * 64 + lane];
#pragma unroll
        for (int nt = 0; nt < 2; ++nt)
          accr[m2][nt] = mfma_16x16x32(ar.h, bu[nt].h, accr[m2][nt]);
      }
    }
    {
      int ch0 = wid * 16 + ((lane >> 4) << 2);
      float4 bvv = *(const float4*)(wf + OBV + ch0);
#pragma unroll
      for (int nt = 0; nt < 2; ++nt) {
        int col = nt * 16 + (lane & 15);
        *(float4*)(vout + ((size_t)b * N_ + n0 + col) * 64 + ch0) =
            make_float4(accv[nt][0] + bvv.x, accv[nt][1] + bvv.y,
                        accv[nt][2] + bvv.z, accv[nt][3] + bvv.w);
      }
    }
#pragma unroll
    for (int m2 = 0; m2 < 2; ++m2) {
      int ch0 = (wid * 2 + m2) * 16 + ((lane >> 4) << 2);
      float4 brv = *(const float4*)(wf + OBR + ch0);
#pragma unroll
      for (int nt = 0; nt < 2; ++nt) {
        int col = nt * 16 + (lane & 15);
        *(float4*)(idenout + ((size_t)b * N_ + n0 + col) * 128 + ch0) =
            make_float4(accr[m2][nt][0] + brv.x, accr[m2][nt][1] + brv.y,
                        accr[m2][nt][2] + brv.z, accr[m2][nt][3] + brv.w);
      }
    }
  }
}

// ------------------------------------------------------------------
// u projection only (q/k folded into k_mv). f32 path unchanged.
// ------------------------------------------------------------------
__global__ __launch_bounds__(256) void k_gemm_u(const float* __restrict__ wf,
                                                const float* __restrict__ x,
                                                float* __restrict__ out) {
  const int b = blockIdx.y;
  const int n0 = blockIdx.x * 64;
  const float* Wt = wf + OWUT;
  const float* bias = wf + OBU;
  __shared__ float ws_[16][64];
  __shared__ float xs_[16][64];
  const int tid = threadIdx.x, tm = tid & 15, tn = tid >> 4;
  float acc[4][4] = {};
  for (int kt = 0; kt < 256; kt += 16) {
    for (int i = tid; i < 1024; i += 256) {
      int kk = i >> 6, col = i & 63;
      ws_[kk][col] = Wt[(size_t)(kt + kk) * 64 + col];
      xs_[kk][col] = x[((size_t)b * 256 + kt + kk) * N_ + n0 + col];
    }
    __syncthreads();
#pragma unroll
    for (int kk = 0; kk < 16; ++kk) {
      float4 x4 = *(const float4*)&xs_[kk][tn * 4];
      float4 w4 = *(const float4*)&ws_[kk][tm * 4];
      float wv[4] = {w4.x, w4.y, w4.z, w4.w};
      float xv[4] = {x4.x, x4.y, x4.z, x4.w};
#pragma unroll
      for (int i = 0; i < 4; ++i)
#pragma unroll
        for (int j = 0; j < 4; ++j) acc[i][j] += wv[i] * xv[j];
    }
    __syncthreads();
  }
#pragma unroll
  for (int j = 0; j < 4; ++j) {
    *(float4*)(out + ((size_t)b * N_ + n0 + tn * 4 + j) * 64 + tm * 4) =
        make_float4(acc[0][j] + bias[tm * 4], acc[1][j] + bias[tm * 4 + 1],
                    acc[2][j] + bias[tm * 4 + 2], acc[3][j] + bias[tm * 4 + 3]);
  }
}

// ------------------------------------------------------------------
// Self-KNN v5 (unchanged): threshold + bitonic sort, exact.
// ------------------------------------------------------------------
__device__ __forceinline__ unsigned long long bitonic64_(unsigned long long v,
                                                         int lane) {
#pragma unroll
  for (int k = 2; k <= 64; k <<= 1) {
#pragma unroll
    for (int j = k >> 1; j > 0; j >>= 1) {
      unsigned long long o = (unsigned long long)__shfl_xor((long long)v, j);
      bool up = (lane & k) == 0;
      bool lower = (lane & j) == 0;
      bool keepmin = (lower == up);
      unsigned long long mn = o < v ? o : v;
      unsigned long long mx = o < v ? v : o;
      v = keepmin ? mn : mx;
    }
  }
  return v;
}

__global__ __launch_bounds__(256, 8) void k_knn(const float* __restrict__ pos,
                                                int* __restrict__ idxout) {
  const int b = blockIdx.x >> 11, n = blockIdx.x & 2047;
  __shared__ unsigned long long wkeys[4][20];
  __shared__ unsigned long long cand[4][64];
  const int tid = threadIdx.x;
  const int lane = tid & 63, wv = tid >> 6;
  const float* pb = pos + (size_t)b * 3 * N_;
  const double xq = pb[n], yq = pb[N_ + n], zq = pb[2 * N_ + n];
  const double sq = xq * xq + yq * yq + zq * zq;
  unsigned long long key[8];
#pragma unroll
  for (int s = 0; s < 8; ++s) {
    int i = tid + s * 256;
    double x = pb[i], y = pb[N_ + i], z = pb[2 * N_ + i];
    double psq = x * x + y * y + z * z;
    double dot = xq * x + yq * y + zq * z;
    double d2 = fmax((sq + psq) - 2.0 * dot, 0.0);
    key[s] = ((unsigned long long)__double_as_longlong(d2) & ~0x7FFull) |
             (unsigned long long)i;
  }
  unsigned long long m = key[0];
#pragma unroll
  for (int s = 1; s < 8; ++s) m = key[s] < m ? key[s] : m;

  unsigned long long v = bitonic64_(m, lane);
  unsigned long long T = (unsigned long long)__shfl((long long)v, 19);

  int c = 0;
#pragma unroll
  for (int s = 0; s < 8; ++s) c += (key[s] <= T) ? 1 : 0;
  int inc = c;
#pragma unroll
  for (int d = 1; d < 64; d <<= 1) {
    int t = __shfl_up(inc, d);
    if (lane >= d) inc += t;
  }
  const int C = __shfl(inc, 63);
  const int off = inc - c;

  if (C <= 64) {
    int o2 = off;
#pragma unroll
    for (int s = 0; s < 8; ++s) {
      if (key[s] <= T) { cand[wv][o2] = key[s]; ++o2; }
    }
    __builtin_amdgcn_wave_barrier();
    asm volatile("s_waitcnt lgkmcnt(0)" ::: "memory");
    unsigned long long cv = (lane < C) ? cand[wv][lane] : ~0ull;
    cv = bitonic64_(cv, lane);
    if (lane < K_) wkeys[wv][lane] = cv;
  } else {
    for (int r = 0; r < K_; ++r) {
      unsigned long long bk = key[0];
#pragma unroll
      for (int s = 1; s < 8; ++s) bk = key[s] < bk ? key[s] : bk;
      unsigned long long wk = bk;
#pragma unroll
      for (int mm = 32; mm; mm >>= 1) {
        unsigned long long ok = (unsigned long long)__shfl_xor((long long)wk, mm);
        if (ok < wk) wk = ok;
      }
      if (lane == 0) wkeys[wv][r] = wk;
      const int widx = (int)(wk & 0x7FF);
#pragma unroll
      for (int s = 0; s < 8; ++s)
        if (widx == tid + s * 256) key[s] = ~0ull;
    }
  }
  __syncthreads();

  if (tid < 128) {
    const int w = tid >> 5, p = tid & 31;
    if (p < 20) {
      const unsigned long long Kk = wkeys[w][p];
      int rank = p;
#pragma unroll
      for (int w2 = 0; w2 < 4; ++w2) {
        if (w2 == w) continue;
        int lo = 0, hi = 20;
        while (lo < hi) {
          int mid = (lo + hi) >> 1;
          if (wkeys[w2][mid] < Kk) lo = mid + 1; else hi = mid;
        }
        rank += lo;
      }
      if (rank < K_)
        idxout[((size_t)b * N_ + n) * K_ + rank] = (int)(Kk & 0x7FF);
    }
  }
}

// ------------------------------------------------------------------
// Fused attention tail v5 (unchanged): P3/P4/P5 on MFMA (16x16x32 f16).
// ------------------------------------------------------------------
__global__ __launch_bounds__(256, 4) void k_attn(
    const float* __restrict__ wf,
    const float* __restrict__ qb, const float* __restrict__ kb,
    const float* __restrict__ vb, const float* __restrict__ ub,
    const float* __restrict__ idenb, const int* __restrict__ idxb,
    const float* __restrict__ pos, float* __restrict__ out) {
  const int lb = ((int)blockIdx.x & 7) * 2048 + ((int)blockIdx.x >> 3);
  const int b = lb >> 11, n = lb & 2047;
  const int tid = threadIdx.x;
  const int lane = tid & 63, wid = tid >> 6;

  __shared__ __align__(16) char smem[26512];
  char*  Sb   = smem;
  char*  hb   = smem + 4096;
  char*  t1b  = smem + 4096;
  char*  peb  = smem + 8192;
  float* lg   = (float*)(smem + 4096);
  float* sVal = (float*)(smem + 20480);
  float* aggs = (float*)(smem + 25680);
  int*   idxs = (int*)(smem + 26192);
  float* prx  = (float*)(smem + 26272);
  float* pry  = (float*)(smem + 26352);
  float* prz  = (float*)(smem + 26432);

  if (tid < 20) idxs[tid] = idxb[((size_t)b * N_ + n) * K_ + tid] & 2047;
  __syncthreads();

  float sreg[5], vreg[5];
  {
    size_t rowq = ((size_t)b * N_ + n) * 64;
    float qvo = qb[rowq + lane];
    float ufo = ub[rowq + lane];
#pragma unroll
    for (int t = 0; t < 5; ++t) {
      int kk = wid * 5 + t;
      int j = idxs[kk];
      size_t rowj = ((size_t)b * N_ + j) * 64;
      float kvv = kb[rowj + lane], vvv = vb[rowj + lane], uvv = ub[rowj + lane];
      float ur = ufo - uvv;
      sreg[t] = (qvo - kvv) + ur;
      vreg[t] = vvv + ur;
    }
    if (tid < 20) {
      int j = idxs[tid];
      const float* pp = pos + (size_t)b * 3 * N_;
      prx[tid] = pp[n] - pp[j];
      pry[tid] = pp[N_ + n] - pp[N_ + j];
      prz[tid] = pp[2 * N_ + n] - pp[2 * N_ + j];
    }
  }
  __syncthreads();

  {
    int ph = lane;
    float w0 = wf[OPW1 + ph * 3], w1 = wf[OPW1 + ph * 3 + 1], w2 = wf[OPW1 + ph * 3 + 2];
    float pb1 = wf[OPB1 + ph], sc = wf[OPSC + ph], sh = wf[OPSH + ph];
#pragma unroll
    for (int t = 0; t < 5; ++t) {
      int kk = wid * 5 + t;
      float u = pb1 + w0 * prx[kk] + w1 * pry[kk] + w2 * prz[kk];
      float tv = fmaxf(u * sc + sh, 0.f);
      *(_Float16*)(t1b + ((kk * 128 + ph * 2) ^ ((kk & 7) << 4))) = (_Float16)tv;
    }
  }
  __syncthreads();

  {
    f32x4_t pacc[2];
#pragma unroll
    for (int nt = 0; nt < 2; ++nt) pacc[nt] = f32x4_t{0.f, 0.f, 0.f, 0.f};
    const int mt = wid;
#pragma unroll
    for (int ks = 0; ks < 2; ++ks) {
      U4H8 a;
      a.u = ((const uint4*)((const unsigned*)(wf + OPWF)))[(mt * 2 + ks) * 64 + lane];
#pragma unroll
      for (int nt = 0; nt < 2; ++nt) {
        int kc = nt * 16 + (lane & 15);
        U4H8 bu;
        bu.u = *(const uint4*)(t1b + ((kc * 128 + (ks * 32 + ((lane >> 4) << 3)) * 2) ^ ((kc & 7) << 4)));
        pacc[nt] = mfma_16x16x32(a.h, bu.h, pacc[nt]);
      }
    }
    const int o0 = mt * 16 + ((lane >> 4) << 2);
    float4 pb2v = *(const float4*)(wf + OPB2 + o0);
#pragma unroll
    for (int nt = 0; nt < 2; ++nt) {
      int kc = nt * 16 + (lane & 15);
      if (kc < 20) {
        float4 o;
        o.x = pacc[nt][0] + pb2v.x; o.y = pacc[nt][1] + pb2v.y;
        o.z = pacc[nt][2] + pb2v.z; o.w = pacc[nt][3] + pb2v.w;
        *(float4*)(peb + ((kc * 256 + o0 * 4) ^ ((kc & 7) << 4))) = o;
      }
    }
  }
  __syncthreads();

  {
#pragma unroll
    for (int t = 0; t < 5; ++t) {
      int kk = wid * 5 + t;
      float pe = *(const float*)(peb + ((kk * 256 + lane * 4) ^ ((kk & 7) << 4)));
      float sv = sreg[t] + pe;
      float vv = vreg[t] + pe;
      sVal[kk * 65 + lane] = vv;
      *(_Float16*)(Sb + ((kk * 128 + lane * 2) ^ ((kk & 7) << 4))) = (_Float16)sv;
    }
  }
  __syncthreads();

#pragma unroll
  for (int pass = 0; pass < 2; ++pass) {
    const int mt0 = wid * 4 + pass * 2;
    f32x4_t acc[2][2];
#pragma unroll
    for (int m = 0; m < 2; ++m)
#pragma unroll
      for (int nt = 0; nt < 2; ++nt) acc[m][nt] = f32x4_t{0.f, 0.f, 0.f, 0.f};
#pragma unroll
    for (int ks = 0; ks < 2; ++ks) {
      U4H8 bfr[2];
#pragma unroll
      for (int nt = 0; nt < 2; ++nt) {
        int kc = nt * 16 + (lane & 15);
        bfr[nt].u = *(const uint4*)(Sb + ((kc * 128 + (ks * 32 + ((lane >> 4) << 3)) * 2) ^ ((kc & 7) << 4)));
      }
#pragma unroll
      for (int m = 0; m < 2; ++m) {
        U4H8 a;
        a.u = ((const uint4*)((const unsigned*)(wf + OAWF)))[((mt0 + m) * 2 + ks) * 64 + lane];
#pragma unroll
        for (int nt = 0; nt < 2; ++nt)
          acc[m][nt] = mfma_16x16x32(a.h, bfr[nt].h, acc[m][nt]);
      }
    }
#pragma unroll
    for (int m = 0; m < 2; ++m) {
      const int c0 = (mt0 + m) * 16 + ((lane >> 4) << 2);
      float4 ab1 = *(const float4*)(wf + OAB1 + c0);
      float4 asc = *(const float4*)(wf + OASC + c0);
      float4 ash = *(const float4*)(wf + OASH + c0);
#pragma unroll
      for (int nt = 0; nt < 2; ++nt) {
        int kc = nt * 16 + (lane & 15);
        if (kc < 20) {
          float h0 = fmaxf((acc[m][nt][0] + ab1.x) * asc.x + ash.x, 0.f);
          float h1 = fmaxf((acc[m][nt][1] + ab1.y) * asc.y + ash.y, 0.f);
          float h2 = fmaxf((acc[m][nt][2] + ab1.z) * asc.z + ash.z, 0.f);
          float h3 = fmaxf((acc[m][nt][3] + ab1.w) * asc.w + ash.w, 0.f);
          uint2 p;
          p.x = pkh2(h0, h1);
          p.y = pkh2(h2, h3);
          *(uint2*)(hb + ((kc * 512 + c0 * 2) ^ ((kc & 7) << 4))) = p;
        }
      }
    }
  }
  __syncthreads();

  {
    f32x4_t acc5[2][2];
#pragma unroll
    for (int m = 0; m < 2; ++m)
#pragma unroll
      for (int nt = 0; nt < 2; ++nt) acc5[m][nt] = f32x4_t{0.f, 0.f, 0.f, 0.f};
#pragma unroll
    for (int ks = 0; ks < 8; ++ks) {
      U4H8 bfr[2];
#pragma unroll
      for (int nt = 0; nt < 2; ++nt) {
        int kc = nt * 16 + (lane & 15);
        bfr[nt].u = *(const uint4*)(hb + ((kc * 512 + (ks * 32 + ((lane >> 4) << 3)) * 2) ^ ((kc & 7) << 4)));
      }
#pragma unroll
      for (int m = 0; m < 2; ++m) {
        U4H8 a;
        a.u = ((const uint4*)((const unsigned*)(wf + OWTF)))[((wid * 2 + m) * 8 + ks) * 64 + lane];
#pragma unroll
        for (int nt = 0; nt < 2; ++nt)
          acc5[m][nt] = mfma_16x16x32(a.h, bfr[nt].h, acc5[m][nt]);
      }
    }
    __syncthreads();
#pragma unroll
    for (int m = 0; m < 2; ++m) {
      const int or0 = (wid * 2 + m) * 16 + ((lane >> 4) << 2);
#pragma unroll
      for (int nt = 0; nt < 2; ++nt) {
        int kc = nt * 16 + (lane & 15);
        if (kc < 20) {
#pragma unroll
          for (int r = 0; r < 4; ++r) lg[kc * 129 + or0 + r] = acc5[m][nt][r];
        }
      }
    }
  }
  __syncthreads();

  if (tid < 128) {
    int orr = tid, o = orr >> 1;
    float l[20];
#pragma unroll
    for (int kk = 0; kk < 20; ++kk) l[kk] = lg[kk * 129 + orr];
    float bt = wf[OABT + o];
    float m = -3.4e38f;
#pragma unroll
    for (int kk = 0; kk < 20; ++kk) { l[kk] += bt; m = fmaxf(m, l[kk]); }
    float s = 0.f;
#pragma unroll
    for (int kk = 0; kk < 20; ++kk) { l[kk] = expf(l[kk] - m); s += l[kk]; }
    float inv = 1.f / s;
    float a = 0.f;
#pragma unroll
    for (int kk = 0; kk < 20; ++kk) a += l[kk] * sVal[kk * 65 + o];
    aggs[orr] = a * inv;
  }
  __syncthreads();

  {
    int co = tid & 127, r = tid >> 7;
    float idv = idenb[((size_t)b * N_ + n) * 128 + co];
    float y = wf[OBE + co];
    const float* w = wf + OWET + co;
#pragma unroll 4
    for (int o = 0; o < 64; ++o) y += w[o * 128] * aggs[o * 2 + r];
    out[((size_t)b * 128 + co) * (size_t)(2 * N_) + 2 * n + r] = y + idv;
  }
}

extern "C" void kernel_launch(void* const* d_in, const int* in_sizes, int n_in,
                              void* d_out, int out_size, void* d_ws, size_t ws_size,
                              hipStream_t stream) {
  (void)in_sizes; (void)n_in; (void)out_size; (void)ws_size;
  InPtrs ip;
  for (int i = 0; i < 38; ++i) ip.p[i] = (const float*)d_in[i];
  char* ws = (char*)d_ws;
  float* wf    = (float*)(ws + OFFB_WF);
  int*   idxb  = (int*)(ws + OFFB_IDX);
  float* qb    = (float*)(ws + OFFB_Q);
  float* kb    = (float*)(ws + OFFB_K);
  float* ubuf  = (float*)(ws + OFFB_U);
  float* vbuf  = (float*)(ws + OFFB_V);
  float* idenb = (float*)(ws + OFFB_IDEN);

  k_prep<<<dim3(256), dim3(256), 0, stream>>>(ip, wf);
  k_mv<<<dim3(64, 8), dim3(256), 0, stream>>>(wf, ip.p[1], ip.p[2], vbuf, idenb, qb, kb);
  k_gemm_u<<<dim3(32, 8), dim3(256), 0, stream>>>(wf, ip.p[3], ubuf);
  k_knn<<<dim3(B_ * N_), dim3(256), 0, stream>>>(ip.p[0], idxb);
  k_attn<<<dim3(B_ * N_), dim3(256), 0, stream>>>(wf, qb, kb, vbuf, ubuf, idenb, idxb,
                                                  ip.p[0], (float*)d_out);
}

// Round 11
// 436.862 us; speedup vs baseline: 4.3133x; 1.0265x over previous
//
#include <hip/hip_runtime.h>
#include <hip/hip_bf16.h>

constexpr int B_ = 8, N_ = 2048, K_ = 20;
constexpr float EPS_ = 1e-5f;

// ---- weight area offsets (float slots; "u" = uint32 of packed half2) ----
// mv/q/k matrices stored as MFMA A-fragments (16x16x32 f16):
// frag index ((mt*KS+ks)*64+l)*4+q -> m = mt*16+(l&15), k = ks*32+(l>>4)*8+2q
constexpr int OW1P = 0;                    // u W1 frags  mt16 ks16 = 65536u
constexpr int OWSP = OW1P + 256 * 256;     // u Ws frags  65536u
constexpr int OW2P = OWSP + 256 * 256;     // u W2 frags  mt16 ks8 = 32768u
constexpr int OWVP = OW2P + 128 * 256;     // u wv frags  mt4 ks8 = 8192u
constexpr int OWRP = OWVP + 128 * 64;      // u wr frags  mt8 ks8 = 16384u
constexpr int OWQT = OWRP + 128 * 128;     // u wq frags  mt4 ks8 = 8192u
constexpr int OWKT = OWQT + 256 * 64;      // u wk frags  8192u
constexpr int OWUT = OWKT + 256 * 64;      // f32 wu^T [256][64]
constexpr int OWET = OWUT + 256 * 64;      // f32 we NATIVE [co 128][o 64]
constexpr int OWTF = OWET + 64 * 128;      // u  wt A-frags  [mt8][ks8][l64]x4u
constexpr int OAWF = OWTF + 16384;         // u  am_w1 A-frags [mt16][ks2][l64]x4u
constexpr int OPWF = OAWF + 8192;          // u  pm_w2 A-frags [mt4][ks2][l64]x4u
constexpr int OPW1 = OPWF + 2048;          // pm_w1 [ph][3]
constexpr int OB1  = OPW1 + 192;           // mv_b1 [256]
constexpr int OBS2 = OB1 + 256;            // mv_bs + mv_b2 [256]
constexpr int OBQ  = OBS2 + 256;
constexpr int OBK  = OBQ + 64;
constexpr int OBV  = OBK + 64;
constexpr int OBU  = OBV + 64;
constexpr int OBR  = OBU + 64;             // [128]
constexpr int OBE  = OBR + 128;            // [128]
constexpr int OPB1 = OBE + 128;            // [64]
constexpr int OPSC = OPB1 + 64;
constexpr int OPSH = OPSC + 64;
constexpr int OPB2 = OPSH + 64;
constexpr int OASC = OPB2 + 64;            // [256]
constexpr int OASH = OASC + 256;
constexpr int OAB1 = OASH + 256;
constexpr int OABT = OAB1 + 256;           // [64]

// ---- workspace byte offsets (28 MiB total) ----
constexpr size_t OFFB_WF   = 0;
constexpr size_t OFFB_IDX  = (size_t)2 << 20;
constexpr size_t OFFB_Q    = (size_t)4 << 20;   // [b][n][64]
constexpr size_t OFFB_K    = (size_t)8 << 20;   // [b][n][64]
constexpr size_t OFFB_U    = (size_t)12 << 20;  // [b][n][64]
constexpr size_t OFFB_V    = (size_t)16 << 20;  // [b][n][64]
constexpr size_t OFFB_IDEN = (size_t)20 << 20;  // [b][n][128]

struct InPtrs { const float* p[38]; };

// ---- f16 helpers ----
typedef _Float16 half2_t __attribute__((ext_vector_type(2)));
typedef _Float16 f16x8_t __attribute__((ext_vector_type(8)));
typedef float    f32x4_t __attribute__((ext_vector_type(4)));

union U4H8 { uint4 u; f16x8_t h; };

__device__ __forceinline__ unsigned pkh2(float a, float b) {
  union { unsigned u; half2_t h; } x;
  x.h = half2_t{(_Float16)a, (_Float16)b};
  return x.u;
}
__device__ __forceinline__ f32x4_t mfma_16x16x32(f16x8_t a, f16x8_t b, f32x4_t c) {
  return __builtin_amdgcn_mfma_f32_16x16x32_f16(a, b, c, 0, 0, 0);
}

// ------------------------------------------------------------------
// Weight prep: MFMA A-fragment packs for mv/q/k/attn, f32 transposes,
// BN folds. A-fragment order (16x16x32): lane l: m = l&15,
// k = (l>>4)*8+2q{,+1}. Frag = 4 consecutive u32 (8 f16).
// ------------------------------------------------------------------
__global__ __launch_bounds__(256) void k_prep(InPtrs in, float* __restrict__ wf) {
  const int tid = blockIdx.x * 256 + threadIdx.x;
  const int nth = gridDim.x * 256;
  const float *mv_w1 = in.p[4], *mv_b1 = in.p[5], *mv_w2 = in.p[6], *mv_b2 = in.p[7],
              *mv_ws = in.p[8], *mv_bs = in.p[9], *wk = in.p[10], *bk = in.p[11],
              *wq = in.p[12], *bq = in.p[13], *wv = in.p[14], *bv = in.p[15],
              *wu = in.p[16], *bu = in.p[17], *pm_w1 = in.p[18], *pm_b1 = in.p[19],
              *pm_g = in.p[20], *pm_be = in.p[21], *pm_m = in.p[22], *pm_v = in.p[23],
              *pm_w2 = in.p[24], *pm_b2 = in.p[25], *am_w1 = in.p[26], *am_b1 = in.p[27],
              *am_g = in.p[28], *am_be = in.p[29], *am_m = in.p[30], *am_v = in.p[31],
              *am_wt = in.p[32], *am_bt = in.p[33], *we = in.p[34], *be = in.p[35],
              *wr = in.p[36], *br = in.p[37];

  {
    unsigned* w1f = (unsigned*)(wf + OW1P);
    for (int i = tid; i < 65536; i += nth) {
      int q = i & 3, l = (i >> 2) & 63, ks = (i >> 8) & 15, mt = i >> 12;
      int m = mt * 16 + (l & 15);
      int k = ks * 32 + ((l >> 4) << 3) + 2 * q;
      w1f[i] = pkh2(mv_w1[m * 512 + k], mv_w1[m * 512 + k + 1]);
    }
    unsigned* wsf = (unsigned*)(wf + OWSP);
    for (int i = tid; i < 65536; i += nth) {
      int q = i & 3, l = (i >> 2) & 63, ks = (i >> 8) & 15, mt = i >> 12;
      int m = mt * 16 + (l & 15);
      int k = ks * 32 + ((l >> 4) << 3) + 2 * q;
      wsf[i] = pkh2(mv_ws[m * 512 + k], mv_ws[m * 512 + k + 1]);
    }
    unsigned* w2f = (unsigned*)(wf + OW2P);
    for (int i = tid; i < 32768; i += nth) {
      int q = i & 3, l = (i >> 2) & 63, ks = (i >> 8) & 7, mt = i >> 11;
      int m = mt * 16 + (l & 15);
      int k = ks * 32 + ((l >> 4) << 3) + 2 * q;
      w2f[i] = pkh2(mv_w2[m * 256 + k], mv_w2[m * 256 + k + 1]);
    }
    unsigned* wvf = (unsigned*)(wf + OWVP);
    for (int i = tid; i < 8192; i += nth) {
      int q = i & 3, l = (i >> 2) & 63, ks = (i >> 8) & 7, mt = i >> 11;
      int m = mt * 16 + (l & 15);
      int k = ks * 32 + ((l >> 4) << 3) + 2 * q;
      wvf[i] = pkh2(wv[m * 256 + k], wv[m * 256 + k + 1]);
    }
    unsigned* wrf = (unsigned*)(wf + OWRP);
    for (int i = tid; i < 16384; i += nth) {
      int q = i & 3, l = (i >> 2) & 63, ks = (i >> 8) & 7, mt = i >> 11;
      int m = mt * 16 + (l & 15);
      int k = ks * 32 + ((l >> 4) << 3) + 2 * q;
      wrf[i] = pkh2(wr[m * 256 + k], wr[m * 256 + k + 1]);
    }
    unsigned* wqf = (unsigned*)(wf + OWQT);
    for (int i = tid; i < 8192; i += nth) {
      int q = i & 3, l = (i >> 2) & 63, ks = (i >> 8) & 7, mt = i >> 11;
      int m = mt * 16 + (l & 15);
      int k = ks * 32 + ((l >> 4) << 3) + 2 * q;
      wqf[i] = pkh2(wq[m * 256 + k], wq[m * 256 + k + 1]);
    }
    unsigned* wkf = (unsigned*)(wf + OWKT);
    for (int i = tid; i < 8192; i += nth) {
      int q = i & 3, l = (i >> 2) & 63, ks = (i >> 8) & 7, mt = i >> 11;
      int m = mt * 16 + (l & 15);
      int k = ks * 32 + ((l >> 4) << 3) + 2 * q;
      wkf[i] = pkh2(wk[m * 256 + k], wk[m * 256 + k + 1]);
    }
  }
  for (int i = tid; i < 256 * 64; i += nth) { int c = i >> 6, m = i & 63; wf[OWUT + i] = wu[m * 256 + c]; }
  for (int i = tid; i < 64 * 128; i += nth) wf[OWET + i] = we[i];  // native [co][o]

  // wt A-frags: A[or(128)][c(256)], mt<8, ks<8
  {
    unsigned* wtf = (unsigned*)(wf + OWTF);
    for (int i = tid; i < 16384; i += nth) {
      int q = i & 3, l = (i >> 2) & 63, ks = (i >> 8) & 7, mt = i >> 11;
      int orr = mt * 16 + (l & 15);
      int c = ks * 32 + ((l >> 4) << 3) + 2 * q;
      wtf[i] = pkh2(am_wt[c * 128 + orr], am_wt[(c + 1) * 128 + orr]);
    }
  }
  // am_w1 A-frags: A[c(256)][o(64)], mt<16, ks<2
  {
    unsigned* awf = (unsigned*)(wf + OAWF);
    for (int i = tid; i < 8192; i += nth) {
      int q = i & 3, l = (i >> 2) & 63, ks = (i >> 8) & 1, mt = i >> 9;
      int c = mt * 16 + (l & 15);
      int o = ks * 32 + ((l >> 4) << 3) + 2 * q;
      awf[i] = pkh2(am_w1[c * 64 + o], am_w1[c * 64 + o + 1]);
    }
  }
  // pm_w2 A-frags: A[o(64)][ph(64)], mt<4, ks<2
  {
    unsigned* pwf = (unsigned*)(wf + OPWF);
    for (int i = tid; i < 2048; i += nth) {
      int q = i & 3, l = (i >> 2) & 63, ks = (i >> 8) & 1, mt = i >> 9;
      int o = mt * 16 + (l & 15);
      int ph = ks * 32 + ((l >> 4) << 3) + 2 * q;
      pwf[i] = pkh2(pm_w2[o * 64 + ph], pm_w2[o * 64 + ph + 1]);
    }
  }
  for (int i = tid; i < 192; i += nth) wf[OPW1 + i] = pm_w1[i];
  for (int i = tid; i < 256; i += nth) {
    wf[OB1 + i] = mv_b1[i];
    wf[OBS2 + i] = mv_bs[i] + mv_b2[i];
    float sc = am_g[i] / sqrtf(am_v[i] + EPS_);
    wf[OASC + i] = sc;
    wf[OASH + i] = am_be[i] - am_m[i] * sc;
    wf[OAB1 + i] = am_b1[i];
  }
  for (int i = tid; i < 64; i += nth) {
    wf[OBQ + i] = bq[i]; wf[OBK + i] = bk[i];
    wf[OBV + i] = bv[i]; wf[OBU + i] = bu[i];
    wf[OABT + i] = am_bt[i]; wf[OPB1 + i] = pm_b1[i]; wf[OPB2 + i] = pm_b2[i];
    float sc = pm_g[i] / sqrtf(pm_v[i] + EPS_);
    wf[OPSC + i] = sc;
    wf[OPSH + i] = pm_be[i] - pm_m[i] * sc;
  }
  for (int i = tid; i < 128; i += nth) { wf[OBR + i] = br[i]; wf[OBE + i] = be[i]; }
}

// ------------------------------------------------------------------
// Fused mv-MLP v3 (unchanged): all 5 mv GEMMs + q/k on MFMA.
// ------------------------------------------------------------------
__global__ __launch_bounds__(256, 2) void k_mv(const float* __restrict__ wf,
                                               const float* __restrict__ keyf,
                                               const float* __restrict__ qryf,
                                               float* __restrict__ vout,
                                               float* __restrict__ idenout,
                                               float* __restrict__ qout,
                                               float* __restrict__ kout) {
  const int b = blockIdx.y;
  const int n0 = blockIdx.x * 32;
  const int tid = threadIdx.x, lane = tid & 63, wid = tid >> 6;
  __shared__ __align__(16) char smem[49152];
  char* xsb = smem;
  char* hbb = smem + 32768;
  char* vbb = smem;

  {
    const int col = tid & 31, kq = tid >> 5;
    const int swz = (col & 7) << 4;
#pragma unroll 4
    for (int it = 0; it < 32; ++it) {
      int k2 = it * 8 + kq;
      int c = 2 * k2;
      const float* s = (c < 256) ? keyf : qryf;
      size_t base = ((size_t)b * 256 + (c & 255)) * N_ + n0 + col;
      float x0 = s[base], x1 = s[base + N_];
      *(unsigned*)(xsb + ((col * 1024 + k2 * 4) ^ swz)) = pkh2(x0, x1);
    }
  }
  __syncthreads();

  f32x4_t acch[4][2], accs[4][2];
#pragma unroll
  for (int m = 0; m < 4; ++m)
#pragma unroll
    for (int nt = 0; nt < 2; ++nt) {
      acch[m][nt] = f32x4_t{0.f, 0.f, 0.f, 0.f};
      accs[m][nt] = f32x4_t{0.f, 0.f, 0.f, 0.f};
    }
  {
    const uint4* w1f = (const uint4*)((const unsigned*)(wf + OW1P));
    const uint4* wsf = (const uint4*)((const unsigned*)(wf + OWSP));
#pragma unroll 2
    for (int ks = 0; ks < 16; ++ks) {
      U4H8 bu[2];
#pragma unroll
      for (int nt = 0; nt < 2; ++nt) {
        int col = nt * 16 + (lane & 15);
        bu[nt].u = *(const uint4*)(xsb + ((col * 1024 + ks * 64 + ((lane >> 4) << 4)) ^ ((col & 7) << 4)));
      }
#pragma unroll
      for (int m = 0; m < 4; ++m) {
        U4H8 a1, as_;
        a1.u = w1f[((wid * 4 + m) * 16 + ks) * 64 + lane];
        as_.u = wsf[((wid * 4 + m) * 16 + ks) * 64 + lane];
#pragma unroll
        for (int nt = 0; nt < 2; ++nt) {
          acch[m][nt] = mfma_16x16x32(a1.h, bu[nt].h, acch[m][nt]);
          accs[m][nt] = mfma_16x16x32(as_.h, bu[nt].h, accs[m][nt]);
        }
      }
    }
  }
#pragma unroll
  for (int m = 0; m < 4; ++m) {
    int ch0 = (wid * 4 + m) * 16 + ((lane >> 4) << 2);
    float4 b1v = *(const float4*)(wf + OB1 + ch0);
#pragma unroll
    for (int nt = 0; nt < 2; ++nt) {
      int col = nt * 16 + (lane & 15);
      float h0 = fmaxf(acch[m][nt][0] + b1v.x, 0.f);
      float h1 = fmaxf(acch[m][nt][1] + b1v.y, 0.f);
      float h2 = fmaxf(acch[m][nt][2] + b1v.z, 0.f);
      float h3 = fmaxf(acch[m][nt][3] + b1v.w, 0.f);
      uint2 p;
      p.x = pkh2(h0, h1);
      p.y = pkh2(h2, h3);
      *(uint2*)(hbb + ((col * 512 + ch0 * 2) ^ ((col & 7) << 4))) = p;
    }
  }

  {
    f32x4_t accq[2], acck[2];
#pragma unroll
    for (int nt = 0; nt < 2; ++nt) {
      accq[nt] = f32x4_t{0.f, 0.f, 0.f, 0.f};
      acck[nt] = f32x4_t{0.f, 0.f, 0.f, 0.f};
    }
    const uint4* wqf = (const uint4*)((const unsigned*)(wf + OWQT));
    const uint4* wkf = (const uint4*)((const unsigned*)(wf + OWKT));
#pragma unroll 2
    for (int ks8 = 0; ks8 < 8; ++ks8) {
      U4H8 bk_[2], bq_[2];
#pragma unroll
      for (int nt = 0; nt < 2; ++nt) {
        int col = nt * 16 + (lane & 15);
        int swz = (col & 7) << 4;
        bk_[nt].u = *(const uint4*)(xsb + ((col * 1024 + ks8 * 64 + ((lane >> 4) << 4)) ^ swz));
        bq_[nt].u = *(const uint4*)(xsb + ((col * 1024 + (8 + ks8) * 64 + ((lane >> 4) << 4)) ^ swz));
      }
      U4H8 aq, ak;
      aq.u = wqf[(wid * 8 + ks8) * 64 + lane];
      ak.u = wkf[(wid * 8 + ks8) * 64 + lane];
#pragma unroll
      for (int nt = 0; nt < 2; ++nt) {
        acck[nt] = mfma_16x16x32(ak.h, bk_[nt].h, acck[nt]);
        accq[nt] = mfma_16x16x32(aq.h, bq_[nt].h, accq[nt]);
      }
    }
    int ch0 = wid * 16 + ((lane >> 4) << 2);
    float4 bqv = *(const float4*)(wf + OBQ + ch0);
    float4 bkv = *(const float4*)(wf + OBK + ch0);
#pragma unroll
    for (int nt = 0; nt < 2; ++nt) {
      int col = nt * 16 + (lane & 15);
      *(float4*)(qout + ((size_t)b * N_ + n0 + col) * 64 + ch0) =
          make_float4(accq[nt][0] + bqv.x, accq[nt][1] + bqv.y,
                      accq[nt][2] + bqv.z, accq[nt][3] + bqv.w);
      *(float4*)(kout + ((size_t)b * N_ + n0 + col) * 64 + ch0) =
          make_float4(acck[nt][0] + bkv.x, acck[nt][1] + bkv.y,
                      acck[nt][2] + bkv.z, acck[nt][3] + bkv.w);
    }
  }
  __syncthreads();

  {
    f32x4_t acc2[4][2];
#pragma unroll
    for (int m = 0; m < 4; ++m)
#pragma unroll
      for (int nt = 0; nt < 2; ++nt) acc2[m][nt] = f32x4_t{0.f, 0.f, 0.f, 0.f};
    const uint4* w2f = (const uint4*)((const unsigned*)(wf + OW2P));
#pragma unroll 2
    for (int ks = 0; ks < 8; ++ks) {
      U4H8 bu[2];
#pragma unroll
      for (int nt = 0; nt < 2; ++nt) {
        int col = nt * 16 + (lane & 15);
        bu[nt].u = *(const uint4*)(hbb + ((col * 512 + ks * 64 + ((lane >> 4) << 4)) ^ ((col & 7) << 4)));
      }
#pragma unroll
      for (int m = 0; m < 4; ++m) {
        U4H8 a2;
        a2.u = w2f[((wid * 4 + m) * 8 + ks) * 64 + lane];
#pragma unroll
        for (int nt = 0; nt < 2; ++nt)
          acc2[m][nt] = mfma_16x16x32(a2.h, bu[nt].h, acc2[m][nt]);
      }
    }
#pragma unroll
    for (int m = 0; m < 4; ++m) {
      int ch0 = (wid * 4 + m) * 16 + ((lane >> 4) << 2);
      float4 bsv = *(const float4*)(wf + OBS2 + ch0);
#pragma unroll
      for (int nt = 0; nt < 2; ++nt) {
        int col = nt * 16 + (lane & 15);
        float v0 = acc2[m][nt][0] + accs[m][nt][0] + bsv.x;
        float v1 = acc2[m][nt][1] + accs[m][nt][1] + bsv.y;
        float v2 = acc2[m][nt][2] + accs[m][nt][2] + bsv.z;
        float v3 = acc2[m][nt][3] + accs[m][nt][3] + bsv.w;
        uint2 p;
        p.x = pkh2(v0, v1);
        p.y = pkh2(v2, v3);
        *(uint2*)(vbb + ((col * 512 + ch0 * 2) ^ ((col & 7) << 4))) = p;
      }
    }
  }
  __syncthreads();

  {
    f32x4_t accv[2], accr[2][2];
#pragma unroll
    for (int nt = 0; nt < 2; ++nt) {
      accv[nt] = f32x4_t{0.f, 0.f, 0.f, 0.f};
      accr[0][nt] = f32x4_t{0.f, 0.f, 0.f, 0.f};
      accr[1][nt] = f32x4_t{0.f, 0.f, 0.f, 0.f};
    }
    const uint4* wvf = (const uint4*)((const unsigned*)(wf + OWVP));
    const uint4* wrf = (const uint4*)((const unsigned*)(wf + OWRP));
#pragma unroll 2
    for (int ks = 0; ks < 8; ++ks) {
      U4H8 bu[2];
#pragma unroll
      for (int nt = 0; nt < 2; ++nt) {
        int col = nt * 16 + (lane & 15);
        bu[nt].u = *(const uint4*)(vbb + ((col * 512 + ks * 64 + ((lane >> 4) << 4)) ^ ((col & 7) << 4)));
      }
      U4H8 av;
      av.u = wvf[(wid * 8 + ks) * 64 + lane];
#pragma unroll
      for (int nt = 0; nt < 2; ++nt)
        accv[nt] = mfma_16x16x32(av.h, bu[nt].h, accv[nt]);
#pragma unroll
      for (int m2 = 0; m2 < 2; ++m2) {
        U4H8 ar;
        ar.u = wrf[((wid * 2 + m2) * 8 + ks) * 64 + lane];
#pragma unroll
        for (int nt = 0; nt < 2; ++nt)
          accr[m2][nt] = mfma_16x16x32(ar.h, bu[nt].h, accr[m2][nt]);
      }
    }
    {
      int ch0 = wid * 16 + ((lane >> 4) << 2);
      float4 bvv = *(const float4*)(wf + OBV + ch0);
#pragma unroll
      for (int nt = 0; nt < 2; ++nt) {
        int col = nt * 16 + (lane & 15);
        *(float4*)(vout + ((size_t)b * N_ + n0 + col) * 64 + ch0) =
            make_float4(accv[nt][0] + bvv.x, accv[nt][1] + bvv.y,
                        accv[nt][2] + bvv.z, accv[nt][3] + bvv.w);
      }
    }
#pragma unroll
    for (int m2 = 0; m2 < 2; ++m2) {
      int ch0 = (wid * 2 + m2) * 16 + ((lane >> 4) << 2);
      float4 brv = *(const float4*)(wf + OBR + ch0);
#pragma unroll
      for (int nt = 0; nt < 2; ++nt) {
        int col = nt * 16 + (lane & 15);
        *(float4*)(idenout + ((size_t)b * N_ + n0 + col) * 128 + ch0) =
            make_float4(accr[m2][nt][0] + brv.x, accr[m2][nt][1] + brv.y,
                        accr[m2][nt][2] + brv.z, accr[m2][nt][3] + brv.w);
      }
    }
  }
}

// ------------------------------------------------------------------
// u projection only (unchanged).
// ------------------------------------------------------------------
__global__ __launch_bounds__(256) void k_gemm_u(const float* __restrict__ wf,
                                                const float* __restrict__ x,
                                                float* __restrict__ out) {
  const int b = blockIdx.y;
  const int n0 = blockIdx.x * 64;
  const float* Wt = wf + OWUT;
  const float* bias = wf + OBU;
  __shared__ float ws_[16][64];
  __shared__ float xs_[16][64];
  const int tid = threadIdx.x, tm = tid & 15, tn = tid >> 4;
  float acc[4][4] = {};
  for (int kt = 0; kt < 256; kt += 16) {
    for (int i = tid; i < 1024; i += 256) {
      int kk = i >> 6, col = i & 63;
      ws_[kk][col] = Wt[(size_t)(kt + kk) * 64 + col];
      xs_[kk][col] = x[((size_t)b * 256 + kt + kk) * N_ + n0 + col];
    }
    __syncthreads();
#pragma unroll
    for (int kk = 0; kk < 16; ++kk) {
      float4 x4 = *(const float4*)&xs_[kk][tn * 4];
      float4 w4 = *(const float4*)&ws_[kk][tm * 4];
      float wv[4] = {w4.x, w4.y, w4.z, w4.w};
      float xv[4] = {x4.x, x4.y, x4.z, x4.w};
#pragma unroll
      for (int i = 0; i < 4; ++i)
#pragma unroll
        for (int j = 0; j < 4; ++j) acc[i][j] += wv[i] * xv[j];
    }
    __syncthreads();
  }
#pragma unroll
  for (int j = 0; j < 4; ++j) {
    *(float4*)(out + ((size_t)b * N_ + n0 + tn * 4 + j) * 64 + tm * 4) =
        make_float4(acc[0][j] + bias[tm * 4], acc[1][j] + bias[tm * 4 + 1],
                    acc[2][j] + bias[tm * 4 + 2], acc[3][j] + bias[tm * 4 + 3]);
  }
}

// ------------------------------------------------------------------
// Self-KNN v5 (unchanged): threshold + bitonic sort, exact.
// ------------------------------------------------------------------
__device__ __forceinline__ unsigned long long bitonic64_(unsigned long long v,
                                                         int lane) {
#pragma unroll
  for (int k = 2; k <= 64; k <<= 1) {
#pragma unroll
    for (int j = k >> 1; j > 0; j >>= 1) {
      unsigned long long o = (unsigned long long)__shfl_xor((long long)v, j);
      bool up = (lane & k) == 0;
      bool lower = (lane & j) == 0;
      bool keepmin = (lower == up);
      unsigned long long mn = o < v ? o : v;
      unsigned long long mx = o < v ? v : o;
      v = keepmin ? mn : mx;
    }
  }
  return v;
}

__global__ __launch_bounds__(256, 8) void k_knn(const float* __restrict__ pos,
                                                int* __restrict__ idxout) {
  const int b = blockIdx.x >> 11, n = blockIdx.x & 2047;
  __shared__ unsigned long long wkeys[4][20];
  __shared__ unsigned long long cand[4][64];
  const int tid = threadIdx.x;
  const int lane = tid & 63, wv = tid >> 6;
  const float* pb = pos + (size_t)b * 3 * N_;
  const double xq = pb[n], yq = pb[N_ + n], zq = pb[2 * N_ + n];
  const double sq = xq * xq + yq * yq + zq * zq;
  unsigned long long key[8];
#pragma unroll
  for (int s = 0; s < 8; ++s) {
    int i = tid + s * 256;
    double x = pb[i], y = pb[N_ + i], z = pb[2 * N_ + i];
    double psq = x * x + y * y + z * z;
    double dot = xq * x + yq * y + zq * z;
    double d2 = fmax((sq + psq) - 2.0 * dot, 0.0);
    key[s] = ((unsigned long long)__double_as_longlong(d2) & ~0x7FFull) |
             (unsigned long long)i;
  }
  unsigned long long m = key[0];
#pragma unroll
  for (int s = 1; s < 8; ++s) m = key[s] < m ? key[s] : m;

  unsigned long long v = bitonic64_(m, lane);
  unsigned long long T = (unsigned long long)__shfl((long long)v, 19);

  int c = 0;
#pragma unroll
  for (int s = 0; s < 8; ++s) c += (key[s] <= T) ? 1 : 0;
  int inc = c;
#pragma unroll
  for (int d = 1; d < 64; d <<= 1) {
    int t = __shfl_up(inc, d);
    if (lane >= d) inc += t;
  }
  const int C = __shfl(inc, 63);
  const int off = inc - c;

  if (C <= 64) {
    int o2 = off;
#pragma unroll
    for (int s = 0; s < 8; ++s) {
      if (key[s] <= T) { cand[wv][o2] = key[s]; ++o2; }
    }
    __builtin_amdgcn_wave_barrier();
    asm volatile("s_waitcnt lgkmcnt(0)" ::: "memory");
    unsigned long long cv = (lane < C) ? cand[wv][lane] : ~0ull;
    cv = bitonic64_(cv, lane);
    if (lane < K_) wkeys[wv][lane] = cv;
  } else {
    for (int r = 0; r < K_; ++r) {
      unsigned long long bk = key[0];
#pragma unroll
      for (int s = 1; s < 8; ++s) bk = key[s] < bk ? key[s] : bk;
      unsigned long long wk = bk;
#pragma unroll
      for (int mm = 32; mm; mm >>= 1) {
        unsigned long long ok = (unsigned long long)__shfl_xor((long long)wk, mm);
        if (ok < wk) wk = ok;
      }
      if (lane == 0) wkeys[wv][r] = wk;
      const int widx = (int)(wk & 0x7FF);
#pragma unroll
      for (int s = 0; s < 8; ++s)
        if (widx == tid + s * 256) key[s] = ~0ull;
    }
  }
  __syncthreads();

  if (tid < 128) {
    const int w = tid >> 5, p = tid & 31;
    if (p < 20) {
      const unsigned long long Kk = wkeys[w][p];
      int rank = p;
#pragma unroll
      for (int w2 = 0; w2 < 4; ++w2) {
        if (w2 == w) continue;
        int lo = 0, hi = 20;
        while (lo < hi) {
          int mid = (lo + hi) >> 1;
          if (wkeys[w2][mid] < Kk) lo = mid + 1; else hi = mid;
        }
        rank += lo;
      }
      if (rank < K_)
        idxout[((size_t)b * N_ + n) * K_ + rank] = (int)(Kk & 0x7FF);
    }
  }
}

// ------------------------------------------------------------------
// Fused attention tail v6: 2 queries/block (QB=2). Columns 0-19 =
// query0 k, 20-39 = query1 k, pad to 48 -> 3 MFMA N-tiles. A-frag
// loads/barriers/P2/P3a amortize over 2 queries; P6 uses all 256
// threads; P7 we native-layout float4, weight stream shared by both
// queries. sVal stored f16. 38.5 KB LDS -> 4 blocks/CU.
// LDS map (bytes): S@0 f16[48][64]=6144 | region@6144..30720:
//   t1 f16[48][64]@6144, pe f32[48][64]@12288, h f16[48][256]@6144,
//   lg f32[40][129]@6144 (each overlay, barrier-separated)
// | sVal f16[48][64]@30720 | aggs f32[2][128]@36864 | idxs[40]@37888
// | prx/pry/prz[40]@38048/38208/38368 -> 38528 total.
// ------------------------------------------------------------------
__global__ __launch_bounds__(256, 4) void k_attn(
    const float* __restrict__ wf,
    const float* __restrict__ qb, const float* __restrict__ kb,
    const float* __restrict__ vb, const float* __restrict__ ub,
    const float* __restrict__ idenb, const int* __restrict__ idxb,
    const float* __restrict__ pos, float* __restrict__ out) {
  const int lb = ((int)blockIdx.x & 7) * 1024 + ((int)blockIdx.x >> 3);
  const int b = lb >> 10, n0 = (lb & 1023) * 2;
  const int tid = threadIdx.x;
  const int lane = tid & 63, wid = tid >> 6;

  __shared__ __align__(16) char smem[38528];
  char*  Sb   = smem;
  char*  hb   = smem + 6144;
  char*  t1b  = smem + 6144;
  char*  peb  = smem + 12288;
  float* lg   = (float*)(smem + 6144);
  char*  svb  = smem + 30720;
  float* aggs = (float*)(smem + 36864);
  int*   idxs = (int*)(smem + 37888);
  float* prx  = (float*)(smem + 38048);
  float* pry  = (float*)(smem + 38208);
  float* prz  = (float*)(smem + 38368);

  if (tid < 40) {
    int qi = tid >= 20;
    idxs[tid] = idxb[((size_t)b * N_ + n0 + qi) * K_ + (tid - qi * 20)] & 2047;
  }
  __syncthreads();

  // P1: gathers; wave w owns cols w*10..w*10+9 (all one query: qi=wid>>1)
  float sreg[10], vreg[10];
  {
    const int qi = wid >> 1;
    size_t rowq = ((size_t)b * N_ + n0 + qi) * 64;
    float qvo = qb[rowq + lane];
    float ufo = ub[rowq + lane];
#pragma unroll
    for (int t = 0; t < 10; ++t) {
      int col = wid * 10 + t;
      int j = idxs[col];
      size_t rowj = ((size_t)b * N_ + j) * 64;
      float kvv = kb[rowj + lane], vvv = vb[rowj + lane], uvv = ub[rowj + lane];
      float ur = ufo - uvv;
      sreg[t] = (qvo - kvv) + ur;
      vreg[t] = vvv + ur;
    }
    if (tid < 40) {
      int j = idxs[tid];
      int qn = n0 + (tid >= 20);
      const float* pp = pos + (size_t)b * 3 * N_;
      prx[tid] = pp[qn] - pp[j];
      pry[tid] = pp[N_ + qn] - pp[N_ + j];
      prz[tid] = pp[2 * N_ + qn] - pp[2 * N_ + j];
    }
  }
  __syncthreads();

  // P2: pos-MLP layer1 + BN + relu -> t1 f16 [col][ph] swz
  {
    int ph = lane;
    float w0 = wf[OPW1 + ph * 3], w1 = wf[OPW1 + ph * 3 + 1], w2 = wf[OPW1 + ph * 3 + 2];
    float pb1 = wf[OPB1 + ph], sc = wf[OPSC + ph], sh = wf[OPSH + ph];
#pragma unroll
    for (int t = 0; t < 10; ++t) {
      int col = wid * 10 + t;
      float u = pb1 + w0 * prx[col] + w1 * pry[col] + w2 * prz[col];
      float tv = fmaxf(u * sc + sh, 0.f);
      *(_Float16*)(t1b + ((col * 128 + ph * 2) ^ ((col & 7) << 4))) = (_Float16)tv;
    }
  }
  __syncthreads();

  // P3a: pe = pm_w2 @ t1 (mt=wid, 2 ks, 3 nt) -> pe f32 [col][o] swz
  {
    f32x4_t pacc[3];
#pragma unroll
    for (int nt = 0; nt < 3; ++nt) pacc[nt] = f32x4_t{0.f, 0.f, 0.f, 0.f};
    const int mt = wid;
#pragma unroll
    for (int ks = 0; ks < 2; ++ks) {
      U4H8 a;
      a.u = ((const uint4*)((const unsigned*)(wf + OPWF)))[(mt * 2 + ks) * 64 + lane];
#pragma unroll
      for (int nt = 0; nt < 3; ++nt) {
        int kc = nt * 16 + (lane & 15);
        U4H8 bu;
        bu.u = *(const uint4*)(t1b + ((kc * 128 + (ks * 32 + ((lane >> 4) << 3)) * 2) ^ ((kc & 7) << 4)));
        pacc[nt] = mfma_16x16x32(a.h, bu.h, pacc[nt]);
      }
    }
    const int o0 = mt * 16 + ((lane >> 4) << 2);
    float4 pb2v = *(const float4*)(wf + OPB2 + o0);
#pragma unroll
    for (int nt = 0; nt < 3; ++nt) {
      int kc = nt * 16 + (lane & 15);
      float4 o;
      o.x = pacc[nt][0] + pb2v.x; o.y = pacc[nt][1] + pb2v.y;
      o.z = pacc[nt][2] + pb2v.z; o.w = pacc[nt][3] + pb2v.w;
      *(float4*)(peb + ((kc * 256 + o0 * 4) ^ ((kc & 7) << 4))) = o;
    }
  }
  __syncthreads();

  // P3b: fold pe into S (f16 swz) and sVal (f16)
  {
#pragma unroll
    for (int t = 0; t < 10; ++t) {
      int col = wid * 10 + t;
      float pe = *(const float*)(peb + ((col * 256 + lane * 4) ^ ((col & 7) << 4)));
      float sv = sreg[t] + pe;
      float vv = vreg[t] + pe;
      *(_Float16*)(svb + col * 128 + lane * 2) = (_Float16)vv;
      *(_Float16*)(Sb + ((col * 128 + lane * 2) ^ ((col & 7) << 4))) = (_Float16)sv;
    }
  }
  __syncthreads();

  // P4: h = relu(bn(am_w1 @ S)) (16 mt: wid*4+pass*2+m, 2 ks, 3 nt)
#pragma unroll
  for (int pass = 0; pass < 2; ++pass) {
    const int mt0 = wid * 4 + pass * 2;
    f32x4_t acc[2][3];
#pragma unroll
    for (int m = 0; m < 2; ++m)
#pragma unroll
      for (int nt = 0; nt < 3; ++nt) acc[m][nt] = f32x4_t{0.f, 0.f, 0.f, 0.f};
#pragma unroll
    for (int ks = 0; ks < 2; ++ks) {
      U4H8 bfr[3];
#pragma unroll
      for (int nt = 0; nt < 3; ++nt) {
        int kc = nt * 16 + (lane & 15);
        bfr[nt].u = *(const uint4*)(Sb + ((kc * 128 + (ks * 32 + ((lane >> 4) << 3)) * 2) ^ ((kc & 7) << 4)));
      }
#pragma unroll
      for (int m = 0; m < 2; ++m) {
        U4H8 a;
        a.u = ((const uint4*)((const unsigned*)(wf + OAWF)))[((mt0 + m) * 2 + ks) * 64 + lane];
#pragma unroll
        for (int nt = 0; nt < 3; ++nt)
          acc[m][nt] = mfma_16x16x32(a.h, bfr[nt].h, acc[m][nt]);
      }
    }
#pragma unroll
    for (int m = 0; m < 2; ++m) {
      const int c0 = (mt0 + m) * 16 + ((lane >> 4) << 2);
      float4 ab1 = *(const float4*)(wf + OAB1 + c0);
      float4 asc = *(const float4*)(wf + OASC + c0);
      float4 ash = *(const float4*)(wf + OASH + c0);
#pragma unroll
      for (int nt = 0; nt < 3; ++nt) {
        int kc = nt * 16 + (lane & 15);
        float h0 = fmaxf((acc[m][nt][0] + ab1.x) * asc.x + ash.x, 0.f);
        float h1 = fmaxf((acc[m][nt][1] + ab1.y) * asc.y + ash.y, 0.f);
        float h2 = fmaxf((acc[m][nt][2] + ab1.z) * asc.z + ash.z, 0.f);
        float h3 = fmaxf((acc[m][nt][3] + ab1.w) * asc.w + ash.w, 0.f);
        uint2 p;
        p.x = pkh2(h0, h1);
        p.y = pkh2(h2, h3);
        *(uint2*)(hb + ((kc * 512 + c0 * 2) ^ ((kc & 7) << 4))) = p;
      }
    }
  }
  __syncthreads();

  // P5: lg = wt @ h (8 mt: wid*2+m, 8 ks, 3 nt)
  {
    f32x4_t acc5[2][3];
#pragma unroll
    for (int m = 0; m < 2; ++m)
#pragma unroll
      for (int nt = 0; nt < 3; ++nt) acc5[m][nt] = f32x4_t{0.f, 0.f, 0.f, 0.f};
#pragma unroll
    for (int ks = 0; ks < 8; ++ks) {
      U4H8 bfr[3];
#pragma unroll
      for (int nt = 0; nt < 3; ++nt) {
        int kc = nt * 16 + (lane & 15);
        bfr[nt].u = *(const uint4*)(hb + ((kc * 512 + (ks * 32 + ((lane >> 4) << 3)) * 2) ^ ((kc & 7) << 4)));
      }
#pragma unroll
      for (int m = 0; m < 2; ++m) {
        U4H8 a;
        a.u = ((const uint4*)((const unsigned*)(wf + OWTF)))[((wid * 2 + m) * 8 + ks) * 64 + lane];
#pragma unroll
        for (int nt = 0; nt < 3; ++nt)
          acc5[m][nt] = mfma_16x16x32(a.h, bfr[nt].h, acc5[m][nt]);
      }
    }
    __syncthreads();  // all h reads done before lg overlays the region
#pragma unroll
    for (int m = 0; m < 2; ++m) {
      const int or0 = (wid * 2 + m) * 16 + ((lane >> 4) << 2);
#pragma unroll
      for (int nt = 0; nt < 3; ++nt) {
        int kc = nt * 16 + (lane & 15);
        if (kc < 40) {
#pragma unroll
          for (int r = 0; r < 4; ++r) lg[kc * 129 + or0 + r] = acc5[m][nt][r];
        }
      }
    }
  }
  __syncthreads();

  // P6: softmax over k + aggregate; all 256 threads (qsel = tid>>7)
  {
    const int qsel = tid >> 7, orr = tid & 127, o = orr >> 1;
    float l[20];
#pragma unroll
    for (int kk = 0; kk < 20; ++kk) l[kk] = lg[(qsel * 20 + kk) * 129 + orr];
    float bt = wf[OABT + o];
    float m = -3.4e38f;
#pragma unroll
    for (int kk = 0; kk < 20; ++kk) { l[kk] += bt; m = fmaxf(m, l[kk]); }
    float s = 0.f;
#pragma unroll
    for (int kk = 0; kk < 20; ++kk) { l[kk] = expf(l[kk] - m); s += l[kk]; }
    float inv = 1.f / s;
    float a = 0.f;
#pragma unroll
    for (int kk = 0; kk < 20; ++kk)
      a += l[kk] * (float)(*(const _Float16*)(svb + (qsel * 20 + kk) * 128 + o * 2));
    aggs[qsel * 128 + orr] = a * inv;
  }
  __syncthreads();

  // P7: y = we @ agg + be + iden; native we [co][o], float4; both queries
  {
    const int co = tid & 127, r = tid >> 7;
    float y0 = wf[OBE + co], y1 = y0;
    const float* w = wf + OWET + co * 64;
#pragma unroll 4
    for (int o4 = 0; o4 < 16; ++o4) {
      float4 w4 = *(const float4*)(w + o4 * 4);
      const float wv[4] = {w4.x, w4.y, w4.z, w4.w};
#pragma unroll
      for (int j = 0; j < 4; ++j) {
        int oi = o4 * 4 + j;
        y0 += wv[j] * aggs[oi * 2 + r];
        y1 += wv[j] * aggs[128 + oi * 2 + r];
      }
    }
    float id0 = idenb[((size_t)b * N_ + n0) * 128 + co];
    float id1 = idenb[((size_t)b * N_ + n0 + 1) * 128 + co];
    size_t obase = ((size_t)b * 128 + co) * (size_t)(2 * N_);
    out[obase + 2 * n0 + r] = y0 + id0;
    out[obase + 2 * n0 + 2 + r] = y1 + id1;
  }
}

extern "C" void kernel_launch(void* const* d_in, const int* in_sizes, int n_in,
                              void* d_out, int out_size, void* d_ws, size_t ws_size,
                              hipStream_t stream) {
  (void)in_sizes; (void)n_in; (void)out_size; (void)ws_size;
  InPtrs ip;
  for (int i = 0; i < 38; ++i) ip.p[i] = (const float*)d_in[i];
  char* ws = (char*)d_ws;
  float* wf    = (float*)(ws + OFFB_WF);
  int*   idxb  = (int*)(ws + OFFB_IDX);
  float* qb    = (float*)(ws + OFFB_Q);
  float* kb    = (float*)(ws + OFFB_K);
  float* ubuf  = (float*)(ws + OFFB_U);
  float* vbuf  = (float*)(ws + OFFB_V);
  float* idenb = (float*)(ws + OFFB_IDEN);

  k_prep<<<dim3(256), dim3(256), 0, stream>>>(ip, wf);
  k_mv<<<dim3(64, 8), dim3(256), 0, stream>>>(wf, ip.p[1], ip.p[2], vbuf, idenb, qb, kb);
  k_gemm_u<<<dim3(32, 8), dim3(256), 0, stream>>>(wf, ip.p[3], ubuf);
  k_knn<<<dim3(B_ * N_), dim3(256), 0, stream>>>(ip.p[0], idxb);
  k_attn<<<dim3(B_ * N_ / 2), dim3(256), 0, stream>>>(wf, qb, kb, vbuf, ubuf, idenb, idxb,
                                                      ip.p[0], (float*)d_out);
}